// Round 20
// baseline (555.536 us; speedup 1.0000x reference)
//
#include <hip/hip_runtime.h>
#include <hip/hip_bf16.h>

typedef __hip_bfloat16 bf16;
typedef unsigned short ush;

static constexpr int kN   = 4096;    // nodes
static constexpr int kND  = 256;     // hidden
static constexpr int kEL  = 131072;  // local edges
static constexpr int kED  = 32;      // edge dim
static constexpr int kELG = 262144;  // line-graph edges
static constexpr int kL   = 2;
static constexpr int kQW  = 832;     // packed qkv+sd GEMM width
static constexpr int kKV  = 512;     // kvaux row stride (bf16), per-head interleaved K/V
static constexpr float kScaleN = 0.17677669529663687f; // 1/sqrt(32)

using frag_ab = __attribute__((ext_vector_type(8))) short;   // 8 bf16 (4 VGPRs)
using frag_cd = __attribute__((ext_vector_type(4))) float;   // 4 fp32

__device__ __forceinline__ float ldf(const void* p, size_t i, int isbf){
    return isbf ? __bfloat162float(((const bf16*)p)[i]) : ((const float*)p)[i];
}
__device__ __forceinline__ ush f2b(float f){ bf16 h = __float2bfloat16(f); return *(ush*)&h; }
__device__ __forceinline__ float b2f(ush u){ return __uint_as_float(((unsigned)u)<<16); }
__device__ __forceinline__ ush ldb(const void* p, size_t i, int isbf){
    return isbf ? ((const ush*)p)[i] : f2b(((const float*)p)[i]);
}

// ---------------- dtype detection (wave-parallel) ----------------
__global__ void detect_k(const ush* __restrict__ xin, int* __restrict__ flag){
    const int t = threadIdx.x;              // 64 threads
    int pl = 0;
    for (int i = t; i < 128; i += 64) {
        ush u = xin[i];
        int e = (u >> 7) & 0xFF;
        if (e == 0 || (e >= 110 && e <= 140)) ++pl;
    }
    #pragma unroll
    for (int off = 32; off > 0; off >>= 1) pl += __shfl_down(pl, off);
    if (t == 0) *flag = (pl >= 102) ? 1 : 0;
}

// ---------------- fused setup: cast x (f32+bf16), init lg (bf16), pack bias, zero counters ----------------
__global__ void setup_misc_k(const void* __restrict__ xin, const void* __restrict__ rel,
                             const int* __restrict__ feat,
                             const void* __restrict__ bq, const void* __restrict__ bk,
                             const void* __restrict__ bv,
                             float* __restrict__ xA, ush* __restrict__ xAb,
                             ush* __restrict__ lgA,
                             float* __restrict__ bQKV,
                             int* __restrict__ cntL, int* __restrict__ cntG,
                             const int* __restrict__ flag){
    const int isbf = *flag;
    long g = (long)blockIdx.x*256 + threadIdx.x;
    if (g < (long)kN*kND) {
        float v = ldf(xin, g, isbf);
        xA[g] = v; xAb[g] = f2b(v);
        return;
    }
    g -= (long)kN*kND;
    if (g < (long)kEL*kED) { int e = (int)(g >> 5), d = (int)(g & 31);
        lgA[g] = ldb(rel, (size_t)feat[e]*kED + d, isbf); return; }
    g -= (long)kEL*kED;
    if (g < 2*kQW) {
        int layer = (int)(g / kQW), j = (int)(g - (long)layer*kQW);
        float v = 0.f;
        if (j < 768) { int w = j >> 8, jj = j & 255;
            const void* B = (w==0)?bq:((w==1)?bk:bv);
            v = ldf(B, (size_t)layer*256 + jj, isbf); }
        bQKV[g] = v; return;
    }
    g -= 2*kQW;
    if (g < kN) { cntL[g] = 0; return; }
    g -= kN;
    if (g < kEL) { cntG[g] = 0; return; }
}

// ---------------- ALL weight pre-transposes: 32x32 LDS-tiled, coalesced both sides ----------------
__global__ __launch_bounds__(256) void trans_tiled_k(
    const void* __restrict__ nWq, const void* __restrict__ nWk, const void* __restrict__ nWv,
    const void* __restrict__ nWo, const void* __restrict__ nF1, const void* __restrict__ nF2,
    const void* __restrict__ eWs, const void* __restrict__ eWd,
    const void* __restrict__ eWq, const void* __restrict__ eWk, const void* __restrict__ eWv,
    const void* __restrict__ eWo, const void* __restrict__ eF1, const void* __restrict__ eF2,
    const int* __restrict__ flag,
    ush* __restrict__ wtQKVSD, ush* __restrict__ wtO, ush* __restrict__ wtF1,
    ush* __restrict__ wtF2, ush* __restrict__ wtEQKV, ush* __restrict__ wtEO,
    ush* __restrict__ wtEF1, ush* __restrict__ wtEF2)
{
    __shared__ ush lds[32][33];
    const int isbf = *flag;
    int idx = blockIdx.x;
    const void* src; size_t soff; ush* dstp; size_t doff;
    int Ns, Kd, r0, c0;
    if (idx < 384) {                                    // nWq/nWk/nWv [L][256][256] -> QKVSD rows 0-767
        int w = idx >> 7, rem = idx & 127;
        int layer = rem >> 6, tile = rem & 63;
        r0 = (tile >> 3) << 5; c0 = (tile & 7) << 5;
        src = (w==0)?nWq:((w==1)?nWk:nWv); soff = (size_t)layer*65536;
        Ns = 256; Kd = 256;
        dstp = wtQKVSD; doff = (size_t)layer*212992 + (size_t)w*65536;
    } else if ((idx -= 384) < 32) {                     // eWs/eWd [L][256][32] -> rows 768-831
        int w = idx >> 4, rem = idx & 15;
        int layer = rem >> 3, tile = rem & 7;
        r0 = tile << 5; c0 = 0;
        src = w ? eWd : eWs; soff = (size_t)layer*8192;
        Ns = 32; Kd = 256;
        dstp = wtQKVSD; doff = (size_t)layer*212992 + (size_t)(768 + w*32)*256;
    } else if ((idx -= 32) < 128) {                     // nWo [L][256][256]
        int layer = idx >> 6, tile = idx & 63;
        r0 = (tile >> 3) << 5; c0 = (tile & 7) << 5;
        src = nWo; soff = (size_t)layer*65536; Ns = 256; Kd = 256;
        dstp = wtO; doff = (size_t)layer*65536;
    } else if ((idx -= 128) < 512) {                    // nF1 [L][256][1024] -> [L][1024][256]
        int layer = idx >> 8, tile = idx & 255;
        r0 = (tile >> 5) << 5; c0 = (tile & 31) << 5;
        src = nF1; soff = (size_t)layer*262144; Ns = 1024; Kd = 256;
        dstp = wtF1; doff = (size_t)layer*262144;
    } else if ((idx -= 512) < 512) {                    // nF2 [L][1024][256] -> [L][256][1024]
        int layer = idx >> 8, tile = idx & 255;
        r0 = (tile >> 3) << 5; c0 = (tile & 7) << 5;
        src = nF2; soff = (size_t)layer*262144; Ns = 256; Kd = 1024;
        dstp = wtF2; doff = (size_t)layer*262144;
    } else if ((idx -= 512) < 6) {                      // eWq/eWk/eWv [L][32][32]
        int w = idx >> 1, layer = idx & 1;
        r0 = 0; c0 = 0;
        src = (w==0)?eWq:((w==1)?eWk:eWv); soff = (size_t)layer*1024; Ns = 32; Kd = 32;
        dstp = wtEQKV; doff = (size_t)(w*2 + layer)*1024;
    } else if ((idx -= 6) < 2) {                        // eWo [L][32][32]
        r0 = 0; c0 = 0;
        src = eWo; soff = (size_t)idx*1024; Ns = 32; Kd = 32;
        dstp = wtEO; doff = (size_t)idx*1024;
    } else if ((idx -= 2) < 8) {                        // eF1 [L][32][128] -> [L][128][32]
        int layer = idx >> 2, tile = idx & 3;
        r0 = 0; c0 = tile << 5;
        src = eF1; soff = (size_t)layer*4096; Ns = 128; Kd = 32;
        dstp = wtEF1; doff = (size_t)layer*4096;
    } else {                                            // eF2 [L][128][32] -> [L][32][128]
        idx -= 8;
        int layer = idx >> 2, tile = idx & 3;
        r0 = tile << 5; c0 = 0;
        src = eF2; soff = (size_t)layer*4096; Ns = 32; Kd = 128;
        dstp = wtEF2; doff = (size_t)layer*4096;
    }
    const int t = threadIdx.x;
    const int c = t & 31, rb = t >> 5;
    #pragma unroll
    for (int p = 0; p < 4; ++p) {
        int r = rb + p*8;
        lds[r][c] = ldb(src, soff + (size_t)(r0 + r)*Ns + c0 + c, isbf);
    }
    __syncthreads();
    #pragma unroll
    for (int p = 0; p < 4; ++p) {
        int rr = rb + p*8;
        dstp[doff + (size_t)(c0 + rr)*Kd + r0 + c] = lds[c][rr];
    }
}

// ---------------- CSR build (both graphs fused) ----------------
__global__ void count2_k(const int* __restrict__ gd, const int* __restrict__ lgd,
                         int* __restrict__ cntL, int* __restrict__ cntG){
    int g = blockIdx.x*256 + threadIdx.x;
    if (g < kEL) atomicAdd(&cntL[gd[g]], 1);
    else if (g < kEL + kELG) atomicAdd(&cntG[lgd[g - kEL]], 1);
}
__global__ __launch_bounds__(256) void scan_blk2_k(
    const int* __restrict__ cntL, const int* __restrict__ cntG,
    int* __restrict__ rowL, int* __restrict__ rowG, int* __restrict__ bsum)
{
    __shared__ int s[256];
    const int t = threadIdx.x;
    const bool isL = blockIdx.x < 4;
    const int* cnt = isL ? cntL : cntG;
    int* out = isL ? rowL : rowG;
    const int blk = isL ? blockIdx.x : blockIdx.x - 4;
    const int n = isL ? kN : kEL;
    const int b0 = blk*1024;
    int v[4], pre[4], tsum = 0;
    #pragma unroll
    for (int j=0;j<4;++j){
        int idx = b0 + t*4 + j;
        v[j] = (idx < n) ? cnt[idx] : 0;
        pre[j] = tsum; tsum += v[j];
    }
    s[t] = tsum; __syncthreads();
    for (int off=1; off<256; off<<=1){
        int x = (t>=off) ? s[t-off] : 0;
        __syncthreads();
        s[t] += x;
        __syncthreads();
    }
    int texc = s[t] - tsum;
    #pragma unroll
    for (int j=0;j<4;++j){
        int idx = b0 + t*4 + j;
        if (idx < n) out[idx] = texc + pre[j];
    }
    if (t == 255) bsum[(isL ? 0 : 8) + blk] = s[255];
}
__global__ __launch_bounds__(256) void scan_top2_k(int* __restrict__ bsum){
    __shared__ int sL[256], sG[256];
    const int t = threadIdx.x;
    int vL = (t < 4)   ? bsum[t]     : 0;
    int vG = (t < 128) ? bsum[8 + t] : 0;
    sL[t] = vL; sG[t] = vG; __syncthreads();
    for (int off=1; off<256; off<<=1){
        int xL = (t>=off) ? sL[t-off] : 0;
        int xG = (t>=off) ? sG[t-off] : 0;
        __syncthreads();
        sL[t] += xL; sG[t] += xG;
        __syncthreads();
    }
    if (t < 4)   bsum[t]     = sL[t] - vL;
    if (t < 128) bsum[8 + t] = sG[t] - vG;
}
__global__ void scan_add2_k(int* __restrict__ rowL, int* __restrict__ rowG,
                            const int* __restrict__ bsum,
                            int* __restrict__ curL, int* __restrict__ curG){
    int g = blockIdx.x*256 + threadIdx.x;
    if (g < kN){ int v = rowL[g] + bsum[g >> 10]; rowL[g] = v; curL[g] = v; }
    else if (g < kN + kEL){ int gg = g - kN;
        int v = rowG[gg] + bsum[8 + (gg >> 10)]; rowG[gg] = v; curG[gg] = v; }
    if (g == 0){ rowL[kN] = kEL; rowG[kEL] = kELG; }
}
__global__ void fill2_k(const int* __restrict__ gd, const int* __restrict__ lgd,
                        int* __restrict__ curL, int* __restrict__ curG,
                        int* __restrict__ eidL, int* __restrict__ eidG){
    int g = blockIdx.x*256 + threadIdx.x;
    if (g < kEL){ int pos = atomicAdd(&curL[gd[g]], 1); eidL[pos] = g; }
    else if (g < kEL + kELG){ int gg = g - kEL;
        int pos = atomicAdd(&curG[lgd[gg]], 1); eidG[pos] = gg; }
}

// ---------------- MFMA GEMM: C[M,N] = A@WT^T + bias (opt relu); BK=64 ----------------
// WT: bf16 [N][K]. 64x64 tile, 4 waves. Requires K%(64*gridDim.z)==0, N%64==0.
// flags: 2=RELU, 4=has-bias, 8=bf16 out, 16=bias packed fp32, 32=A is bf16,
//        64=QKV split output (col<256 -> fp32 C; 256-767 -> bf16 aux interleaved; 768+ -> aux2),
//        128=split-K over gridDim.z (bias by z==0 only; fp32 partials at C + z*M*N)
__global__ __launch_bounds__(256) void mgemm_k(
    const float* __restrict__ A, const ush* __restrict__ WT,
    const void* __restrict__ bias, size_t boff,
    float* __restrict__ C, const int* __restrict__ flag,
    int M, int N, int K, int flags, ush* __restrict__ aux, ush* __restrict__ aux2)
{
    __shared__ __align__(16) ush As[64*72];
    __shared__ __align__(16) ush Ws[64*72];
    const int isbf = *flag;
    const int t = threadIdx.x;
    const int m0 = blockIdx.y*64, n0 = blockIdx.x*64;
    const int wave = t>>6, lane = t&63;
    const int quad = lane>>4, l15 = lane&15;
    const int r = t>>3, kq = (t&7)*8;      // rows r and r+32, 8 K-elems at kq
    const bool abf = flags & 32;
    const bool spk = flags & 128;
    const int Kc   = spk ? (K / gridDim.z) : K;
    const int koff = spk ? (blockIdx.z * Kc) : 0;

    frag_cd acc[4];
    #pragma unroll
    for (int tl=0; tl<4; ++tl)
        #pragma unroll
        for (int j=0;j<4;++j) acc[tl][j] = 0.f;

    const float* ap0 = A + (size_t)(m0+r)*K + koff + kq;
    const float* ap1 = A + (size_t)(m0+r+32)*K + koff + kq;
    const ush*   ab0 = (const ush*)A + (size_t)(m0+r)*K + koff + kq;
    const ush*   ab1 = (const ush*)A + (size_t)(m0+r+32)*K + koff + kq;
    const ush*   wp0 = WT + (size_t)(n0+r)*K + koff + kq;
    const ush*   wp1 = WT + (size_t)(n0+r+32)*K + koff + kq;

    float4 a00,a01,a10,a11; uint4 av0,av1, wv0,wv1;
    auto loadT = [&](int kk){
        if (abf) { av0 = *(const uint4*)(ab0+kk); av1 = *(const uint4*)(ab1+kk); }
        else { a00 = *(const float4*)(ap0+kk); a01 = *(const float4*)(ap0+kk+4);
               a10 = *(const float4*)(ap1+kk); a11 = *(const float4*)(ap1+kk+4); }
        wv0 = *(const uint4*)(wp0+kk); wv1 = *(const uint4*)(wp1+kk);
    };
    loadT(0);

    for (int kk = 0; kk < Kc; kk += 64) {
        if (abf) {
            *(uint4*)&As[r*72 + kq]        = av0;
            *(uint4*)&As[(r+32)*72 + kq]   = av1;
        } else {
            *(ushort4*)&As[r*72 + kq]       = make_ushort4(f2b(a00.x),f2b(a00.y),f2b(a00.z),f2b(a00.w));
            *(ushort4*)&As[r*72 + kq + 4]   = make_ushort4(f2b(a01.x),f2b(a01.y),f2b(a01.z),f2b(a01.w));
            *(ushort4*)&As[(r+32)*72 + kq]     = make_ushort4(f2b(a10.x),f2b(a10.y),f2b(a10.z),f2b(a10.w));
            *(ushort4*)&As[(r+32)*72 + kq + 4] = make_ushort4(f2b(a11.x),f2b(a11.y),f2b(a11.z),f2b(a11.w));
        }
        *(uint4*)&Ws[r*72 + kq]      = wv0;
        *(uint4*)&Ws[(r+32)*72 + kq] = wv1;
        __syncthreads();
        if (kk + 64 < Kc) loadT(kk + 64);
        frag_ab af0 = *(const frag_ab*)&As[(wave*16 + l15)*72 + quad*8];
        frag_ab af1 = *(const frag_ab*)&As[(wave*16 + l15)*72 + 32 + quad*8];
        #pragma unroll
        for (int tl = 0; tl < 4; ++tl) {
            frag_ab bf0 = *(const frag_ab*)&Ws[(tl*16 + l15)*72 + quad*8];
            acc[tl] = __builtin_amdgcn_mfma_f32_16x16x32_bf16(af0, bf0, acc[tl], 0, 0, 0);
            frag_ab bf1 = *(const frag_ab*)&Ws[(tl*16 + l15)*72 + 32 + quad*8];
            acc[tl] = __builtin_amdgcn_mfma_f32_16x16x32_bf16(af1, bf1, acc[tl], 0, 0, 0);
        }
        __syncthreads();
    }
    const bool do_relu = flags & 2;
    const bool has_b   = (flags & 4) && (!spk || blockIdx.z == 0);
    const bool obf     = flags & 8;
    float* Cz = spk ? (C + (size_t)blockIdx.z * M * N) : C;
    #pragma unroll
    for (int tl = 0; tl < 4; ++tl) {
        int col = n0 + tl*16 + l15;
        float bv = 0.f;
        if (has_b) bv = (flags & 16) ? ((const float*)bias)[boff + col]
                                     : ldf(bias, boff + col, isbf);
        // kvaux/xsd column mapping for QKV split output:
        int adst = -1; bool tox = false;
        if (flags & 64 && col >= 256) {
            int c = col - 256;
            if (c < 512) {
                int isv = c >> 8;            // 0 = K, 1 = V
                int cc = c & 255;
                int h = cc >> 5, d = cc & 31;
                int base = (h < 4) ? h*64 : 256 + (h-4)*64;
                adst = base + isv*32 + d;
            } else { adst = c - 512; tox = true; }   // SD -> compact xsd [row][64]
        }
        #pragma unroll
        for (int rg = 0; rg < 4; ++rg) {
            int row = m0 + wave*16 + quad*4 + rg;
            float v = acc[tl][rg] + bv;
            if (do_relu) v = fmaxf(v, 0.f);
            if (flags & 64) {
                if (col < 256)  C[(size_t)row*256 + col] = v;
                else if (tox)   aux2[(size_t)row*64 + adst] = f2b(v);
                else            aux[(size_t)row*kKV + adst] = f2b(v);
            } else if (obf) ((ush*)C)[(size_t)row*N + col] = f2b(v);
            else            Cz[(size_t)row*N + col] = v;
        }
    }
}

// ---------------- fused GEMM(N=256) + bias + residual + LayerNorm, dual f32+bf16 out ----------------
// A bf16 [M][K], WT bf16 [256][K]. Block = 16 rows x 256 cols, 4 waves (wave owns 64-col quadrant).
// out = LN(res + A@WT^T + bias). Grid = M/16. K % 64 == 0.
__global__ __launch_bounds__(256) void gemm_ln_k(
    const ush* __restrict__ A, const ush* __restrict__ WT,
    const void* __restrict__ bias, size_t boff,
    const float* __restrict__ res,
    const void* __restrict__ g, const void* __restrict__ be, size_t goff,
    float* __restrict__ out, ush* __restrict__ outb,
    const int* __restrict__ flag, int K)
{
    __shared__ __align__(16) ush As[16*72];
    __shared__ __align__(16) ush Ws[256*72];
    __shared__ float cs[16][260];
    __shared__ float bs[256], gsv[256], bes[256];
    const int isbf = *flag;
    const int t = threadIdx.x;
    const int m0 = blockIdx.x * 16;
    const int wave = t >> 6, lane = t & 63;
    const int quad = lane >> 4, l15 = lane & 15;

    bs[t]  = ldf(bias, boff + t, isbf);
    gsv[t] = ldf(g,  goff + t, isbf);
    bes[t] = ldf(be, goff + t, isbf);

    frag_cd acc[4];
    #pragma unroll
    for (int nt = 0; nt < 4; ++nt)
        #pragma unroll
        for (int j = 0; j < 4; ++j) acc[nt][j] = 0.f;

    const int ar = t >> 4, ak = (t & 15) * 4;   // A staging: row ar, 4 ush at ak
    const ush* ap = A + (size_t)(m0 + ar)*K + ak;

    ushort4 avr; uint4 wvr[8];
    auto loadT = [&](int kk){
        avr = *(const ushort4*)(ap + kk);
        #pragma unroll
        for (int j = 0; j < 8; ++j) {
            int idx = t + j*256;
            int cl = idx >> 3, k8 = (idx & 7) * 8;
            wvr[j] = *(const uint4*)&WT[(size_t)cl*K + kk + k8];
        }
    };
    loadT(0);

    for (int kk = 0; kk < K; kk += 64) {
        *(ushort4*)&As[ar*72 + ak] = avr;
        #pragma unroll
        for (int j = 0; j < 8; ++j) {
            int idx = t + j*256;
            int cl = idx >> 3, k8 = (idx & 7) * 8;
            *(uint4*)&Ws[cl*72 + k8] = wvr[j];
        }
        __syncthreads();
        if (kk + 64 < K) loadT(kk + 64);
        frag_ab af0 = *(const frag_ab*)&As[l15*72 + quad*8];
        frag_ab af1 = *(const frag_ab*)&As[l15*72 + 32 + quad*8];
        #pragma unroll
        for (int nt = 0; nt < 4; ++nt) {
            frag_ab bf0 = *(const frag_ab*)&Ws[(wave*64 + nt*16 + l15)*72 + quad*8];
            acc[nt] = __builtin_amdgcn_mfma_f32_16x16x32_bf16(af0, bf0, acc[nt], 0, 0, 0);
            frag_ab bf1 = *(const frag_ab*)&Ws[(wave*64 + nt*16 + l15)*72 + 32 + quad*8];
            acc[nt] = __builtin_amdgcn_mfma_f32_16x16x32_bf16(af1, bf1, acc[nt], 0, 0, 0);
        }
        __syncthreads();
    }
    // epilogue: acc + bias + residual into cs
    #pragma unroll
    for (int nt = 0; nt < 4; ++nt) {
        const int col = wave*64 + nt*16 + l15;
        #pragma unroll
        for (int rg = 0; rg < 4; ++rg) {
            const int row = quad*4 + rg;
            cs[row][col] = acc[nt][rg] + bs[col] + res[(size_t)(m0 + row)*256 + col];
        }
    }
    __syncthreads();
    // LN: thread handles (row = t>>4, 16 cols at (t&15)*16); reduce across 16-lane group
    {
        const int row = t >> 4, cc = (t & 15) * 16;
        float v[16];
        float s = 0.f;
        #pragma unroll
        for (int j = 0; j < 16; ++j) { v[j] = cs[row][cc + j]; s += v[j]; }
        s += __shfl_xor(s, 1); s += __shfl_xor(s, 2);
        s += __shfl_xor(s, 4); s += __shfl_xor(s, 8);
        const float mean = s * (1.f/256.f);
        float qq = 0.f;
        #pragma unroll
        for (int j = 0; j < 16; ++j) { float d = v[j] - mean; qq += d*d; }
        qq += __shfl_xor(qq, 1); qq += __shfl_xor(qq, 2);
        qq += __shfl_xor(qq, 4); qq += __shfl_xor(qq, 8);
        const float inv = rsqrtf(fmaxf(qq, 0.f) * (1.f/256.f) + 1e-5f);
        const size_t base = (size_t)(m0 + row)*256 + cc;
        #pragma unroll
        for (int j = 0; j < 16; ++j) {
            float r = (v[j] - mean)*inv*gsv[cc + j] + bes[cc + j];
            out[base + j] = r;
            outb[base + j] = f2b(r);
        }
    }
}

// ---------------- MFMA eq/ekv (+gathered mixed), 128 rows/block, bf16 in/out ----------------
// xsd: compact [4096][64] bf16 (src at 0-31, dst at 32-63). Vectorized staging.
// Output: eq [el][32]; ekv [el][64] interleaved (k_h at h*8, v_h at h*8+4).
__global__ __launch_bounds__(256) void eqkv_mfma_k(
    const ush* __restrict__ lg, const ush* __restrict__ xsd,
    const int* __restrict__ gsrc, const int* __restrict__ gdst,
    const ush* __restrict__ WQKV, size_t woff,
    const void* __restrict__ bq, size_t boff,
    ush* __restrict__ eq, ush* __restrict__ ekv,
    const int* __restrict__ flag)
{
    __shared__ __align__(16) ush mixs[128*40];
    __shared__ __align__(16) ush wts[3][32*40];
    __shared__ float bqs[32];
    const int isbf = *flag;
    const int t = threadIdx.x;
    const int e0 = blockIdx.x * 128;
    #pragma unroll
    for (int i = t; i < 768; i += 256) {
        int m = i >> 8, r2 = i & 255;
        int n = r2 >> 3, k4 = (r2 & 7) * 4;
        *(ushort4*)&wts[m][n*40 + k4] =
            *(const ushort4*)&WQKV[(size_t)m*2048 + woff + (size_t)n*32 + k4];
    }
    if (t < 32) bqs[t] = ldf(bq, boff + t, isbf);
    {
        int r = t >> 1, c0 = (t & 1) * 16;
        int e = e0 + r;
        int s = gsrc[e], d2 = gdst[e];
        const ush* lp = lg  + (size_t)e*32  + c0;
        const ush* sp = xsd + (size_t)s*64  + c0;
        const ush* dp = xsd + (size_t)d2*64 + 32 + c0;
        uint4 lv0 = *(const uint4*)lp,     lv1 = *(const uint4*)(lp+8);
        uint4 sv0 = *(const uint4*)sp,     sv1 = *(const uint4*)(sp+8);
        uint4 dv0 = *(const uint4*)dp,     dv1 = *(const uint4*)(dp+8);
        auto pk = [](unsigned a, unsigned b, unsigned c)->unsigned {
            ush lo = f2b(b2f((ush)(a & 0xffff)) + b2f((ush)(b & 0xffff)) + b2f((ush)(c & 0xffff)));
            ush hi = f2b(b2f((ush)(a >> 16))    + b2f((ush)(b >> 16))    + b2f((ush)(c >> 16)));
            return (unsigned)lo | ((unsigned)hi << 16);
        };
        uint4 o0, o1;
        o0.x = pk(lv0.x, sv0.x, dv0.x); o0.y = pk(lv0.y, sv0.y, dv0.y);
        o0.z = pk(lv0.z, sv0.z, dv0.z); o0.w = pk(lv0.w, sv0.w, dv0.w);
        o1.x = pk(lv1.x, sv1.x, dv1.x); o1.y = pk(lv1.y, sv1.y, dv1.y);
        o1.z = pk(lv1.z, sv1.z, dv1.z); o1.w = pk(lv1.w, sv1.w, dv1.w);
        *(uint4*)&mixs[r*40 + c0]     = o0;
        *(uint4*)&mixs[r*40 + c0 + 8] = o1;
    }
    __syncthreads();
    const int wave = t >> 6, l15 = t & 15, quad = (t >> 4) & 3;
    #pragma unroll
    for (int mi = 0; mi < 2; ++mi) {
        const int mt = wave*2 + mi;
        frag_ab af = *(const frag_ab*)&mixs[(mt*16 + l15)*40 + quad*8];
        #pragma unroll
        for (int w = 0; w < 3; ++w) {
            #pragma unroll
            for (int nt = 0; nt < 2; ++nt) {
                frag_ab bf = *(const frag_ab*)&wts[w][(nt*16 + l15)*40 + quad*8];
                frag_cd acc = {0.f, 0.f, 0.f, 0.f};
                acc = __builtin_amdgcn_mfma_f32_16x16x32_bf16(af, bf, acc, 0, 0, 0);
                const float bv = (w==0) ? bqs[nt*16 + l15] : 0.f;
                const int col = nt*16 + l15;            // 0..31
                const int h = col >> 2, d = col & 3;
                #pragma unroll
                for (int rg = 0; rg < 4; ++rg) {
                    int row = e0 + mt*16 + quad*4 + rg;
                    float v = acc[rg] + bv;
                    if (w == 0)      eq[(size_t)row*32 + col] = f2b(v);
                    else if (w == 1) ekv[(size_t)row*64 + h*8 + d] = f2b(v);
                    else             ekv[(size_t)row*64 + h*8 + 4 + d] = f2b(v);
                }
            }
        }
    }
}

// ---------------- MFMA edge FFN: LN(A + relu(A@W1+b1)@W2 + b2); bf16 A / bf16 out ----------------
__global__ __launch_bounds__(256) void effn_mfma_k(
    const ush* __restrict__ A,
    const ush* __restrict__ W1T, size_t w1off, const void* __restrict__ b1, size_t b1off,
    const ush* __restrict__ W2T, size_t w2off, const void* __restrict__ b2, size_t b2off,
    const void* __restrict__ g, const void* __restrict__ be, size_t goff,
    ush* __restrict__ out, const int* __restrict__ flag)
{
    __shared__ __align__(16) ush w1t[128*40];
    __shared__ __align__(16) ush w2t[32*136];
    __shared__ __align__(16) ush hid[64*136];
    __shared__ float b1s[128], b2s[32];
    const int isbf = *flag;
    const int t = threadIdx.x;
    const int wave = t >> 6, l15 = t & 15, quad = (t >> 4) & 3;

    #pragma unroll
    for (int i = t; i < 1024; i += 256) {
        int n1 = i >> 3, k4 = (i & 7) * 4;
        *(ushort4*)&w1t[n1*40 + k4] = *(const ushort4*)&W1T[w1off + (size_t)n1*32 + k4];
        int n2 = i >> 5, kq2 = (i & 31) * 4;
        *(ushort4*)&w2t[n2*136 + kq2] = *(const ushort4*)&W2T[w2off + (size_t)n2*128 + kq2];
    }
    if (t < 128) b1s[t] = ldf(b1, b1off + t, isbf);
    if (t < 32)  b2s[t] = ldf(b2, b2off + t, isbf);
    __syncthreads();

    const float g0  = ldf(g,  goff + l15, isbf),      g1v = ldf(g,  goff + 16 + l15, isbf);
    const float be0 = ldf(be, goff + l15, isbf),      be1 = ldf(be, goff + 16 + l15, isbf);
    const float bb0 = b2s[l15], bb1 = b2s[16 + l15];

    for (int tt = 0; tt < 2; ++tt) {
        const int e0 = (blockIdx.x*2 + tt) * 64;
        {
            const int m = wave*16 + l15;
            frag_ab af = *(const frag_ab*)&A[(size_t)(e0+m)*32 + quad*8];
            #pragma unroll
            for (int nt = 0; nt < 8; ++nt) {
                frag_ab bf = *(const frag_ab*)&w1t[(nt*16 + l15)*40 + quad*8];
                frag_cd acc = {0.f, 0.f, 0.f, 0.f};
                acc = __builtin_amdgcn_mfma_f32_16x16x32_bf16(af, bf, acc, 0, 0, 0);
                float bv = b1s[nt*16 + l15];
                #pragma unroll
                for (int rg = 0; rg < 4; ++rg) {
                    int row = wave*16 + quad*4 + rg;
                    hid[row*136 + nt*16 + l15] = f2b(fmaxf(acc[rg] + bv, 0.f));
                }
            }
        }
        // hid rows are wave-private -> no barrier needed
        frag_cd acc2[2] = {{0.f,0.f,0.f,0.f},{0.f,0.f,0.f,0.f}};
        #pragma unroll
        for (int ks = 0; ks < 4; ++ks) {
            frag_ab af2 = *(const frag_ab*)&hid[(wave*16 + l15)*136 + ks*32 + quad*8];
            #pragma unroll
            for (int tl = 0; tl < 2; ++tl) {
                frag_ab bf2 = *(const frag_ab*)&w2t[(tl*16 + l15)*136 + ks*32 + quad*8];
                acc2[tl] = __builtin_amdgcn_mfma_f32_16x16x32_bf16(af2, bf2, acc2[tl], 0, 0, 0);
            }
        }
        #pragma unroll
        for (int rg = 0; rg < 4; ++rg) {
            const int row = e0 + wave*16 + quad*4 + rg;
            float v0 = acc2[0][rg] + bb0 + b2f(A[(size_t)row*32 + l15]);
            float v1 = acc2[1][rg] + bb1 + b2f(A[(size_t)row*32 + 16 + l15]);
            float s = v0 + v1;
            s += __shfl_xor(s,1); s += __shfl_xor(s,2); s += __shfl_xor(s,4); s += __shfl_xor(s,8);
            const float mean = s * (1.f/32.f);
            float q = (v0-mean)*(v0-mean) + (v1-mean)*(v1-mean);
            q += __shfl_xor(q,1); q += __shfl_xor(q,2); q += __shfl_xor(q,4); q += __shfl_xor(q,8);
            const float inv = rsqrtf(q * (1.f/32.f) + 1e-5f);
            out[(size_t)row*32 + l15]      = f2b((v0-mean)*inv*g0  + be0);
            out[(size_t)row*32 + 16 + l15] = f2b((v1-mean)*inv*g1v + be1);
        }
    }
}

// ---------------- full-graph attention: (b,h,quarter) blocks, 512 grid (online softmax) ----------------
// q: fp32 [4096][256]; kv: bf16 [4096][kKV], full head h: K at h*64, V at h*64+32
__global__ __launch_bounds__(512) void full_attn_k(
    const float* __restrict__ q, const ush* __restrict__ kv,
    const void* __restrict__ rel, const int* __restrict__ feat, ush* __restrict__ o,
    const int* __restrict__ flag)
{
    __shared__ __align__(8) ush ks[128][36];
    __shared__ __align__(8) ush vs[128][36];
    __shared__ __align__(8) ush rs[128][36];
    __shared__ float pb[8][32][34];            // per-wave partials: m, l, acc[32]
    const int isbf = *flag;
    const int bid = blockIdx.x;
    const int b = bid >> 4, h = (bid >> 2) & 3, qtr = bid & 3;
    const int t = threadIdx.x;
    for (int i = t; i < 4096; i += 512) {
        int r = i >> 5, d = i & 31;
        rs[r][d] = ldb(rel, i, isbf);
        const ush* kvrow = kv + (size_t)(b*128 + r)*kKV + h*64 + d;
        ks[r][d] = kvrow[0];
        vs[r][d] = kvrow[32];
    }
    __syncthreads();
    const int wave = t >> 6, lane = t & 63;
    const int dstL = lane >> 1, part = lane & 1;   // 2 lanes per dst
    const int dst = qtr*32 + dstL;
    const int dbase = part*16;                     // this lane's 16 dims
    float qr[16];
    { size_t base = ((size_t)(b*128 + dst))*256 + h*32 + dbase;
      #pragma unroll
      for (int d=0; d<16; ++d) qr[d] = q[base + d]; }
    const int* fp = feat + (size_t)b*16384 + dst;
    const int s0 = wave*16;
    float m = -1e30f, l = 0.f;
    float acc[16];
    #pragma unroll
    for (int d=0; d<16; ++d) acc[d] = 0.f;
    int f = fp[s0*128];
    for (int sI = 0; sI < 16; ++sI) {
        const int s = s0 + sI;
        int fn = (sI+1 < 16) ? fp[(s+1)*128] : 0;
        float er[16];
        float scp = 0.f;
        #pragma unroll
        for (int j2 = 0; j2 < 4; ++j2) {
            ushort4 eu = *(const ushort4*)&rs[f][dbase + j2*4];
            ushort4 ku = *(const ushort4*)&ks[s][dbase + j2*4];
            float e0 = b2f(eu.x), e1 = b2f(eu.y), e2 = b2f(eu.z), e3 = b2f(eu.w);
            er[j2*4+0]=e0; er[j2*4+1]=e1; er[j2*4+2]=e2; er[j2*4+3]=e3;
            scp += (b2f(ku.x)+e0)*qr[j2*4+0] + (b2f(ku.y)+e1)*qr[j2*4+1]
                 + (b2f(ku.z)+e2)*qr[j2*4+2] + (b2f(ku.w)+e3)*qr[j2*4+3];
        }
        const float sc = (scp + __shfl_xor(scp, 1)) * kScaleN;
        float mn = fmaxf(m, sc);
        float c0 = __expf(m - mn);
        float pp = __expf(sc - mn);
        l = l*c0 + pp;
        #pragma unroll
        for (int j2 = 0; j2 < 4; ++j2) {
            ushort4 vu = *(const ushort4*)&vs[s][dbase + j2*4];
            acc[j2*4+0] = acc[j2*4+0]*c0 + pp*(b2f(vu.x)+er[j2*4+0]);
            acc[j2*4+1] = acc[j2*4+1]*c0 + pp*(b2f(vu.y)+er[j2*4+1]);
            acc[j2*4+2] = acc[j2*4+2]*c0 + pp*(b2f(vu.z)+er[j2*4+2]);
            acc[j2*4+3] = acc[j2*4+3]*c0 + pp*(b2f(vu.w)+er[j2*4+3]);
        }
        m = mn; f = fn;
    }
    if (part == 0) { pb[wave][dstL][0] = m; pb[wave][dstL][1] = l; }
    #pragma unroll
    for (int d=0; d<16; ++d) pb[wave][dstL][2 + dbase + d] = acc[d];
    __syncthreads();
    // merge: thread (dstL2, grp) handles dims [grp*2, grp*2+2) of dst=qtr*32+dstL2
    {
        const int dstL2 = t & 31, grp = t >> 5;   // grp in [0,16)
        float mw[8], lw[8];
        #pragma unroll
        for (int w=0; w<8; ++w){ mw[w]=pb[w][dstL2][0]; lw[w]=pb[w][dstL2][1]; }
        float M = mw[0];
        #pragma unroll
        for (int w=1; w<8; ++w) M = fmaxf(M, mw[w]);
        float sw[8];
        float L = 0.f;
        #pragma unroll
        for (int w=0; w<8; ++w){ sw[w] = __expf(mw[w]-M); L += lw[w]*sw[w]; }
        const float inv = 1.f / fmaxf(L, 1e-30f);
        size_t base = ((size_t)(b*128 + qtr*32 + dstL2))*kND + h*32 + grp*2;
        #pragma unroll
        for (int d=0; d<2; ++d) {
            float a = 0.f;
            #pragma unroll
            for (int w=0; w<8; ++w) a += pb[w][dstL2][2+grp*2+d]*sw[w];
            o[base + d] = f2b(a*inv);
        }
    }
}

// ---------------- local-graph GATHER attention (heads 4..7), LDS-staged edge list ----------------
// kv: [4096][kKV] bf16: local head h (0..3): K at 256+h*64, V at 256+h*64+32 (adjacent)
__global__ __launch_bounds__(256) void loc_gather_k(
    const float* __restrict__ q, const ush* __restrict__ kv,
    const ush* __restrict__ lg, const int* __restrict__ gsrc,
    const int* __restrict__ rowp, const int* __restrict__ eidl,
    ush* __restrict__ o)
{
    __shared__ int eids[192], srcs[192];
    const int n = blockIdx.x;
    const int beg = rowp[n], end = rowp[n+1];
    const int deg = end - beg;
    {
        const int tc = threadIdx.x;
        const int dc = (deg < 192) ? deg : 192;
        if (tc < dc) { int e = eidl[beg + tc]; eids[tc] = e; srcs[tc] = gsrc[e]; }
    }
    __syncthreads();
    const int h = threadIdx.x >> 6;
    const int lane = threadIdx.x & 63;
    const int g = lane >> 4;
    const int d0 = (lane & 15) * 2;
    const size_t hoff = (size_t)(4 + h) * 32 + d0;
    const float2 q2 = *(const float2*)&q[(size_t)n*256 + hoff];
    float m = -1e30f, l = 0.f, ax = 0.f, ay = 0.f;
    if (deg > 0) {
        const int nIter = (deg + 3) >> 2;
        int idx = beg + g;
        for (int it = 0; it < nIter; ++it) {
            const bool valid = idx < end;
            const int ii = min(idx, end-1) - beg;
            int e, s;
            if (ii < 192) { e = eids[ii]; s = srcs[ii]; }
            else          { e = eidl[beg + ii]; s = gsrc[e]; }
            idx += 4;
            const ushort2 ku = *(const ushort2*)&kv[(size_t)s*kKV + 256 + h*64 + d0];
            const ushort2 lvu = *(const ushort2*)&lg[(size_t)e*32 + d0];
            const ushort2 vu = *(const ushort2*)&kv[(size_t)s*kKV + 256 + h*64 + 32 + d0];
            const float lvx = b2f(lvu.x), lvy = b2f(lvu.y);
            float part = (b2f(ku.x)+lvx)*q2.x + (b2f(ku.y)+lvy)*q2.y;
            part += __shfl_xor(part, 1);
            part += __shfl_xor(part, 2);
            part += __shfl_xor(part, 4);
            part += __shfl_xor(part, 8);
            const float sc = part * kScaleN;
            const float mn = valid ? fmaxf(m, sc) : m;
            const float c  = __expf(m - mn);
            const float pp = valid ? __expf(sc - mn) : 0.f;
            l  = l*c  + pp;
            ax = ax*c + pp*(b2f(vu.x)+lvx);
            ay = ay*c + pp*(b2f(vu.y)+lvy);
            m  = mn;
        }
        #pragma unroll
        for (int off = 16; off <= 32; off <<= 1) {
            const float mo = __shfl_xor(m, off);
            const float lo = __shfl_xor(l, off);
            const float xo = __shfl_xor(ax, off);
            const float yo = __shfl_xor(ay, off);
            const float M  = fmaxf(m, mo);
            const float c1 = __expf(m - M);
            const float c2 = __expf(mo - M);
            l  = l*c1  + lo*c2;
            ax = ax*c1 + xo*c2;
            ay = ay*c1 + yo*c2;
            m  = M;
        }
    }
    if (g == 0) {
        const float inv = 1.f / fmaxf(l, 1e-30f);
        *(ushort2*)&o[(size_t)n*kND + hoff] = make_ushort2(f2b(ax*inv), f2b(ay*inv));
    }
}

// ---------------- fused line-graph attention + Wo GEMM + LN (bf16 in/out) ----------------
// ekv: [el][64] interleaved; src indices LDS-staged (contiguous eid window per 32 dsts)
__global__ __launch_bounds__(256) void lgs_ewo_k(
    const ush* __restrict__ eq, const ush* __restrict__ ekv,
    const int* __restrict__ lsrc, const int* __restrict__ rowp, const int* __restrict__ eidl,
    const ush* __restrict__ res,
    const ush* __restrict__ WO, size_t wooff, const void* __restrict__ bo, size_t booff,
    const void* __restrict__ g1, const void* __restrict__ be1, size_t g1off,
    ush* __restrict__ out, const int* __restrict__ flag)
{
    __shared__ __align__(16) ush ows[32*40];
    __shared__ __align__(16) ush wos[32*40];
    __shared__ float cs[32][36];
    __shared__ float bos[32], gs[32], bs[32];
    __shared__ int srcs[256];
    const int isbf = *flag;
    const int t = threadIdx.x;
    const int base = blockIdx.x * 32;
    {
        int n = t >> 3, k4 = (t & 7) * 4;
        *(ushort4*)&wos[n*40 + k4] = *(const ushort4*)&WO[wooff + (size_t)n*32 + k4];
    }
    if (t < 32) {
        bos[t] = ldf(bo, booff + t, isbf);
        gs[t]  = ldf(g1, g1off + t, isbf);
        bs[t]  = ldf(be1, g1off + t, isbf);
    }
    // ---- stage src indices for this block's contiguous edge window ----
    const int beg0 = rowp[base];
    {
        int cnt = rowp[base + 32] - beg0;
        if (cnt > 256) cnt = 256;
        for (int j = t; j < cnt; j += 256) srcs[j] = lsrc[eidl[beg0 + j]];
    }
    __syncthreads();
    // ---- phase 1: gather attention, thread = (dst-edge, head) ----
    {
        const int d2 = base + (t >> 3), h = t & 7;
        const ushort4 qu = *(const ushort4*)&eq[(size_t)d2*32 + h*4];
        const float q0 = b2f(qu.x), q1 = b2f(qu.y), q2 = b2f(qu.z), q3 = b2f(qu.w);
        const int beg = rowp[d2], end = rowp[d2+1];
        float m = -1e30f, l = 0.f;
        float4 acc = make_float4(0.f,0.f,0.f,0.f);
        for (int i = beg; i < end; ++i) {
            const int io = i - beg0;
            const int s = (io < 256) ? srcs[io] : lsrc[eidl[i]];
            const uint4 kv8 = *(const uint4*)&ekv[(size_t)s*64 + h*8];   // k4|v4, 16B
            const ush k0 = (ush)(kv8.x & 0xffff), k1 = (ush)(kv8.x >> 16);
            const ush k2 = (ush)(kv8.y & 0xffff), k3 = (ush)(kv8.y >> 16);
            const ush v0u = (ush)(kv8.z & 0xffff), v1u = (ush)(kv8.z >> 16);
            const ush v2u = (ush)(kv8.w & 0xffff), v3u = (ush)(kv8.w >> 16);
            float sc = (b2f(k0)*q0 + b2f(k1)*q1 + b2f(k2)*q2 + b2f(k3)*q3) * 0.5f;
            float mn = fmaxf(m, sc);
            float c = __expf(m - mn);
            float pp = __expf(sc - mn);
            l = l*c + pp;
            acc.x = acc.x*c + pp*b2f(v0u);
            acc.y = acc.y*c + pp*b2f(v1u);
            acc.z = acc.z*c + pp*b2f(v2u);
            acc.w = acc.w*c + pp*b2f(v3u);
            m = mn;
        }
        const float inv = 1.f / fmaxf(l, 1e-30f);
        const int r = t >> 3, c0 = h*4;
        ows[r*40 + c0 + 0] = f2b(acc.x*inv);
        ows[r*40 + c0 + 1] = f2b(acc.y*inv);
        ows[r*40 + c0 + 2] = f2b(acc.z*inv);
        ows[r*40 + c0 + 3] = f2b(acc.w*inv);
    }
    __syncthreads();
    // ---- phase 2: 32x32 GEMM ----
    {
        const int wave = t >> 6, l15 = t & 15, quad = (t >> 4) & 3;
        const int mt = wave & 1, nt = wave >> 1;
        frag_ab af = *(const frag_ab*)&ows[(mt*16 + l15)*40 + quad*8];
        frag_ab bf = *(const frag_ab*)&wos[(nt*16 + l15)*40 + quad*8];
        frag_cd acc = {0.f, 0.f, 0.f, 0.f};
        acc = __builtin_amdgcn_mfma_f32_16x16x32_bf16(af, bf, acc, 0, 0, 0);
        #pragma unroll
        for (int rg = 0; rg < 4; ++rg) {
            const int row = mt*16 + quad*4 + rg;
            const int col = nt*16 + l15;
            cs[row][col] = acc[rg] + bos[col] + b2f(res[(size_t)(base+row)*32 + col]);
        }
    }
    __syncthreads();
    // ---- phase 3: LN per row ----
    {
        const int row = t >> 3, c0 = (t & 7) * 4;
        const float v0 = cs[row][c0], v1 = cs[row][c0+1];
        const float v2 = cs[row][c0+2], v3 = cs[row][c0+3];
        float s = v0+v1+v2+v3;
        s += __shfl_xor(s,1); s += __shfl_xor(s,2); s += __shfl_xor(s,4);
        const float mean = s * (1.f/32.f);
        float qq = (v0-mean)*(v0-mean)+(v1-mean)*(v1-mean)
                 + (v2-mean)*(v2-mean)+(v3-mean)*(v3-mean);
        qq += __shfl_xor(qq,1); qq += __shfl_xor(qq,2); qq += __shfl_xor(qq,4);
        const float inv = rsqrtf(qq * (1.f/32.f) + 1e-5f);
        out[(size_t)(base+row)*32 + c0 + 0] = f2b((v0-mean)*inv*gs[c0+0] + bs[c0+0]);
        out[(size_t)(base+row)*32 + c0 + 1] = f2b((v1-mean)*inv*gs[c0+1] + bs[c0+1]);
        out[(size_t)(base+row)*32 + c0 + 2] = f2b((v2-mean)*inv*gs[c0+2] + bs[c0+2]);
        out[(size_t)(base+row)*32 + c0 + 3] = f2b((v3-mean)*inv*gs[c0+3] + bs[c0+3]);
    }
}

// ---------------- output ----------------
__global__ void out_k(const float* __restrict__ xf, const ush* __restrict__ lgf,
                      void* __restrict__ out, const int* __restrict__ flag){
    const int isbf = *flag;
    int g = blockIdx.x*256 + threadIdx.x;
    if (g < kN*kND) {
        float v = xf[g];
        if (isbf) ((ush*)out)[g] = f2b(v);
        else      ((float*)out)[g] = v;
    } else {
        ush u = lgf[g - kN*kND];
        if (isbf) ((ush*)out)[g] = u;
        else      ((float*)out)[g] = b2f(u);
    }
}

// ---------------- host helper ----------------
static inline void mgemm(const float* A, const ush* WT, const void* bias, size_t boff,
                         float* C, const int* flag, int M, int N, int K, int flags,
                         hipStream_t s, ush* aux, ush* aux2, int splitz = 1){
    dim3 grid((N+63)/64, M/64, splitz);
    mgemm_k<<<grid, 256, 0, s>>>(A, WT, bias, boff, C, flag, M, N, K, flags, aux, aux2);
}

extern "C" void kernel_launch(void* const* d_in, const int* in_sizes, int n_in,
                              void* d_out, int out_size, void* d_ws, size_t ws_size,
                              hipStream_t stream) {
    const void* x_in      = d_in[0];
    const void* rel       = d_in[1];
    const int* g_src      = (const int*)d_in[4];
    const int* g_dst      = (const int*)d_in[5];
    const int* lg_src     = (const int*)d_in[6];
    const int* lg_dst     = (const int*)d_in[7];
    const int* edge_feat  = (const int*)d_in[8];
    const int* full_feat  = (const int*)d_in[9];
    const void* n_Wq   = d_in[10];
    const void* n_bq   = d_in[11];
    const void* n_Wk   = d_in[12];
    const void* n_bk   = d_in[13];
    const void* n_Wv   = d_in[14];
    const void* n_bv   = d_in[15];
    const void* n_Wo   = d_in[16];
    const void* n_bo   = d_in[17];
    const void* n_lng  = d_in[18];
    const void* n_lnb  = d_in[19];
    const void* n_fW1  = d_in[20];
    const void* n_fb1  = d_in[21];
    const void* n_fW2  = d_in[22];
    const void* n_fb2  = d_in[23];
    const void* n_flng = d_in[24];
    const void* n_flnb = d_in[25];
    const void* e_Wsrc = d_in[26];
    const void* e_Wdst = d_in[27];
    const void* e_Wq   = d_in[28];
    const void* e_bq   = d_in[29];
    const void* e_Wk   = d_in[30];
    const void* e_Wv   = d_in[31];
    const void* e_Wo   = d_in[32];
    const void* e_bo   = d_in[33];
    const void* e_lng  = d_in[34];
    const void* e_lnb  = d_in[35];
    const void* e_fW1  = d_in[36];
    const void* e_fb1  = d_in[37];
    const void* e_fW2  = d_in[38];
    const void* e_fb2  = d_in[39];
    const void* e_flng = d_in[40];
    const void* e_flnb = d_in[41];

    // ---- workspace carve-up (units: floats) ----
    float* p = (float*)d_ws;
    size_t off = 0;
    auto AL = [&](size_t n){ float* r = p + off; off += n; return r; };
    int* flagp = (int*)AL(64);
    float* xA   = AL((size_t)kN*kND);
    float* xB   = AL((size_t)kN*kND);
    float* xM   = AL((size_t)kN*kND);
    ush*   xAb  = (ush*)AL((size_t)kN*kND/2);
    ush*   xBb  = (ush*)AL((size_t)kN*kND/2);
    ush*   xMb  = (ush*)AL((size_t)kN*kND/2);
    float* qkvb = AL((size_t)kN*kND);            // fp32 Q only, [4096][256]
    ush*   kvaux= (ush*)AL((size_t)kN*kKV/2);    // bf16 [4096][512]: interleaved K/V
    ush*   xsdb = (ush*)AL((size_t)kN*32);       // bf16 [4096][64]: compact SD
    ush*   ob   = (ush*)AL((size_t)kN*kND/2);
    float* tN   = AL((size_t)kN*kND*2);          // (unused; kept for layout stability)
    ush*   nh   = (ush*)AL((size_t)kN*512);      // kN*1024 bf16
    ush*   lgA  = (ush*)AL((size_t)kEL*kED/2);   // bf16 edge residual chain
    ush*   lgB  = (ush*)AL((size_t)kEL*kED/2);
    ush*   lgM  = (ush*)AL((size_t)kEL*kED/2);
    ush*   eqb  = (ush*)AL((size_t)kEL*16);      // kEL*32 bf16
    ush*   ekvb = (ush*)AL((size_t)kEL*32);      // kEL*64 bf16 interleaved K/V
    // CSR structures
    int* cntL  = (int*)AL(kN);
    int* rowL  = (int*)AL(kN + 64);
    int* curL  = (int*)AL(kN);
    int* eidL  = (int*)AL(kEL);
    int* cntG  = (int*)AL(kEL);
    int* rowG  = (int*)AL(kEL + 64);
    int* curG  = (int*)AL(kEL);
    int* eidG  = (int*)AL(kELG);
    int* bsum  = (int*)AL(256);
    // pre-transposed bf16 weights
    ush* wtQKVSD = (ush*)AL(212992);   // [L][832][256] bf16 (425984 ush)
    float* bQKV  = AL(2*kQW);
    ush* wtO  = (ush*)AL(65536);
    ush* wtF1 = (ush*)AL(262144);
    ush* wtF2 = (ush*)AL(262144);
    ush* wtEQKV = (ush*)AL(3072);
    ush* wtEO   = (ush*)AL(1024);
    ush* wtEF1  = (ush*)AL(4096);
    ush* wtEF2  = (ush*)AL(4096);
    if (ws_size < off * sizeof(float)) return;

    detect_k<<<1, 64, 0, stream>>>((const ush*)x_in, flagp);
    {
        long total = (long)kN*kND + (long)kEL*kED + 2*kQW + kN + kEL;
        int blocks = (int)((total + 255) / 256);
        setup_misc_k<<<blocks, 256, 0, stream>>>(x_in, rel, edge_feat, n_bq, n_bk, n_bv,
                                                 xA, xAb, lgA, bQKV, cntL, cntG, flagp);
    }
    trans_tiled_k<<<1592, 256, 0, stream>>>(n_Wq, n_Wk, n_Wv, n_Wo, n_fW1, n_fW2,
                                            e_Wsrc, e_Wdst, e_Wq, e_Wk, e_Wv, e_Wo,
                                            e_fW1, e_fW2, flagp,
                                            wtQKVSD, wtO, wtF1, wtF2,
                                            wtEQKV, wtEO, wtEF1, wtEF2);

    count2_k<<<(kEL+kELG)/256, 256, 0, stream>>>(g_dst, lg_dst, cntL, cntG);
    scan_blk2_k<<<132, 256, 0, stream>>>(cntL, cntG, rowL, rowG, bsum);
    scan_top2_k<<<1, 256, 0, stream>>>(bsum);
    scan_add2_k<<<(kN+kEL)/256, 256, 0, stream>>>(rowL, rowG, bsum, curL, curG);
    fill2_k<<<(kEL+kELG)/256, 256, 0, stream>>>(g_dst, lg_dst, curL, curG, eidL, eidG);

    float* xc = xA;  float* xn = xB;
    ush* xcb = xAb;  ush* xnb = xBb;
    ush* lgc = lgA;  ush* lgn = lgB;
    (void)tN;

    for (int i = 0; i < kL; ++i) {
        const size_t o256 = (size_t)i*kND;
        const size_t o1024= (size_t)i*1024;
        const size_t o32  = (size_t)i*kED;
        const size_t o128 = (size_t)i*128;

        // ===== node update (fp32 Q + bf16 K/V + compact SD side-outputs) =====
        mgemm((const float*)xcb, wtQKVSD + (size_t)i*212992, bQKV, (size_t)i*kQW, qkvb,
              flagp, kN, kQW, kND, 4|16|32|64, stream, kvaux, xsdb);
        full_attn_k<<<512, 512, 0, stream>>>(qkvb, kvaux, rel, full_feat, ob, flagp);
        loc_gather_k<<<kN, 256, 0, stream>>>(qkvb, kvaux, lgc, g_src, rowL, eidL, ob);
        // fused Wo GEMM + residual + LN
        gemm_ln_k<<<kN/16, 256, 0, stream>>>(ob, wtO + (size_t)i*65536, n_bo, o256,
                                             xc, n_lng, n_lnb, o256, xM, xMb, flagp, kND);
        mgemm((const float*)xMb, wtF1 + (size_t)i*262144, n_fb1, o1024, (float*)nh, flagp,
              kN, 1024, kND, 4|2|8|32, stream, nullptr, nullptr);
        // fused F2 GEMM + residual + LN
        gemm_ln_k<<<kN/16, 256, 0, stream>>>(nh, wtF2 + (size_t)i*262144, n_fb2, o256,
                                             xM, n_flng, n_flnb, o256, xn, xnb, flagp, 1024);

        // ===== edge update (uses PRE-update xc, lgc) =====
        eqkv_mfma_k<<<kEL/128, 256, 0, stream>>>(lgc, xsdb, g_src, g_dst,
                                                 wtEQKV, (size_t)i*1024, e_bq, o32,
                                                 eqb, ekvb, flagp);
        lgs_ewo_k<<<kEL/32, 256, 0, stream>>>(eqb, ekvb, lg_src, rowG, eidG,
                                              lgc, wtEO, (size_t)i*1024, e_bo, o32,
                                              e_lng, e_lnb, o32, lgM, flagp);
        effn_mfma_k<<<kEL/128, 256, 0, stream>>>(lgM, wtEF1, (size_t)i*4096, e_fb1, o128,
                                                 wtEF2, (size_t)i*4096, e_fb2, o32,
                                                 e_flng, e_flnb, o32, lgn, flagp);

        { float* t = xc; xc = xn; xn = t; }
        { ush* t = xcb; xcb = xnb; xnb = t; }
        { ush* t = lgc; lgc = lgn; lgn = t; }
    }

    out_k<<<(kN*kND + kEL*kED)/256, 256, 0, stream>>>(xc, lgc, d_out, flagp);
}

// Round 21
// 512.851 us; speedup vs baseline: 1.0832x; 1.0832x over previous
//
#include <hip/hip_runtime.h>
#include <hip/hip_bf16.h>

typedef __hip_bfloat16 bf16;
typedef unsigned short ush;

static constexpr int kN   = 4096;    // nodes
static constexpr int kND  = 256;     // hidden
static constexpr int kEL  = 131072;  // local edges
static constexpr int kED  = 32;      // edge dim
static constexpr int kELG = 262144;  // line-graph edges
static constexpr int kL   = 2;
static constexpr int kQW  = 832;     // packed qkv+sd GEMM width
static constexpr int kKV  = 512;     // kvaux row stride (bf16), per-head interleaved K/V
static constexpr float kScaleN = 0.17677669529663687f; // 1/sqrt(32)

using frag_ab = __attribute__((ext_vector_type(8))) short;   // 8 bf16 (4 VGPRs)
using frag_cd = __attribute__((ext_vector_type(4))) float;   // 4 fp32

__device__ __forceinline__ float ldf(const void* p, size_t i, int isbf){
    return isbf ? __bfloat162float(((const bf16*)p)[i]) : ((const float*)p)[i];
}
__device__ __forceinline__ ush f2b(float f){ bf16 h = __float2bfloat16(f); return *(ush*)&h; }
__device__ __forceinline__ float b2f(ush u){ return __uint_as_float(((unsigned)u)<<16); }
__device__ __forceinline__ ush ldb(const void* p, size_t i, int isbf){
    return isbf ? ((const ush*)p)[i] : f2b(((const float*)p)[i]);
}

// ---------------- dtype detection (wave-parallel) ----------------
__global__ void detect_k(const ush* __restrict__ xin, int* __restrict__ flag){
    const int t = threadIdx.x;              // 64 threads
    int pl = 0;
    for (int i = t; i < 128; i += 64) {
        ush u = xin[i];
        int e = (u >> 7) & 0xFF;
        if (e == 0 || (e >= 110 && e <= 140)) ++pl;
    }
    #pragma unroll
    for (int off = 32; off > 0; off >>= 1) pl += __shfl_down(pl, off);
    if (t == 0) *flag = (pl >= 102) ? 1 : 0;
}

// ---------------- fused setup: cast x (f32+bf16), init lg (bf16), pack bias, zero counters ----------------
__global__ void setup_misc_k(const void* __restrict__ xin, const void* __restrict__ rel,
                             const int* __restrict__ feat,
                             const void* __restrict__ bq, const void* __restrict__ bk,
                             const void* __restrict__ bv,
                             float* __restrict__ xA, ush* __restrict__ xAb,
                             ush* __restrict__ lgA,
                             float* __restrict__ bQKV,
                             int* __restrict__ cntL, int* __restrict__ cntG,
                             const int* __restrict__ flag){
    const int isbf = *flag;
    long g = (long)blockIdx.x*256 + threadIdx.x;
    if (g < (long)kN*kND) {
        float v = ldf(xin, g, isbf);
        xA[g] = v; xAb[g] = f2b(v);
        return;
    }
    g -= (long)kN*kND;
    if (g < (long)kEL*kED) { int e = (int)(g >> 5), d = (int)(g & 31);
        lgA[g] = ldb(rel, (size_t)feat[e]*kED + d, isbf); return; }
    g -= (long)kEL*kED;
    if (g < 2*kQW) {
        int layer = (int)(g / kQW), j = (int)(g - (long)layer*kQW);
        float v = 0.f;
        if (j < 768) { int w = j >> 8, jj = j & 255;
            const void* B = (w==0)?bq:((w==1)?bk:bv);
            v = ldf(B, (size_t)layer*256 + jj, isbf); }
        bQKV[g] = v; return;
    }
    g -= 2*kQW;
    if (g < kN) { cntL[g] = 0; return; }
    g -= kN;
    if (g < kEL) { cntG[g] = 0; return; }
}

// ---------------- ALL weight pre-transposes: 32x32 LDS-tiled, coalesced both sides ----------------
__global__ __launch_bounds__(256) void trans_tiled_k(
    const void* __restrict__ nWq, const void* __restrict__ nWk, const void* __restrict__ nWv,
    const void* __restrict__ nWo, const void* __restrict__ nF1, const void* __restrict__ nF2,
    const void* __restrict__ eWs, const void* __restrict__ eWd,
    const void* __restrict__ eWq, const void* __restrict__ eWk, const void* __restrict__ eWv,
    const void* __restrict__ eWo, const void* __restrict__ eF1, const void* __restrict__ eF2,
    const int* __restrict__ flag,
    ush* __restrict__ wtQKVSD, ush* __restrict__ wtO, ush* __restrict__ wtF1,
    ush* __restrict__ wtF2, ush* __restrict__ wtEQKV, ush* __restrict__ wtEO,
    ush* __restrict__ wtEF1, ush* __restrict__ wtEF2)
{
    __shared__ ush lds[32][33];
    const int isbf = *flag;
    int idx = blockIdx.x;
    const void* src; size_t soff; ush* dstp; size_t doff;
    int Ns, Kd, r0, c0;
    if (idx < 384) {                                    // nWq/nWk/nWv [L][256][256] -> QKVSD rows 0-767
        int w = idx >> 7, rem = idx & 127;
        int layer = rem >> 6, tile = rem & 63;
        r0 = (tile >> 3) << 5; c0 = (tile & 7) << 5;
        src = (w==0)?nWq:((w==1)?nWk:nWv); soff = (size_t)layer*65536;
        Ns = 256; Kd = 256;
        dstp = wtQKVSD; doff = (size_t)layer*212992 + (size_t)w*65536;
    } else if ((idx -= 384) < 32) {                     // eWs/eWd [L][256][32] -> rows 768-831
        int w = idx >> 4, rem = idx & 15;
        int layer = rem >> 3, tile = rem & 7;
        r0 = tile << 5; c0 = 0;
        src = w ? eWd : eWs; soff = (size_t)layer*8192;
        Ns = 32; Kd = 256;
        dstp = wtQKVSD; doff = (size_t)layer*212992 + (size_t)(768 + w*32)*256;
    } else if ((idx -= 32) < 128) {                     // nWo [L][256][256]
        int layer = idx >> 6, tile = idx & 63;
        r0 = (tile >> 3) << 5; c0 = (tile & 7) << 5;
        src = nWo; soff = (size_t)layer*65536; Ns = 256; Kd = 256;
        dstp = wtO; doff = (size_t)layer*65536;
    } else if ((idx -= 128) < 512) {                    // nF1 [L][256][1024] -> [L][1024][256]
        int layer = idx >> 8, tile = idx & 255;
        r0 = (tile >> 5) << 5; c0 = (tile & 31) << 5;
        src = nF1; soff = (size_t)layer*262144; Ns = 1024; Kd = 256;
        dstp = wtF1; doff = (size_t)layer*262144;
    } else if ((idx -= 512) < 512) {                    // nF2 [L][1024][256] -> [L][256][1024]
        int layer = idx >> 8, tile = idx & 255;
        r0 = (tile >> 3) << 5; c0 = (tile & 7) << 5;
        src = nF2; soff = (size_t)layer*262144; Ns = 256; Kd = 1024;
        dstp = wtF2; doff = (size_t)layer*262144;
    } else if ((idx -= 512) < 6) {                      // eWq/eWk/eWv [L][32][32]
        int w = idx >> 1, layer = idx & 1;
        r0 = 0; c0 = 0;
        src = (w==0)?eWq:((w==1)?eWk:eWv); soff = (size_t)layer*1024; Ns = 32; Kd = 32;
        dstp = wtEQKV; doff = (size_t)(w*2 + layer)*1024;
    } else if ((idx -= 6) < 2) {                        // eWo [L][32][32]
        r0 = 0; c0 = 0;
        src = eWo; soff = (size_t)idx*1024; Ns = 32; Kd = 32;
        dstp = wtEO; doff = (size_t)idx*1024;
    } else if ((idx -= 2) < 8) {                        // eF1 [L][32][128] -> [L][128][32]
        int layer = idx >> 2, tile = idx & 3;
        r0 = 0; c0 = tile << 5;
        src = eF1; soff = (size_t)layer*4096; Ns = 128; Kd = 32;
        dstp = wtEF1; doff = (size_t)layer*4096;
    } else {                                            // eF2 [L][128][32] -> [L][32][128]
        idx -= 8;
        int layer = idx >> 2, tile = idx & 3;
        r0 = tile << 5; c0 = 0;
        src = eF2; soff = (size_t)layer*4096; Ns = 32; Kd = 128;
        dstp = wtEF2; doff = (size_t)layer*4096;
    }
    const int t = threadIdx.x;
    const int c = t & 31, rb = t >> 5;
    #pragma unroll
    for (int p = 0; p < 4; ++p) {
        int r = rb + p*8;
        lds[r][c] = ldb(src, soff + (size_t)(r0 + r)*Ns + c0 + c, isbf);
    }
    __syncthreads();
    #pragma unroll
    for (int p = 0; p < 4; ++p) {
        int rr = rb + p*8;
        dstp[doff + (size_t)(c0 + rr)*Kd + r0 + c] = lds[c][rr];
    }
}

// ---------------- CSR build (both graphs fused) ----------------
__global__ void count2_k(const int* __restrict__ gd, const int* __restrict__ lgd,
                         int* __restrict__ cntL, int* __restrict__ cntG){
    int g = blockIdx.x*256 + threadIdx.x;
    if (g < kEL) atomicAdd(&cntL[gd[g]], 1);
    else if (g < kEL + kELG) atomicAdd(&cntG[lgd[g - kEL]], 1);
}
__global__ __launch_bounds__(256) void scan_blk2_k(
    const int* __restrict__ cntL, const int* __restrict__ cntG,
    int* __restrict__ rowL, int* __restrict__ rowG, int* __restrict__ bsum)
{
    __shared__ int s[256];
    const int t = threadIdx.x;
    const bool isL = blockIdx.x < 4;
    const int* cnt = isL ? cntL : cntG;
    int* out = isL ? rowL : rowG;
    const int blk = isL ? blockIdx.x : blockIdx.x - 4;
    const int n = isL ? kN : kEL;
    const int b0 = blk*1024;
    int v[4], pre[4], tsum = 0;
    #pragma unroll
    for (int j=0;j<4;++j){
        int idx = b0 + t*4 + j;
        v[j] = (idx < n) ? cnt[idx] : 0;
        pre[j] = tsum; tsum += v[j];
    }
    s[t] = tsum; __syncthreads();
    for (int off=1; off<256; off<<=1){
        int x = (t>=off) ? s[t-off] : 0;
        __syncthreads();
        s[t] += x;
        __syncthreads();
    }
    int texc = s[t] - tsum;
    #pragma unroll
    for (int j=0;j<4;++j){
        int idx = b0 + t*4 + j;
        if (idx < n) out[idx] = texc + pre[j];
    }
    if (t == 255) bsum[(isL ? 0 : 8) + blk] = s[255];
}
__global__ __launch_bounds__(256) void scan_top2_k(int* __restrict__ bsum){
    __shared__ int sL[256], sG[256];
    const int t = threadIdx.x;
    int vL = (t < 4)   ? bsum[t]     : 0;
    int vG = (t < 128) ? bsum[8 + t] : 0;
    sL[t] = vL; sG[t] = vG; __syncthreads();
    for (int off=1; off<256; off<<=1){
        int xL = (t>=off) ? sL[t-off] : 0;
        int xG = (t>=off) ? sG[t-off] : 0;
        __syncthreads();
        sL[t] += xL; sG[t] += xG;
        __syncthreads();
    }
    if (t < 4)   bsum[t]     = sL[t] - vL;
    if (t < 128) bsum[8 + t] = sG[t] - vG;
}
__global__ void scan_add2_k(int* __restrict__ rowL, int* __restrict__ rowG,
                            const int* __restrict__ bsum,
                            int* __restrict__ curL, int* __restrict__ curG){
    int g = blockIdx.x*256 + threadIdx.x;
    if (g < kN){ int v = rowL[g] + bsum[g >> 10]; rowL[g] = v; curL[g] = v; }
    else if (g < kN + kEL){ int gg = g - kN;
        int v = rowG[gg] + bsum[8 + (gg >> 10)]; rowG[gg] = v; curG[gg] = v; }
    if (g == 0){ rowL[kN] = kEL; rowG[kEL] = kELG; }
}
__global__ void fill2_k(const int* __restrict__ gd, const int* __restrict__ lgd,
                        int* __restrict__ curL, int* __restrict__ curG,
                        int* __restrict__ eidL, int* __restrict__ eidG){
    int g = blockIdx.x*256 + threadIdx.x;
    if (g < kEL){ int pos = atomicAdd(&curL[gd[g]], 1); eidL[pos] = g; }
    else if (g < kEL + kELG){ int gg = g - kEL;
        int pos = atomicAdd(&curG[lgd[gg]], 1); eidG[pos] = gg; }
}

// ---------------- MFMA GEMM: C[M,N] = A@WT^T + bias (opt relu); BK=64 ----------------
// WT: bf16 [N][K]. 64x64 tile, 4 waves. Requires K%(64*gridDim.z)==0, N%64==0.
// flags: 2=RELU, 4=has-bias, 8=bf16 out, 16=bias packed fp32, 32=A is bf16,
//        64=QKV split output (col<256 -> fp32 C; 256-767 -> bf16 aux interleaved; 768+ -> aux2),
//        128=split-K over gridDim.z (bias by z==0 only; fp32 partials at C + z*M*N)
__global__ __launch_bounds__(256) void mgemm_k(
    const float* __restrict__ A, const ush* __restrict__ WT,
    const void* __restrict__ bias, size_t boff,
    float* __restrict__ C, const int* __restrict__ flag,
    int M, int N, int K, int flags, ush* __restrict__ aux, ush* __restrict__ aux2)
{
    __shared__ __align__(16) ush As[64*72];
    __shared__ __align__(16) ush Ws[64*72];
    const int isbf = *flag;
    const int t = threadIdx.x;
    const int m0 = blockIdx.y*64, n0 = blockIdx.x*64;
    const int wave = t>>6, lane = t&63;
    const int quad = lane>>4, l15 = lane&15;
    const int r = t>>3, kq = (t&7)*8;      // rows r and r+32, 8 K-elems at kq
    const bool abf = flags & 32;
    const bool spk = flags & 128;
    const int Kc   = spk ? (K / gridDim.z) : K;
    const int koff = spk ? (blockIdx.z * Kc) : 0;

    frag_cd acc[4];
    #pragma unroll
    for (int tl=0; tl<4; ++tl)
        #pragma unroll
        for (int j=0;j<4;++j) acc[tl][j] = 0.f;

    const float* ap0 = A + (size_t)(m0+r)*K + koff + kq;
    const float* ap1 = A + (size_t)(m0+r+32)*K + koff + kq;
    const ush*   ab0 = (const ush*)A + (size_t)(m0+r)*K + koff + kq;
    const ush*   ab1 = (const ush*)A + (size_t)(m0+r+32)*K + koff + kq;
    const ush*   wp0 = WT + (size_t)(n0+r)*K + koff + kq;
    const ush*   wp1 = WT + (size_t)(n0+r+32)*K + koff + kq;

    float4 a00,a01,a10,a11; uint4 av0,av1, wv0,wv1;
    auto loadT = [&](int kk){
        if (abf) { av0 = *(const uint4*)(ab0+kk); av1 = *(const uint4*)(ab1+kk); }
        else { a00 = *(const float4*)(ap0+kk); a01 = *(const float4*)(ap0+kk+4);
               a10 = *(const float4*)(ap1+kk); a11 = *(const float4*)(ap1+kk+4); }
        wv0 = *(const uint4*)(wp0+kk); wv1 = *(const uint4*)(wp1+kk);
    };
    loadT(0);

    for (int kk = 0; kk < Kc; kk += 64) {
        if (abf) {
            *(uint4*)&As[r*72 + kq]        = av0;
            *(uint4*)&As[(r+32)*72 + kq]   = av1;
        } else {
            *(ushort4*)&As[r*72 + kq]       = make_ushort4(f2b(a00.x),f2b(a00.y),f2b(a00.z),f2b(a00.w));
            *(ushort4*)&As[r*72 + kq + 4]   = make_ushort4(f2b(a01.x),f2b(a01.y),f2b(a01.z),f2b(a01.w));
            *(ushort4*)&As[(r+32)*72 + kq]     = make_ushort4(f2b(a10.x),f2b(a10.y),f2b(a10.z),f2b(a10.w));
            *(ushort4*)&As[(r+32)*72 + kq + 4] = make_ushort4(f2b(a11.x),f2b(a11.y),f2b(a11.z),f2b(a11.w));
        }
        *(uint4*)&Ws[r*72 + kq]      = wv0;
        *(uint4*)&Ws[(r+32)*72 + kq] = wv1;
        __syncthreads();
        if (kk + 64 < Kc) loadT(kk + 64);
        frag_ab af0 = *(const frag_ab*)&As[(wave*16 + l15)*72 + quad*8];
        frag_ab af1 = *(const frag_ab*)&As[(wave*16 + l15)*72 + 32 + quad*8];
        #pragma unroll
        for (int tl = 0; tl < 4; ++tl) {
            frag_ab bf0 = *(const frag_ab*)&Ws[(tl*16 + l15)*72 + quad*8];
            acc[tl] = __builtin_amdgcn_mfma_f32_16x16x32_bf16(af0, bf0, acc[tl], 0, 0, 0);
            frag_ab bf1 = *(const frag_ab*)&Ws[(tl*16 + l15)*72 + 32 + quad*8];
            acc[tl] = __builtin_amdgcn_mfma_f32_16x16x32_bf16(af1, bf1, acc[tl], 0, 0, 0);
        }
        __syncthreads();
    }
    const bool do_relu = flags & 2;
    const bool has_b   = (flags & 4) && (!spk || blockIdx.z == 0);
    const bool obf     = flags & 8;
    float* Cz = spk ? (C + (size_t)blockIdx.z * M * N) : C;
    #pragma unroll
    for (int tl = 0; tl < 4; ++tl) {
        int col = n0 + tl*16 + l15;
        float bv = 0.f;
        if (has_b) bv = (flags & 16) ? ((const float*)bias)[boff + col]
                                     : ldf(bias, boff + col, isbf);
        // kvaux/xsd column mapping for QKV split output:
        int adst = -1; bool tox = false;
        if (flags & 64 && col >= 256) {
            int c = col - 256;
            if (c < 512) {
                int isv = c >> 8;            // 0 = K, 1 = V
                int cc = c & 255;
                int h = cc >> 5, d = cc & 31;
                int base = (h < 4) ? h*64 : 256 + (h-4)*64;
                adst = base + isv*32 + d;
            } else { adst = c - 512; tox = true; }   // SD -> compact xsd [row][64]
        }
        #pragma unroll
        for (int rg = 0; rg < 4; ++rg) {
            int row = m0 + wave*16 + quad*4 + rg;
            float v = acc[tl][rg] + bv;
            if (do_relu) v = fmaxf(v, 0.f);
            if (flags & 64) {
                if (col < 256)  C[(size_t)row*256 + col] = v;
                else if (tox)   aux2[(size_t)row*64 + adst] = f2b(v);
                else            aux[(size_t)row*kKV + adst] = f2b(v);
            } else if (obf) ((ush*)C)[(size_t)row*N + col] = f2b(v);
            else            Cz[(size_t)row*N + col] = v;
        }
    }
}

// ---------------- LayerNorm (node rows, D=256): out = LN(a + b [+ b2]), dual f32+bf16 ----------------
// 4 rows/block, wave per row. b2 nullable (split-K second partial).
__global__ __launch_bounds__(256) void ln_k(
    const float* __restrict__ a, const float* __restrict__ b, const float* __restrict__ b2,
    const void* __restrict__ g, const void* __restrict__ be, size_t goff,
    float* __restrict__ out, ush* __restrict__ outb,
    const int* __restrict__ flag, int D)
{
    const int isbf = *flag;
    const int row = blockIdx.x*4 + (threadIdx.x >> 6);
    const int t = threadIdx.x & 63;
    float v[4];
    int cnt = 0;
    float s = 0.f;
    for (int i = t; i < D; i += 64) {
        float x = a[(size_t)row*D + i];
        if (b)  x += b[(size_t)row*D + i];
        if (b2) x += b2[(size_t)row*D + i];
        v[cnt++] = x; s += x;
    }
    #pragma unroll
    for (int off = 32; off > 0; off >>= 1) s += __shfl_down(s, off);
    s = __shfl(s, 0);
    const float mean = s / D;
    float qq = 0.f;
    for (int c2 = 0; c2 < cnt; ++c2) { float d = v[c2]-mean; qq += d*d; }
    #pragma unroll
    for (int off = 32; off > 0; off >>= 1) qq += __shfl_down(qq, off);
    qq = __shfl(qq, 0);
    const float inv = rsqrtf(fmaxf(qq, 0.f) / D + 1e-5f);
    cnt = 0;
    for (int i = t; i < D; i += 64) {
        float r = (v[cnt++] - mean)*inv*ldf(g, goff + i, isbf) + ldf(be, goff + i, isbf);
        out[(size_t)row*D + i] = r;
        outb[(size_t)row*D + i] = f2b(r);
    }
}

// ---------------- MFMA eq/ekv (+gathered mixed), 128 rows/block, bf16 in/out ----------------
// xsd: compact [4096][64] bf16 (src at 0-31, dst at 32-63). Vectorized staging.
// Output: eq [el][32]; ekv [el][64] interleaved (k_h at h*8, v_h at h*8+4).
__global__ __launch_bounds__(256) void eqkv_mfma_k(
    const ush* __restrict__ lg, const ush* __restrict__ xsd,
    const int* __restrict__ gsrc, const int* __restrict__ gdst,
    const ush* __restrict__ WQKV, size_t woff,
    const void* __restrict__ bq, size_t boff,
    ush* __restrict__ eq, ush* __restrict__ ekv,
    const int* __restrict__ flag)
{
    __shared__ __align__(16) ush mixs[128*40];
    __shared__ __align__(16) ush wts[3][32*40];
    __shared__ float bqs[32];
    const int isbf = *flag;
    const int t = threadIdx.x;
    const int e0 = blockIdx.x * 128;
    #pragma unroll
    for (int i = t; i < 768; i += 256) {
        int m = i >> 8, r2 = i & 255;
        int n = r2 >> 3, k4 = (r2 & 7) * 4;
        *(ushort4*)&wts[m][n*40 + k4] =
            *(const ushort4*)&WQKV[(size_t)m*2048 + woff + (size_t)n*32 + k4];
    }
    if (t < 32) bqs[t] = ldf(bq, boff + t, isbf);
    {
        int r = t >> 1, c0 = (t & 1) * 16;
        int e = e0 + r;
        int s = gsrc[e], d2 = gdst[e];
        const ush* lp = lg  + (size_t)e*32  + c0;
        const ush* sp = xsd + (size_t)s*64  + c0;
        const ush* dp = xsd + (size_t)d2*64 + 32 + c0;
        uint4 lv0 = *(const uint4*)lp,     lv1 = *(const uint4*)(lp+8);
        uint4 sv0 = *(const uint4*)sp,     sv1 = *(const uint4*)(sp+8);
        uint4 dv0 = *(const uint4*)dp,     dv1 = *(const uint4*)(dp+8);
        auto pk = [](unsigned a, unsigned b, unsigned c)->unsigned {
            ush lo = f2b(b2f((ush)(a & 0xffff)) + b2f((ush)(b & 0xffff)) + b2f((ush)(c & 0xffff)));
            ush hi = f2b(b2f((ush)(a >> 16))    + b2f((ush)(b >> 16))    + b2f((ush)(c >> 16)));
            return (unsigned)lo | ((unsigned)hi << 16);
        };
        uint4 o0, o1;
        o0.x = pk(lv0.x, sv0.x, dv0.x); o0.y = pk(lv0.y, sv0.y, dv0.y);
        o0.z = pk(lv0.z, sv0.z, dv0.z); o0.w = pk(lv0.w, sv0.w, dv0.w);
        o1.x = pk(lv1.x, sv1.x, dv1.x); o1.y = pk(lv1.y, sv1.y, dv1.y);
        o1.z = pk(lv1.z, sv1.z, dv1.z); o1.w = pk(lv1.w, sv1.w, dv1.w);
        *(uint4*)&mixs[r*40 + c0]     = o0;
        *(uint4*)&mixs[r*40 + c0 + 8] = o1;
    }
    __syncthreads();
    const int wave = t >> 6, l15 = t & 15, quad = (t >> 4) & 3;
    #pragma unroll
    for (int mi = 0; mi < 2; ++mi) {
        const int mt = wave*2 + mi;
        frag_ab af = *(const frag_ab*)&mixs[(mt*16 + l15)*40 + quad*8];
        #pragma unroll
        for (int w = 0; w < 3; ++w) {
            #pragma unroll
            for (int nt = 0; nt < 2; ++nt) {
                frag_ab bf = *(const frag_ab*)&wts[w][(nt*16 + l15)*40 + quad*8];
                frag_cd acc = {0.f, 0.f, 0.f, 0.f};
                acc = __builtin_amdgcn_mfma_f32_16x16x32_bf16(af, bf, acc, 0, 0, 0);
                const float bv = (w==0) ? bqs[nt*16 + l15] : 0.f;
                const int col = nt*16 + l15;            // 0..31
                const int h = col >> 2, d = col & 3;
                #pragma unroll
                for (int rg = 0; rg < 4; ++rg) {
                    int row = e0 + mt*16 + quad*4 + rg;
                    float v = acc[rg] + bv;
                    if (w == 0)      eq[(size_t)row*32 + col] = f2b(v);
                    else if (w == 1) ekv[(size_t)row*64 + h*8 + d] = f2b(v);
                    else             ekv[(size_t)row*64 + h*8 + 4 + d] = f2b(v);
                }
            }
        }
    }
}

// ---------------- MFMA edge FFN: LN(A + relu(A@W1+b1)@W2 + b2); bf16 A / bf16 out ----------------
__global__ __launch_bounds__(256) void effn_mfma_k(
    const ush* __restrict__ A,
    const ush* __restrict__ W1T, size_t w1off, const void* __restrict__ b1, size_t b1off,
    const ush* __restrict__ W2T, size_t w2off, const void* __restrict__ b2, size_t b2off,
    const void* __restrict__ g, const void* __restrict__ be, size_t goff,
    ush* __restrict__ out, const int* __restrict__ flag)
{
    __shared__ __align__(16) ush w1t[128*40];
    __shared__ __align__(16) ush w2t[32*136];
    __shared__ __align__(16) ush hid[64*136];
    __shared__ float b1s[128], b2s[32];
    const int isbf = *flag;
    const int t = threadIdx.x;
    const int wave = t >> 6, l15 = t & 15, quad = (t >> 4) & 3;

    #pragma unroll
    for (int i = t; i < 1024; i += 256) {
        int n1 = i >> 3, k4 = (i & 7) * 4;
        *(ushort4*)&w1t[n1*40 + k4] = *(const ushort4*)&W1T[w1off + (size_t)n1*32 + k4];
        int n2 = i >> 5, kq2 = (i & 31) * 4;
        *(ushort4*)&w2t[n2*136 + kq2] = *(const ushort4*)&W2T[w2off + (size_t)n2*128 + kq2];
    }
    if (t < 128) b1s[t] = ldf(b1, b1off + t, isbf);
    if (t < 32)  b2s[t] = ldf(b2, b2off + t, isbf);
    __syncthreads();

    const float g0  = ldf(g,  goff + l15, isbf),      g1v = ldf(g,  goff + 16 + l15, isbf);
    const float be0 = ldf(be, goff + l15, isbf),      be1 = ldf(be, goff + 16 + l15, isbf);
    const float bb0 = b2s[l15], bb1 = b2s[16 + l15];

    for (int tt = 0; tt < 2; ++tt) {
        const int e0 = (blockIdx.x*2 + tt) * 64;
        {
            const int m = wave*16 + l15;
            frag_ab af = *(const frag_ab*)&A[(size_t)(e0+m)*32 + quad*8];
            #pragma unroll
            for (int nt = 0; nt < 8; ++nt) {
                frag_ab bf = *(const frag_ab*)&w1t[(nt*16 + l15)*40 + quad*8];
                frag_cd acc = {0.f, 0.f, 0.f, 0.f};
                acc = __builtin_amdgcn_mfma_f32_16x16x32_bf16(af, bf, acc, 0, 0, 0);
                float bv = b1s[nt*16 + l15];
                #pragma unroll
                for (int rg = 0; rg < 4; ++rg) {
                    int row = wave*16 + quad*4 + rg;
                    hid[row*136 + nt*16 + l15] = f2b(fmaxf(acc[rg] + bv, 0.f));
                }
            }
        }
        // hid rows are wave-private -> no barrier needed
        frag_cd acc2[2] = {{0.f,0.f,0.f,0.f},{0.f,0.f,0.f,0.f}};
        #pragma unroll
        for (int ks = 0; ks < 4; ++ks) {
            frag_ab af2 = *(const frag_ab*)&hid[(wave*16 + l15)*136 + ks*32 + quad*8];
            #pragma unroll
            for (int tl = 0; tl < 2; ++tl) {
                frag_ab bf2 = *(const frag_ab*)&w2t[(tl*16 + l15)*136 + ks*32 + quad*8];
                acc2[tl] = __builtin_amdgcn_mfma_f32_16x16x32_bf16(af2, bf2, acc2[tl], 0, 0, 0);
            }
        }
        #pragma unroll
        for (int rg = 0; rg < 4; ++rg) {
            const int row = e0 + wave*16 + quad*4 + rg;
            float v0 = acc2[0][rg] + bb0 + b2f(A[(size_t)row*32 + l15]);
            float v1 = acc2[1][rg] + bb1 + b2f(A[(size_t)row*32 + 16 + l15]);
            float s = v0 + v1;
            s += __shfl_xor(s,1); s += __shfl_xor(s,2); s += __shfl_xor(s,4); s += __shfl_xor(s,8);
            const float mean = s * (1.f/32.f);
            float q = (v0-mean)*(v0-mean) + (v1-mean)*(v1-mean);
            q += __shfl_xor(q,1); q += __shfl_xor(q,2); q += __shfl_xor(q,4); q += __shfl_xor(q,8);
            const float inv = rsqrtf(q * (1.f/32.f) + 1e-5f);
            out[(size_t)row*32 + l15]      = f2b((v0-mean)*inv*g0  + be0);
            out[(size_t)row*32 + 16 + l15] = f2b((v1-mean)*inv*g1v + be1);
        }
    }
}

// ---------------- full-graph attention: (b,h,quarter) blocks, 512 grid (online softmax) ----------------
// q: fp32 [4096][256]; kv: bf16 [4096][kKV], full head h: K at h*64, V at h*64+32
__global__ __launch_bounds__(512) void full_attn_k(
    const float* __restrict__ q, const ush* __restrict__ kv,
    const void* __restrict__ rel, const int* __restrict__ feat, ush* __restrict__ o,
    const int* __restrict__ flag)
{
    __shared__ __align__(8) ush ks[128][36];
    __shared__ __align__(8) ush vs[128][36];
    __shared__ __align__(8) ush rs[128][36];
    __shared__ float pb[8][32][34];            // per-wave partials: m, l, acc[32]
    const int isbf = *flag;
    const int bid = blockIdx.x;
    const int b = bid >> 4, h = (bid >> 2) & 3, qtr = bid & 3;
    const int t = threadIdx.x;
    for (int i = t; i < 4096; i += 512) {
        int r = i >> 5, d = i & 31;
        rs[r][d] = ldb(rel, i, isbf);
        const ush* kvrow = kv + (size_t)(b*128 + r)*kKV + h*64 + d;
        ks[r][d] = kvrow[0];
        vs[r][d] = kvrow[32];
    }
    __syncthreads();
    const int wave = t >> 6, lane = t & 63;
    const int dstL = lane >> 1, part = lane & 1;   // 2 lanes per dst
    const int dst = qtr*32 + dstL;
    const int dbase = part*16;                     // this lane's 16 dims
    float qr[16];
    { size_t base = ((size_t)(b*128 + dst))*256 + h*32 + dbase;
      #pragma unroll
      for (int d=0; d<16; ++d) qr[d] = q[base + d]; }
    const int* fp = feat + (size_t)b*16384 + dst;
    const int s0 = wave*16;
    float m = -1e30f, l = 0.f;
    float acc[16];
    #pragma unroll
    for (int d=0; d<16; ++d) acc[d] = 0.f;
    int f = fp[s0*128];
    for (int sI = 0; sI < 16; ++sI) {
        const int s = s0 + sI;
        int fn = (sI+1 < 16) ? fp[(s+1)*128] : 0;
        float er[16];
        float scp = 0.f;
        #pragma unroll
        for (int j2 = 0; j2 < 4; ++j2) {
            ushort4 eu = *(const ushort4*)&rs[f][dbase + j2*4];
            ushort4 ku = *(const ushort4*)&ks[s][dbase + j2*4];
            float e0 = b2f(eu.x), e1 = b2f(eu.y), e2 = b2f(eu.z), e3 = b2f(eu.w);
            er[j2*4+0]=e0; er[j2*4+1]=e1; er[j2*4+2]=e2; er[j2*4+3]=e3;
            scp += (b2f(ku.x)+e0)*qr[j2*4+0] + (b2f(ku.y)+e1)*qr[j2*4+1]
                 + (b2f(ku.z)+e2)*qr[j2*4+2] + (b2f(ku.w)+e3)*qr[j2*4+3];
        }
        const float sc = (scp + __shfl_xor(scp, 1)) * kScaleN;
        float mn = fmaxf(m, sc);
        float c0 = __expf(m - mn);
        float pp = __expf(sc - mn);
        l = l*c0 + pp;
        #pragma unroll
        for (int j2 = 0; j2 < 4; ++j2) {
            ushort4 vu = *(const ushort4*)&vs[s][dbase + j2*4];
            acc[j2*4+0] = acc[j2*4+0]*c0 + pp*(b2f(vu.x)+er[j2*4+0]);
            acc[j2*4+1] = acc[j2*4+1]*c0 + pp*(b2f(vu.y)+er[j2*4+1]);
            acc[j2*4+2] = acc[j2*4+2]*c0 + pp*(b2f(vu.z)+er[j2*4+2]);
            acc[j2*4+3] = acc[j2*4+3]*c0 + pp*(b2f(vu.w)+er[j2*4+3]);
        }
        m = mn; f = fn;
    }
    if (part == 0) { pb[wave][dstL][0] = m; pb[wave][dstL][1] = l; }
    #pragma unroll
    for (int d=0; d<16; ++d) pb[wave][dstL][2 + dbase + d] = acc[d];
    __syncthreads();
    // merge: thread (dstL2, grp) handles dims [grp*2, grp*2+2) of dst=qtr*32+dstL2
    {
        const int dstL2 = t & 31, grp = t >> 5;   // grp in [0,16)
        float mw[8], lw[8];
        #pragma unroll
        for (int w=0; w<8; ++w){ mw[w]=pb[w][dstL2][0]; lw[w]=pb[w][dstL2][1]; }
        float M = mw[0];
        #pragma unroll
        for (int w=1; w<8; ++w) M = fmaxf(M, mw[w]);
        float sw[8];
        float L = 0.f;
        #pragma unroll
        for (int w=0; w<8; ++w){ sw[w] = __expf(mw[w]-M); L += lw[w]*sw[w]; }
        const float inv = 1.f / fmaxf(L, 1e-30f);
        size_t base = ((size_t)(b*128 + qtr*32 + dstL2))*kND + h*32 + grp*2;
        #pragma unroll
        for (int d=0; d<2; ++d) {
            float a = 0.f;
            #pragma unroll
            for (int w=0; w<8; ++w) a += pb[w][dstL2][2+grp*2+d]*sw[w];
            o[base + d] = f2b(a*inv);
        }
    }
}

// ---------------- local-graph GATHER attention (heads 4..7), LDS-staged edge list ----------------
// kv: [4096][kKV] bf16: local head h (0..3): K at 256+h*64, V at 256+h*64+32 (adjacent)
__global__ __launch_bounds__(256) void loc_gather_k(
    const float* __restrict__ q, const ush* __restrict__ kv,
    const ush* __restrict__ lg, const int* __restrict__ gsrc,
    const int* __restrict__ rowp, const int* __restrict__ eidl,
    ush* __restrict__ o)
{
    __shared__ int eids[192], srcs[192];
    const int n = blockIdx.x;
    const int beg = rowp[n], end = rowp[n+1];
    const int deg = end - beg;
    {
        const int tc = threadIdx.x;
        const int dc = (deg < 192) ? deg : 192;
        if (tc < dc) { int e = eidl[beg + tc]; eids[tc] = e; srcs[tc] = gsrc[e]; }
    }
    __syncthreads();
    const int h = threadIdx.x >> 6;
    const int lane = threadIdx.x & 63;
    const int g = lane >> 4;
    const int d0 = (lane & 15) * 2;
    const size_t hoff = (size_t)(4 + h) * 32 + d0;
    const float2 q2 = *(const float2*)&q[(size_t)n*256 + hoff];
    float m = -1e30f, l = 0.f, ax = 0.f, ay = 0.f;
    if (deg > 0) {
        const int nIter = (deg + 3) >> 2;
        int idx = beg + g;
        for (int it = 0; it < nIter; ++it) {
            const bool valid = idx < end;
            const int ii = min(idx, end-1) - beg;
            int e, s;
            if (ii < 192) { e = eids[ii]; s = srcs[ii]; }
            else          { e = eidl[beg + ii]; s = gsrc[e]; }
            idx += 4;
            const ushort2 ku = *(const ushort2*)&kv[(size_t)s*kKV + 256 + h*64 + d0];
            const ushort2 lvu = *(const ushort2*)&lg[(size_t)e*32 + d0];
            const ushort2 vu = *(const ushort2*)&kv[(size_t)s*kKV + 256 + h*64 + 32 + d0];
            const float lvx = b2f(lvu.x), lvy = b2f(lvu.y);
            float part = (b2f(ku.x)+lvx)*q2.x + (b2f(ku.y)+lvy)*q2.y;
            part += __shfl_xor(part, 1);
            part += __shfl_xor(part, 2);
            part += __shfl_xor(part, 4);
            part += __shfl_xor(part, 8);
            const float sc = part * kScaleN;
            const float mn = valid ? fmaxf(m, sc) : m;
            const float c  = __expf(m - mn);
            const float pp = valid ? __expf(sc - mn) : 0.f;
            l  = l*c  + pp;
            ax = ax*c + pp*(b2f(vu.x)+lvx);
            ay = ay*c + pp*(b2f(vu.y)+lvy);
            m  = mn;
        }
        #pragma unroll
        for (int off = 16; off <= 32; off <<= 1) {
            const float mo = __shfl_xor(m, off);
            const float lo = __shfl_xor(l, off);
            const float xo = __shfl_xor(ax, off);
            const float yo = __shfl_xor(ay, off);
            const float M  = fmaxf(m, mo);
            const float c1 = __expf(m - M);
            const float c2 = __expf(mo - M);
            l  = l*c1  + lo*c2;
            ax = ax*c1 + xo*c2;
            ay = ay*c1 + yo*c2;
            m  = M;
        }
    }
    if (g == 0) {
        const float inv = 1.f / fmaxf(l, 1e-30f);
        *(ushort2*)&o[(size_t)n*kND + hoff] = make_ushort2(f2b(ax*inv), f2b(ay*inv));
    }
}

// ---------------- fused line-graph attention + Wo GEMM + LN (bf16 in/out) ----------------
// ekv: [el][64] interleaved; src indices LDS-staged (contiguous eid window per 32 dsts)
__global__ __launch_bounds__(256) void lgs_ewo_k(
    const ush* __restrict__ eq, const ush* __restrict__ ekv,
    const int* __restrict__ lsrc, const int* __restrict__ rowp, const int* __restrict__ eidl,
    const ush* __restrict__ res,
    const ush* __restrict__ WO, size_t wooff, const void* __restrict__ bo, size_t booff,
    const void* __restrict__ g1, const void* __restrict__ be1, size_t g1off,
    ush* __restrict__ out, const int* __restrict__ flag)
{
    __shared__ __align__(16) ush ows[32*40];
    __shared__ __align__(16) ush wos[32*40];
    __shared__ float cs[32][36];
    __shared__ float bos[32], gs[32], bs[32];
    __shared__ int srcs[256];
    const int isbf = *flag;
    const int t = threadIdx.x;
    const int base = blockIdx.x * 32;
    {
        int n = t >> 3, k4 = (t & 7) * 4;
        *(ushort4*)&wos[n*40 + k4] = *(const ushort4*)&WO[wooff + (size_t)n*32 + k4];
    }
    if (t < 32) {
        bos[t] = ldf(bo, booff + t, isbf);
        gs[t]  = ldf(g1, g1off + t, isbf);
        bs[t]  = ldf(be1, g1off + t, isbf);
    }
    // ---- stage src indices for this block's contiguous edge window ----
    const int beg0 = rowp[base];
    {
        int cnt = rowp[base + 32] - beg0;
        if (cnt > 256) cnt = 256;
        for (int j = t; j < cnt; j += 256) srcs[j] = lsrc[eidl[beg0 + j]];
    }
    __syncthreads();
    // ---- phase 1: gather attention, thread = (dst-edge, head) ----
    {
        const int d2 = base + (t >> 3), h = t & 7;
        const ushort4 qu = *(const ushort4*)&eq[(size_t)d2*32 + h*4];
        const float q0 = b2f(qu.x), q1 = b2f(qu.y), q2 = b2f(qu.z), q3 = b2f(qu.w);
        const int beg = rowp[d2], end = rowp[d2+1];
        float m = -1e30f, l = 0.f;
        float4 acc = make_float4(0.f,0.f,0.f,0.f);
        for (int i = beg; i < end; ++i) {
            const int io = i - beg0;
            const int s = (io < 256) ? srcs[io] : lsrc[eidl[i]];
            const uint4 kv8 = *(const uint4*)&ekv[(size_t)s*64 + h*8];   // k4|v4, 16B
            const ush k0 = (ush)(kv8.x & 0xffff), k1 = (ush)(kv8.x >> 16);
            const ush k2 = (ush)(kv8.y & 0xffff), k3 = (ush)(kv8.y >> 16);
            const ush v0u = (ush)(kv8.z & 0xffff), v1u = (ush)(kv8.z >> 16);
            const ush v2u = (ush)(kv8.w & 0xffff), v3u = (ush)(kv8.w >> 16);
            float sc = (b2f(k0)*q0 + b2f(k1)*q1 + b2f(k2)*q2 + b2f(k3)*q3) * 0.5f;
            float mn = fmaxf(m, sc);
            float c = __expf(m - mn);
            float pp = __expf(sc - mn);
            l = l*c + pp;
            acc.x = acc.x*c + pp*b2f(v0u);
            acc.y = acc.y*c + pp*b2f(v1u);
            acc.z = acc.z*c + pp*b2f(v2u);
            acc.w = acc.w*c + pp*b2f(v3u);
            m = mn;
        }
        const float inv = 1.f / fmaxf(l, 1e-30f);
        const int r = t >> 3, c0 = h*4;
        ows[r*40 + c0 + 0] = f2b(acc.x*inv);
        ows[r*40 + c0 + 1] = f2b(acc.y*inv);
        ows[r*40 + c0 + 2] = f2b(acc.z*inv);
        ows[r*40 + c0 + 3] = f2b(acc.w*inv);
    }
    __syncthreads();
    // ---- phase 2: 32x32 GEMM ----
    {
        const int wave = t >> 6, l15 = t & 15, quad = (t >> 4) & 3;
        const int mt = wave & 1, nt = wave >> 1;
        frag_ab af = *(const frag_ab*)&ows[(mt*16 + l15)*40 + quad*8];
        frag_ab bf = *(const frag_ab*)&wos[(nt*16 + l15)*40 + quad*8];
        frag_cd acc = {0.f, 0.f, 0.f, 0.f};
        acc = __builtin_amdgcn_mfma_f32_16x16x32_bf16(af, bf, acc, 0, 0, 0);
        #pragma unroll
        for (int rg = 0; rg < 4; ++rg) {
            const int row = mt*16 + quad*4 + rg;
            const int col = nt*16 + l15;
            cs[row][col] = acc[rg] + bos[col] + b2f(res[(size_t)(base+row)*32 + col]);
        }
    }
    __syncthreads();
    // ---- phase 3: LN per row ----
    {
        const int row = t >> 3, c0 = (t & 7) * 4;
        const float v0 = cs[row][c0], v1 = cs[row][c0+1];
        const float v2 = cs[row][c0+2], v3 = cs[row][c0+3];
        float s = v0+v1+v2+v3;
        s += __shfl_xor(s,1); s += __shfl_xor(s,2); s += __shfl_xor(s,4);
        const float mean = s * (1.f/32.f);
        float qq = (v0-mean)*(v0-mean)+(v1-mean)*(v1-mean)
                 + (v2-mean)*(v2-mean)+(v3-mean)*(v3-mean);
        qq += __shfl_xor(qq,1); qq += __shfl_xor(qq,2); qq += __shfl_xor(qq,4);
        const float inv = rsqrtf(qq * (1.f/32.f) + 1e-5f);
        out[(size_t)(base+row)*32 + c0 + 0] = f2b((v0-mean)*inv*gs[c0+0] + bs[c0+0]);
        out[(size_t)(base+row)*32 + c0 + 1] = f2b((v1-mean)*inv*gs[c0+1] + bs[c0+1]);
        out[(size_t)(base+row)*32 + c0 + 2] = f2b((v2-mean)*inv*gs[c0+2] + bs[c0+2]);
        out[(size_t)(base+row)*32 + c0 + 3] = f2b((v3-mean)*inv*gs[c0+3] + bs[c0+3]);
    }
}

// ---------------- output ----------------
__global__ void out_k(const float* __restrict__ xf, const ush* __restrict__ lgf,
                      void* __restrict__ out, const int* __restrict__ flag){
    const int isbf = *flag;
    int g = blockIdx.x*256 + threadIdx.x;
    if (g < kN*kND) {
        float v = xf[g];
        if (isbf) ((ush*)out)[g] = f2b(v);
        else      ((float*)out)[g] = v;
    } else {
        ush u = lgf[g - kN*kND];
        if (isbf) ((ush*)out)[g] = u;
        else      ((float*)out)[g] = b2f(u);
    }
}

// ---------------- host helper ----------------
static inline void mgemm(const float* A, const ush* WT, const void* bias, size_t boff,
                         float* C, const int* flag, int M, int N, int K, int flags,
                         hipStream_t s, ush* aux, ush* aux2, int splitz = 1){
    dim3 grid((N+63)/64, M/64, splitz);
    mgemm_k<<<grid, 256, 0, s>>>(A, WT, bias, boff, C, flag, M, N, K, flags, aux, aux2);
}

extern "C" void kernel_launch(void* const* d_in, const int* in_sizes, int n_in,
                              void* d_out, int out_size, void* d_ws, size_t ws_size,
                              hipStream_t stream) {
    const void* x_in      = d_in[0];
    const void* rel       = d_in[1];
    const int* g_src      = (const int*)d_in[4];
    const int* g_dst      = (const int*)d_in[5];
    const int* lg_src     = (const int*)d_in[6];
    const int* lg_dst     = (const int*)d_in[7];
    const int* edge_feat  = (const int*)d_in[8];
    const int* full_feat  = (const int*)d_in[9];
    const void* n_Wq   = d_in[10];
    const void* n_bq   = d_in[11];
    const void* n_Wk   = d_in[12];
    const void* n_bk   = d_in[13];
    const void* n_Wv   = d_in[14];
    const void* n_bv   = d_in[15];
    const void* n_Wo   = d_in[16];
    const void* n_bo   = d_in[17];
    const void* n_lng  = d_in[18];
    const void* n_lnb  = d_in[19];
    const void* n_fW1  = d_in[20];
    const void* n_fb1  = d_in[21];
    const void* n_fW2  = d_in[22];
    const void* n_fb2  = d_in[23];
    const void* n_flng = d_in[24];
    const void* n_flnb = d_in[25];
    const void* e_Wsrc = d_in[26];
    const void* e_Wdst = d_in[27];
    const void* e_Wq   = d_in[28];
    const void* e_bq   = d_in[29];
    const void* e_Wk   = d_in[30];
    const void* e_Wv   = d_in[31];
    const void* e_Wo   = d_in[32];
    const void* e_bo   = d_in[33];
    const void* e_lng  = d_in[34];
    const void* e_lnb  = d_in[35];
    const void* e_fW1  = d_in[36];
    const void* e_fb1  = d_in[37];
    const void* e_fW2  = d_in[38];
    const void* e_fb2  = d_in[39];
    const void* e_flng = d_in[40];
    const void* e_flnb = d_in[41];

    // ---- workspace carve-up (units: floats) ----
    float* p = (float*)d_ws;
    size_t off = 0;
    auto AL = [&](size_t n){ float* r = p + off; off += n; return r; };
    int* flagp = (int*)AL(64);
    float* xA   = AL((size_t)kN*kND);
    float* xB   = AL((size_t)kN*kND);
    float* xM   = AL((size_t)kN*kND);
    ush*   xAb  = (ush*)AL((size_t)kN*kND/2);
    ush*   xBb  = (ush*)AL((size_t)kN*kND/2);
    ush*   xMb  = (ush*)AL((size_t)kN*kND/2);
    float* qkvb = AL((size_t)kN*kND);            // fp32 Q only, [4096][256]
    ush*   kvaux= (ush*)AL((size_t)kN*kKV/2);    // bf16 [4096][512]: interleaved K/V
    ush*   xsdb = (ush*)AL((size_t)kN*32);       // bf16 [4096][64]: compact SD
    ush*   ob   = (ush*)AL((size_t)kN*kND/2);
    float* tN   = AL((size_t)kN*kND*2);          // split-K partials (2x)
    ush*   nh   = (ush*)AL((size_t)kN*512);      // kN*1024 bf16
    ush*   lgA  = (ush*)AL((size_t)kEL*kED/2);   // bf16 edge residual chain
    ush*   lgB  = (ush*)AL((size_t)kEL*kED/2);
    ush*   lgM  = (ush*)AL((size_t)kEL*kED/2);
    ush*   eqb  = (ush*)AL((size_t)kEL*16);      // kEL*32 bf16
    ush*   ekvb = (ush*)AL((size_t)kEL*32);      // kEL*64 bf16 interleaved K/V
    // CSR structures
    int* cntL  = (int*)AL(kN);
    int* rowL  = (int*)AL(kN + 64);
    int* curL  = (int*)AL(kN);
    int* eidL  = (int*)AL(kEL);
    int* cntG  = (int*)AL(kEL);
    int* rowG  = (int*)AL(kEL + 64);
    int* curG  = (int*)AL(kEL);
    int* eidG  = (int*)AL(kELG);
    int* bsum  = (int*)AL(256);
    // pre-transposed bf16 weights
    ush* wtQKVSD = (ush*)AL(212992);   // [L][832][256] bf16 (425984 ush)
    float* bQKV  = AL(2*kQW);
    ush* wtO  = (ush*)AL(65536);
    ush* wtF1 = (ush*)AL(262144);
    ush* wtF2 = (ush*)AL(262144);
    ush* wtEQKV = (ush*)AL(3072);
    ush* wtEO   = (ush*)AL(1024);
    ush* wtEF1  = (ush*)AL(4096);
    ush* wtEF2  = (ush*)AL(4096);
    if (ws_size < off * sizeof(float)) return;

    float* tN2 = tN + (size_t)kN*kND;

    detect_k<<<1, 64, 0, stream>>>((const ush*)x_in, flagp);
    {
        long total = (long)kN*kND + (long)kEL*kED + 2*kQW + kN + kEL;
        int blocks = (int)((total + 255) / 256);
        setup_misc_k<<<blocks, 256, 0, stream>>>(x_in, rel, edge_feat, n_bq, n_bk, n_bv,
                                                 xA, xAb, lgA, bQKV, cntL, cntG, flagp);
    }
    trans_tiled_k<<<1592, 256, 0, stream>>>(n_Wq, n_Wk, n_Wv, n_Wo, n_fW1, n_fW2,
                                            e_Wsrc, e_Wdst, e_Wq, e_Wk, e_Wv, e_Wo,
                                            e_fW1, e_fW2, flagp,
                                            wtQKVSD, wtO, wtF1, wtF2,
                                            wtEQKV, wtEO, wtEF1, wtEF2);

    count2_k<<<(kEL+kELG)/256, 256, 0, stream>>>(g_dst, lg_dst, cntL, cntG);
    scan_blk2_k<<<132, 256, 0, stream>>>(cntL, cntG, rowL, rowG, bsum);
    scan_top2_k<<<1, 256, 0, stream>>>(bsum);
    scan_add2_k<<<(kN+kEL)/256, 256, 0, stream>>>(rowL, rowG, bsum, curL, curG);
    fill2_k<<<(kEL+kELG)/256, 256, 0, stream>>>(g_dst, lg_dst, curL, curG, eidL, eidG);

    float* xc = xA;  float* xn = xB;
    ush* xcb = xAb;  ush* xnb = xBb;
    ush* lgc = lgA;  ush* lgn = lgB;

    for (int i = 0; i < kL; ++i) {
        const size_t o256 = (size_t)i*kND;
        const size_t o1024= (size_t)i*1024;
        const size_t o32  = (size_t)i*kED;
        const size_t o128 = (size_t)i*128;

        // ===== node update (fp32 Q + bf16 K/V + compact SD side-outputs) =====
        mgemm((const float*)xcb, wtQKVSD + (size_t)i*212992, bQKV, (size_t)i*kQW, qkvb,
              flagp, kN, kQW, kND, 4|16|32|64, stream, kvaux, xsdb);
        full_attn_k<<<512, 512, 0, stream>>>(qkvb, kvaux, rel, full_feat, ob, flagp);
        loc_gather_k<<<kN, 256, 0, stream>>>(qkvb, kvaux, lgc, g_src, rowL, eidL, ob);
        mgemm((const float*)ob, wtO + (size_t)i*65536, n_bo, o256, tN, flagp,
              kN, kND, kND, 4|32|128, stream, nullptr, nullptr, 2);
        ln_k<<<kN/4, 256, 0, stream>>>(xc, tN, tN2, n_lng, n_lnb, o256, xM, xMb, flagp, kND);
        mgemm((const float*)xMb, wtF1 + (size_t)i*262144, n_fb1, o1024, (float*)nh, flagp,
              kN, 1024, kND, 4|2|8|32, stream, nullptr, nullptr);
        mgemm((const float*)nh, wtF2 + (size_t)i*262144, n_fb2, o256, tN, flagp,
              kN, kND, 1024, 4|32|128, stream, nullptr, nullptr, 2);
        ln_k<<<kN/4, 256, 0, stream>>>(xM, tN, tN2, n_flng, n_flnb, o256, xn, xnb, flagp, kND);

        // ===== edge update (uses PRE-update xc, lgc) =====
        eqkv_mfma_k<<<kEL/128, 256, 0, stream>>>(lgc, xsdb, g_src, g_dst,
                                                 wtEQKV, (size_t)i*1024, e_bq, o32,
                                                 eqb, ekvb, flagp);
        lgs_ewo_k<<<kEL/32, 256, 0, stream>>>(eqb, ekvb, lg_src, rowG, eidG,
                                              lgc, wtEO, (size_t)i*1024, e_bo, o32,
                                              e_lng, e_lnb, o32, lgM, flagp);
        effn_mfma_k<<<kEL/128, 256, 0, stream>>>(lgM, wtEF1, (size_t)i*4096, e_fb1, o128,
                                                 wtEF2, (size_t)i*4096, e_fb2, o32,
                                                 e_flng, e_flnb, o32, lgn, flagp);

        { float* t = xc; xc = xn; xn = t; }
        { ush* t = xcb; xcb = xnb; xnb = t; }
        { ush* t = lgc; lgc = lgn; lgn = t; }
    }

    out_k<<<(kN*kND + kEL*kED)/256, 256, 0, stream>>>(xc, lgc, d_out, flagp);
}

// Round 22
// 505.922 us; speedup vs baseline: 1.0981x; 1.0137x over previous
//
#include <hip/hip_runtime.h>
#include <hip/hip_bf16.h>

typedef __hip_bfloat16 bf16;
typedef unsigned short ush;

static constexpr int kN   = 4096;    // nodes
static constexpr int kND  = 256;     // hidden
static constexpr int kEL  = 131072;  // local edges
static constexpr int kED  = 32;      // edge dim
static constexpr int kELG = 262144;  // line-graph edges
static constexpr int kL   = 2;
static constexpr int kQW  = 832;     // packed qkv+sd GEMM width
static constexpr int kKV  = 512;     // kvaux row stride (bf16), per-head interleaved K/V
static constexpr float kScaleN = 0.17677669529663687f; // 1/sqrt(32)

using frag_ab = __attribute__((ext_vector_type(8))) short;   // 8 bf16 (4 VGPRs)
using frag_cd = __attribute__((ext_vector_type(4))) float;   // 4 fp32

__device__ __forceinline__ float ldf(const void* p, size_t i, int isbf){
    return isbf ? __bfloat162float(((const bf16*)p)[i]) : ((const float*)p)[i];
}
__device__ __forceinline__ ush f2b(float f){ bf16 h = __float2bfloat16(f); return *(ush*)&h; }
__device__ __forceinline__ float b2f(ush u){ return __uint_as_float(((unsigned)u)<<16); }
__device__ __forceinline__ ush ldb(const void* p, size_t i, int isbf){
    return isbf ? ((const ush*)p)[i] : f2b(((const float*)p)[i]);
}

// ---------------- dtype detection (wave-parallel) ----------------
__global__ void detect_k(const ush* __restrict__ xin, int* __restrict__ flag){
    const int t = threadIdx.x;              // 64 threads
    int pl = 0;
    for (int i = t; i < 128; i += 64) {
        ush u = xin[i];
        int e = (u >> 7) & 0xFF;
        if (e == 0 || (e >= 110 && e <= 140)) ++pl;
    }
    #pragma unroll
    for (int off = 32; off > 0; off >>= 1) pl += __shfl_down(pl, off);
    if (t == 0) *flag = (pl >= 102) ? 1 : 0;
}

// ---------------- fused setup: cast x (f32+bf16), init lg (bf16), pack bias, zero counters ----------------
__global__ void setup_misc_k(const void* __restrict__ xin, const void* __restrict__ rel,
                             const int* __restrict__ feat,
                             const void* __restrict__ bq, const void* __restrict__ bk,
                             const void* __restrict__ bv,
                             float* __restrict__ xA, ush* __restrict__ xAb,
                             ush* __restrict__ lgA,
                             float* __restrict__ bQKV,
                             int* __restrict__ cntL, int* __restrict__ cntG,
                             const int* __restrict__ flag){
    const int isbf = *flag;
    long g = (long)blockIdx.x*256 + threadIdx.x;
    if (g < (long)kN*kND) {
        float v = ldf(xin, g, isbf);
        xA[g] = v; xAb[g] = f2b(v);
        return;
    }
    g -= (long)kN*kND;
    if (g < (long)kEL*kED) { int e = (int)(g >> 5), d = (int)(g & 31);
        lgA[g] = ldb(rel, (size_t)feat[e]*kED + d, isbf); return; }
    g -= (long)kEL*kED;
    if (g < 2*kQW) {
        int layer = (int)(g / kQW), j = (int)(g - (long)layer*kQW);
        float v = 0.f;
        if (j < 768) { int w = j >> 8, jj = j & 255;
            const void* B = (w==0)?bq:((w==1)?bk:bv);
            v = ldf(B, (size_t)layer*256 + jj, isbf); }
        bQKV[g] = v; return;
    }
    g -= 2*kQW;
    if (g < kN) { cntL[g] = 0; return; }
    g -= kN;
    if (g < kEL) { cntG[g] = 0; return; }
}

// ---------------- ALL weight pre-transposes: 32x32 LDS-tiled, coalesced both sides ----------------
__global__ __launch_bounds__(256) void trans_tiled_k(
    const void* __restrict__ nWq, const void* __restrict__ nWk, const void* __restrict__ nWv,
    const void* __restrict__ nWo, const void* __restrict__ nF1, const void* __restrict__ nF2,
    const void* __restrict__ eWs, const void* __restrict__ eWd,
    const void* __restrict__ eWq, const void* __restrict__ eWk, const void* __restrict__ eWv,
    const void* __restrict__ eWo, const void* __restrict__ eF1, const void* __restrict__ eF2,
    const int* __restrict__ flag,
    ush* __restrict__ wtQKVSD, ush* __restrict__ wtO, ush* __restrict__ wtF1,
    ush* __restrict__ wtF2, ush* __restrict__ wtEQKV, ush* __restrict__ wtEO,
    ush* __restrict__ wtEF1, ush* __restrict__ wtEF2)
{
    __shared__ ush lds[32][33];
    const int isbf = *flag;
    int idx = blockIdx.x;
    const void* src; size_t soff; ush* dstp; size_t doff;
    int Ns, Kd, r0, c0;
    if (idx < 384) {                                    // nWq/nWk/nWv [L][256][256] -> QKVSD rows 0-767
        int w = idx >> 7, rem = idx & 127;
        int layer = rem >> 6, tile = rem & 63;
        r0 = (tile >> 3) << 5; c0 = (tile & 7) << 5;
        src = (w==0)?nWq:((w==1)?nWk:nWv); soff = (size_t)layer*65536;
        Ns = 256; Kd = 256;
        dstp = wtQKVSD; doff = (size_t)layer*212992 + (size_t)w*65536;
    } else if ((idx -= 384) < 32) {                     // eWs/eWd [L][256][32] -> rows 768-831
        int w = idx >> 4, rem = idx & 15;
        int layer = rem >> 3, tile = rem & 7;
        r0 = tile << 5; c0 = 0;
        src = w ? eWd : eWs; soff = (size_t)layer*8192;
        Ns = 32; Kd = 256;
        dstp = wtQKVSD; doff = (size_t)layer*212992 + (size_t)(768 + w*32)*256;
    } else if ((idx -= 32) < 128) {                     // nWo [L][256][256]
        int layer = idx >> 6, tile = idx & 63;
        r0 = (tile >> 3) << 5; c0 = (tile & 7) << 5;
        src = nWo; soff = (size_t)layer*65536; Ns = 256; Kd = 256;
        dstp = wtO; doff = (size_t)layer*65536;
    } else if ((idx -= 128) < 512) {                    // nF1 [L][256][1024] -> [L][1024][256]
        int layer = idx >> 8, tile = idx & 255;
        r0 = (tile >> 5) << 5; c0 = (tile & 31) << 5;
        src = nF1; soff = (size_t)layer*262144; Ns = 1024; Kd = 256;
        dstp = wtF1; doff = (size_t)layer*262144;
    } else if ((idx -= 512) < 512) {                    // nF2 [L][1024][256] -> [L][256][1024]
        int layer = idx >> 8, tile = idx & 255;
        r0 = (tile >> 3) << 5; c0 = (tile & 7) << 5;
        src = nF2; soff = (size_t)layer*262144; Ns = 256; Kd = 1024;
        dstp = wtF2; doff = (size_t)layer*262144;
    } else if ((idx -= 512) < 6) {                      // eWq/eWk/eWv [L][32][32]
        int w = idx >> 1, layer = idx & 1;
        r0 = 0; c0 = 0;
        src = (w==0)?eWq:((w==1)?eWk:eWv); soff = (size_t)layer*1024; Ns = 32; Kd = 32;
        dstp = wtEQKV; doff = (size_t)(w*2 + layer)*1024;
    } else if ((idx -= 6) < 2) {                        // eWo [L][32][32]
        r0 = 0; c0 = 0;
        src = eWo; soff = (size_t)idx*1024; Ns = 32; Kd = 32;
        dstp = wtEO; doff = (size_t)idx*1024;
    } else if ((idx -= 2) < 8) {                        // eF1 [L][32][128] -> [L][128][32]
        int layer = idx >> 2, tile = idx & 3;
        r0 = 0; c0 = tile << 5;
        src = eF1; soff = (size_t)layer*4096; Ns = 128; Kd = 32;
        dstp = wtEF1; doff = (size_t)layer*4096;
    } else {                                            // eF2 [L][128][32] -> [L][32][128]
        idx -= 8;
        int layer = idx >> 2, tile = idx & 3;
        r0 = tile << 5; c0 = 0;
        src = eF2; soff = (size_t)layer*4096; Ns = 32; Kd = 128;
        dstp = wtEF2; doff = (size_t)layer*4096;
    }
    const int t = threadIdx.x;
    const int c = t & 31, rb = t >> 5;
    #pragma unroll
    for (int p = 0; p < 4; ++p) {
        int r = rb + p*8;
        lds[r][c] = ldb(src, soff + (size_t)(r0 + r)*Ns + c0 + c, isbf);
    }
    __syncthreads();
    #pragma unroll
    for (int p = 0; p < 4; ++p) {
        int rr = rb + p*8;
        dstp[doff + (size_t)(c0 + rr)*Kd + r0 + c] = lds[c][rr];
    }
}

// ---------------- CSR build (both graphs fused) ----------------
__global__ void count2_k(const int* __restrict__ gd, const int* __restrict__ lgd,
                         int* __restrict__ cntL, int* __restrict__ cntG){
    int g = blockIdx.x*256 + threadIdx.x;
    if (g < kEL) atomicAdd(&cntL[gd[g]], 1);
    else if (g < kEL + kELG) atomicAdd(&cntG[lgd[g - kEL]], 1);
}
__global__ __launch_bounds__(256) void scan_blk2_k(
    const int* __restrict__ cntL, const int* __restrict__ cntG,
    int* __restrict__ rowL, int* __restrict__ rowG, int* __restrict__ bsum)
{
    __shared__ int s[256];
    const int t = threadIdx.x;
    const bool isL = blockIdx.x < 4;
    const int* cnt = isL ? cntL : cntG;
    int* out = isL ? rowL : rowG;
    const int blk = isL ? blockIdx.x : blockIdx.x - 4;
    const int n = isL ? kN : kEL;
    const int b0 = blk*1024;
    int v[4], pre[4], tsum = 0;
    #pragma unroll
    for (int j=0;j<4;++j){
        int idx = b0 + t*4 + j;
        v[j] = (idx < n) ? cnt[idx] : 0;
        pre[j] = tsum; tsum += v[j];
    }
    s[t] = tsum; __syncthreads();
    for (int off=1; off<256; off<<=1){
        int x = (t>=off) ? s[t-off] : 0;
        __syncthreads();
        s[t] += x;
        __syncthreads();
    }
    int texc = s[t] - tsum;
    #pragma unroll
    for (int j=0;j<4;++j){
        int idx = b0 + t*4 + j;
        if (idx < n) out[idx] = texc + pre[j];
    }
    if (t == 255) bsum[(isL ? 0 : 8) + blk] = s[255];
}
__global__ __launch_bounds__(256) void scan_top2_k(int* __restrict__ bsum){
    __shared__ int sL[256], sG[256];
    const int t = threadIdx.x;
    int vL = (t < 4)   ? bsum[t]     : 0;
    int vG = (t < 128) ? bsum[8 + t] : 0;
    sL[t] = vL; sG[t] = vG; __syncthreads();
    for (int off=1; off<256; off<<=1){
        int xL = (t>=off) ? sL[t-off] : 0;
        int xG = (t>=off) ? sG[t-off] : 0;
        __syncthreads();
        sL[t] += xL; sG[t] += xG;
        __syncthreads();
    }
    if (t < 4)   bsum[t]     = sL[t] - vL;
    if (t < 128) bsum[8 + t] = sG[t] - vG;
}
__global__ void scan_add2_k(int* __restrict__ rowL, int* __restrict__ rowG,
                            const int* __restrict__ bsum,
                            int* __restrict__ curL, int* __restrict__ curG){
    int g = blockIdx.x*256 + threadIdx.x;
    if (g < kN){ int v = rowL[g] + bsum[g >> 10]; rowL[g] = v; curL[g] = v; }
    else if (g < kN + kEL){ int gg = g - kN;
        int v = rowG[gg] + bsum[8 + (gg >> 10)]; rowG[gg] = v; curG[gg] = v; }
    if (g == 0){ rowL[kN] = kEL; rowG[kEL] = kELG; }
}
__global__ void fill2_k(const int* __restrict__ gd, const int* __restrict__ lgd,
                        int* __restrict__ curL, int* __restrict__ curG,
                        int* __restrict__ eidL, int* __restrict__ eidG){
    int g = blockIdx.x*256 + threadIdx.x;
    if (g < kEL){ int pos = atomicAdd(&curL[gd[g]], 1); eidL[pos] = g; }
    else if (g < kEL + kELG){ int gg = g - kEL;
        int pos = atomicAdd(&curG[lgd[gg]], 1); eidG[pos] = gg; }
}

// ---------------- MFMA GEMM: C[M,N] = A@WT^T + bias (opt relu); BK=64 ----------------
// WT: bf16 [N][K]. 64x64 tile, 4 waves. Requires K%(64*gridDim.z)==0, N%64==0.
// flags: 2=RELU, 4=has-bias, 8=bf16 out, 16=bias packed fp32, 32=A is bf16,
//        64=QKV split output (col<256 -> fp32 C; 256-767 -> bf16 aux interleaved; 768+ -> aux2),
//        128=split-K over gridDim.z (bias by z==0 only; fp32 partials at C + z*M*N)
__global__ __launch_bounds__(256) void mgemm_k(
    const float* __restrict__ A, const ush* __restrict__ WT,
    const void* __restrict__ bias, size_t boff,
    float* __restrict__ C, const int* __restrict__ flag,
    int M, int N, int K, int flags, ush* __restrict__ aux, ush* __restrict__ aux2)
{
    __shared__ __align__(16) ush As[64*72];
    __shared__ __align__(16) ush Ws[64*72];
    const int isbf = *flag;
    const int t = threadIdx.x;
    const int m0 = blockIdx.y*64, n0 = blockIdx.x*64;
    const int wave = t>>6, lane = t&63;
    const int quad = lane>>4, l15 = lane&15;
    const int r = t>>3, kq = (t&7)*8;      // rows r and r+32, 8 K-elems at kq
    const bool abf = flags & 32;
    const bool spk = flags & 128;
    const int Kc   = spk ? (K / gridDim.z) : K;
    const int koff = spk ? (blockIdx.z * Kc) : 0;

    frag_cd acc[4];
    #pragma unroll
    for (int tl=0; tl<4; ++tl)
        #pragma unroll
        for (int j=0;j<4;++j) acc[tl][j] = 0.f;

    const float* ap0 = A + (size_t)(m0+r)*K + koff + kq;
    const float* ap1 = A + (size_t)(m0+r+32)*K + koff + kq;
    const ush*   ab0 = (const ush*)A + (size_t)(m0+r)*K + koff + kq;
    const ush*   ab1 = (const ush*)A + (size_t)(m0+r+32)*K + koff + kq;
    const ush*   wp0 = WT + (size_t)(n0+r)*K + koff + kq;
    const ush*   wp1 = WT + (size_t)(n0+r+32)*K + koff + kq;

    float4 a00,a01,a10,a11; uint4 av0,av1, wv0,wv1;
    auto loadT = [&](int kk){
        if (abf) { av0 = *(const uint4*)(ab0+kk); av1 = *(const uint4*)(ab1+kk); }
        else { a00 = *(const float4*)(ap0+kk); a01 = *(const float4*)(ap0+kk+4);
               a10 = *(const float4*)(ap1+kk); a11 = *(const float4*)(ap1+kk+4); }
        wv0 = *(const uint4*)(wp0+kk); wv1 = *(const uint4*)(wp1+kk);
    };
    loadT(0);

    for (int kk = 0; kk < Kc; kk += 64) {
        if (abf) {
            *(uint4*)&As[r*72 + kq]        = av0;
            *(uint4*)&As[(r+32)*72 + kq]   = av1;
        } else {
            *(ushort4*)&As[r*72 + kq]       = make_ushort4(f2b(a00.x),f2b(a00.y),f2b(a00.z),f2b(a00.w));
            *(ushort4*)&As[r*72 + kq + 4]   = make_ushort4(f2b(a01.x),f2b(a01.y),f2b(a01.z),f2b(a01.w));
            *(ushort4*)&As[(r+32)*72 + kq]     = make_ushort4(f2b(a10.x),f2b(a10.y),f2b(a10.z),f2b(a10.w));
            *(ushort4*)&As[(r+32)*72 + kq + 4] = make_ushort4(f2b(a11.x),f2b(a11.y),f2b(a11.z),f2b(a11.w));
        }
        *(uint4*)&Ws[r*72 + kq]      = wv0;
        *(uint4*)&Ws[(r+32)*72 + kq] = wv1;
        __syncthreads();
        if (kk + 64 < Kc) loadT(kk + 64);
        frag_ab af0 = *(const frag_ab*)&As[(wave*16 + l15)*72 + quad*8];
        frag_ab af1 = *(const frag_ab*)&As[(wave*16 + l15)*72 + 32 + quad*8];
        #pragma unroll
        for (int tl = 0; tl < 4; ++tl) {
            frag_ab bf0 = *(const frag_ab*)&Ws[(tl*16 + l15)*72 + quad*8];
            acc[tl] = __builtin_amdgcn_mfma_f32_16x16x32_bf16(af0, bf0, acc[tl], 0, 0, 0);
            frag_ab bf1 = *(const frag_ab*)&Ws[(tl*16 + l15)*72 + 32 + quad*8];
            acc[tl] = __builtin_amdgcn_mfma_f32_16x16x32_bf16(af1, bf1, acc[tl], 0, 0, 0);
        }
        __syncthreads();
    }
    const bool do_relu = flags & 2;
    const bool has_b   = (flags & 4) && (!spk || blockIdx.z == 0);
    const bool obf     = flags & 8;
    float* Cz = spk ? (C + (size_t)blockIdx.z * M * N) : C;
    #pragma unroll
    for (int tl = 0; tl < 4; ++tl) {
        int col = n0 + tl*16 + l15;
        float bv = 0.f;
        if (has_b) bv = (flags & 16) ? ((const float*)bias)[boff + col]
                                     : ldf(bias, boff + col, isbf);
        // kvaux/xsd column mapping for QKV split output:
        int adst = -1; bool tox = false;
        if (flags & 64 && col >= 256) {
            int c = col - 256;
            if (c < 512) {
                int isv = c >> 8;            // 0 = K, 1 = V
                int cc = c & 255;
                int h = cc >> 5, d = cc & 31;
                int base = (h < 4) ? h*64 : 256 + (h-4)*64;
                adst = base + isv*32 + d;
            } else { adst = c - 512; tox = true; }   // SD -> compact xsd [row][64]
        }
        #pragma unroll
        for (int rg = 0; rg < 4; ++rg) {
            int row = m0 + wave*16 + quad*4 + rg;
            float v = acc[tl][rg] + bv;
            if (do_relu) v = fmaxf(v, 0.f);
            if (flags & 64) {
                if (col < 256)  C[(size_t)row*256 + col] = v;
                else if (tox)   aux2[(size_t)row*64 + adst] = f2b(v);
                else            aux[(size_t)row*kKV + adst] = f2b(v);
            } else if (obf) ((ush*)C)[(size_t)row*N + col] = f2b(v);
            else            Cz[(size_t)row*N + col] = v;
        }
    }
}

// ---------------- LayerNorm (node rows, D=256): out = LN(a + b [+ b2]), dual f32+bf16 ----------------
// 4 rows/block, wave per row. b2 nullable. fin nullable: also write final output (dtype by flag).
__global__ __launch_bounds__(256) void ln_k(
    const float* __restrict__ a, const float* __restrict__ b, const float* __restrict__ b2,
    const void* __restrict__ g, const void* __restrict__ be, size_t goff,
    float* __restrict__ out, ush* __restrict__ outb,
    void* __restrict__ fin,
    const int* __restrict__ flag, int D)
{
    const int isbf = *flag;
    const int row = blockIdx.x*4 + (threadIdx.x >> 6);
    const int t = threadIdx.x & 63;
    float v[4];
    int cnt = 0;
    float s = 0.f;
    for (int i = t; i < D; i += 64) {
        float x = a[(size_t)row*D + i];
        if (b)  x += b[(size_t)row*D + i];
        if (b2) x += b2[(size_t)row*D + i];
        v[cnt++] = x; s += x;
    }
    #pragma unroll
    for (int off = 32; off > 0; off >>= 1) s += __shfl_down(s, off);
    s = __shfl(s, 0);
    const float mean = s / D;
    float qq = 0.f;
    for (int c2 = 0; c2 < cnt; ++c2) { float d = v[c2]-mean; qq += d*d; }
    #pragma unroll
    for (int off = 32; off > 0; off >>= 1) qq += __shfl_down(qq, off);
    qq = __shfl(qq, 0);
    const float inv = rsqrtf(fmaxf(qq, 0.f) / D + 1e-5f);
    cnt = 0;
    for (int i = t; i < D; i += 64) {
        float r = (v[cnt++] - mean)*inv*ldf(g, goff + i, isbf) + ldf(be, goff + i, isbf);
        out[(size_t)row*D + i] = r;
        outb[(size_t)row*D + i] = f2b(r);
        if (fin) {
            if (isbf) ((ush*)fin)[(size_t)row*D + i] = f2b(r);
            else      ((float*)fin)[(size_t)row*D + i] = r;
        }
    }
}

// ---------------- MFMA eq/ekv (+gathered mixed), 128 rows/block, bf16 in/out ----------------
// xsd: compact [4096][64] bf16 (src at 0-31, dst at 32-63). Vectorized staging.
// Output: eq [el][32]; ekv [el][64] interleaved (k_h at h*8, v_h at h*8+4).
__global__ __launch_bounds__(256) void eqkv_mfma_k(
    const ush* __restrict__ lg, const ush* __restrict__ xsd,
    const int* __restrict__ gsrc, const int* __restrict__ gdst,
    const ush* __restrict__ WQKV, size_t woff,
    const void* __restrict__ bq, size_t boff,
    ush* __restrict__ eq, ush* __restrict__ ekv,
    const int* __restrict__ flag)
{
    __shared__ __align__(16) ush mixs[128*40];
    __shared__ __align__(16) ush wts[3][32*40];
    __shared__ float bqs[32];
    const int isbf = *flag;
    const int t = threadIdx.x;
    const int e0 = blockIdx.x * 128;
    #pragma unroll
    for (int i = t; i < 768; i += 256) {
        int m = i >> 8, r2 = i & 255;
        int n = r2 >> 3, k4 = (r2 & 7) * 4;
        *(ushort4*)&wts[m][n*40 + k4] =
            *(const ushort4*)&WQKV[(size_t)m*2048 + woff + (size_t)n*32 + k4];
    }
    if (t < 32) bqs[t] = ldf(bq, boff + t, isbf);
    {
        int r = t >> 1, c0 = (t & 1) * 16;
        int e = e0 + r;
        int s = gsrc[e], d2 = gdst[e];
        const ush* lp = lg  + (size_t)e*32  + c0;
        const ush* sp = xsd + (size_t)s*64  + c0;
        const ush* dp = xsd + (size_t)d2*64 + 32 + c0;
        uint4 lv0 = *(const uint4*)lp,     lv1 = *(const uint4*)(lp+8);
        uint4 sv0 = *(const uint4*)sp,     sv1 = *(const uint4*)(sp+8);
        uint4 dv0 = *(const uint4*)dp,     dv1 = *(const uint4*)(dp+8);
        auto pk = [](unsigned a, unsigned b, unsigned c)->unsigned {
            ush lo = f2b(b2f((ush)(a & 0xffff)) + b2f((ush)(b & 0xffff)) + b2f((ush)(c & 0xffff)));
            ush hi = f2b(b2f((ush)(a >> 16))    + b2f((ush)(b >> 16))    + b2f((ush)(c >> 16)));
            return (unsigned)lo | ((unsigned)hi << 16);
        };
        uint4 o0, o1;
        o0.x = pk(lv0.x, sv0.x, dv0.x); o0.y = pk(lv0.y, sv0.y, dv0.y);
        o0.z = pk(lv0.z, sv0.z, dv0.z); o0.w = pk(lv0.w, sv0.w, dv0.w);
        o1.x = pk(lv1.x, sv1.x, dv1.x); o1.y = pk(lv1.y, sv1.y, dv1.y);
        o1.z = pk(lv1.z, sv1.z, dv1.z); o1.w = pk(lv1.w, sv1.w, dv1.w);
        *(uint4*)&mixs[r*40 + c0]     = o0;
        *(uint4*)&mixs[r*40 + c0 + 8] = o1;
    }
    __syncthreads();
    const int wave = t >> 6, l15 = t & 15, quad = (t >> 4) & 3;
    #pragma unroll
    for (int mi = 0; mi < 2; ++mi) {
        const int mt = wave*2 + mi;
        frag_ab af = *(const frag_ab*)&mixs[(mt*16 + l15)*40 + quad*8];
        #pragma unroll
        for (int w = 0; w < 3; ++w) {
            #pragma unroll
            for (int nt = 0; nt < 2; ++nt) {
                frag_ab bf = *(const frag_ab*)&wts[w][(nt*16 + l15)*40 + quad*8];
                frag_cd acc = {0.f, 0.f, 0.f, 0.f};
                acc = __builtin_amdgcn_mfma_f32_16x16x32_bf16(af, bf, acc, 0, 0, 0);
                const float bv = (w==0) ? bqs[nt*16 + l15] : 0.f;
                const int col = nt*16 + l15;            // 0..31
                const int h = col >> 2, d = col & 3;
                #pragma unroll
                for (int rg = 0; rg < 4; ++rg) {
                    int row = e0 + mt*16 + quad*4 + rg;
                    float v = acc[rg] + bv;
                    if (w == 0)      eq[(size_t)row*32 + col] = f2b(v);
                    else if (w == 1) ekv[(size_t)row*64 + h*8 + d] = f2b(v);
                    else             ekv[(size_t)row*64 + h*8 + 4 + d] = f2b(v);
                }
            }
        }
    }
}

// ---------------- MFMA edge FFN: LN(A + relu(A@W1+b1)@W2 + b2); bf16 A / bf16 out ----------------
// fin nullable: also write final lg output at offset kN*kND (dtype by flag).
__global__ __launch_bounds__(256) void effn_mfma_k(
    const ush* __restrict__ A,
    const ush* __restrict__ W1T, size_t w1off, const void* __restrict__ b1, size_t b1off,
    const ush* __restrict__ W2T, size_t w2off, const void* __restrict__ b2, size_t b2off,
    const void* __restrict__ g, const void* __restrict__ be, size_t goff,
    ush* __restrict__ out, void* __restrict__ fin, const int* __restrict__ flag)
{
    __shared__ __align__(16) ush w1t[128*40];
    __shared__ __align__(16) ush w2t[32*136];
    __shared__ __align__(16) ush hid[64*136];
    __shared__ float b1s[128], b2s[32];
    const int isbf = *flag;
    const int t = threadIdx.x;
    const int wave = t >> 6, l15 = t & 15, quad = (t >> 4) & 3;

    #pragma unroll
    for (int i = t; i < 1024; i += 256) {
        int n1 = i >> 3, k4 = (i & 7) * 4;
        *(ushort4*)&w1t[n1*40 + k4] = *(const ushort4*)&W1T[w1off + (size_t)n1*32 + k4];
        int n2 = i >> 5, kq2 = (i & 31) * 4;
        *(ushort4*)&w2t[n2*136 + kq2] = *(const ushort4*)&W2T[w2off + (size_t)n2*128 + kq2];
    }
    if (t < 128) b1s[t] = ldf(b1, b1off + t, isbf);
    if (t < 32)  b2s[t] = ldf(b2, b2off + t, isbf);
    __syncthreads();

    const float g0  = ldf(g,  goff + l15, isbf),      g1v = ldf(g,  goff + 16 + l15, isbf);
    const float be0 = ldf(be, goff + l15, isbf),      be1 = ldf(be, goff + 16 + l15, isbf);
    const float bb0 = b2s[l15], bb1 = b2s[16 + l15];

    for (int tt = 0; tt < 2; ++tt) {
        const int e0 = (blockIdx.x*2 + tt) * 64;
        {
            const int m = wave*16 + l15;
            frag_ab af = *(const frag_ab*)&A[(size_t)(e0+m)*32 + quad*8];
            #pragma unroll
            for (int nt = 0; nt < 8; ++nt) {
                frag_ab bf = *(const frag_ab*)&w1t[(nt*16 + l15)*40 + quad*8];
                frag_cd acc = {0.f, 0.f, 0.f, 0.f};
                acc = __builtin_amdgcn_mfma_f32_16x16x32_bf16(af, bf, acc, 0, 0, 0);
                float bv = b1s[nt*16 + l15];
                #pragma unroll
                for (int rg = 0; rg < 4; ++rg) {
                    int row = wave*16 + quad*4 + rg;
                    hid[row*136 + nt*16 + l15] = f2b(fmaxf(acc[rg] + bv, 0.f));
                }
            }
        }
        // hid rows are wave-private -> no barrier needed
        frag_cd acc2[2] = {{0.f,0.f,0.f,0.f},{0.f,0.f,0.f,0.f}};
        #pragma unroll
        for (int ks = 0; ks < 4; ++ks) {
            frag_ab af2 = *(const frag_ab*)&hid[(wave*16 + l15)*136 + ks*32 + quad*8];
            #pragma unroll
            for (int tl = 0; tl < 2; ++tl) {
                frag_ab bf2 = *(const frag_ab*)&w2t[(tl*16 + l15)*136 + ks*32 + quad*8];
                acc2[tl] = __builtin_amdgcn_mfma_f32_16x16x32_bf16(af2, bf2, acc2[tl], 0, 0, 0);
            }
        }
        #pragma unroll
        for (int rg = 0; rg < 4; ++rg) {
            const int row = e0 + wave*16 + quad*4 + rg;
            float v0 = acc2[0][rg] + bb0 + b2f(A[(size_t)row*32 + l15]);
            float v1 = acc2[1][rg] + bb1 + b2f(A[(size_t)row*32 + 16 + l15]);
            float s = v0 + v1;
            s += __shfl_xor(s,1); s += __shfl_xor(s,2); s += __shfl_xor(s,4); s += __shfl_xor(s,8);
            const float mean = s * (1.f/32.f);
            float q = (v0-mean)*(v0-mean) + (v1-mean)*(v1-mean);
            q += __shfl_xor(q,1); q += __shfl_xor(q,2); q += __shfl_xor(q,4); q += __shfl_xor(q,8);
            const float inv = rsqrtf(q * (1.f/32.f) + 1e-5f);
            const ush u0 = f2b((v0-mean)*inv*g0  + be0);
            const ush u1 = f2b((v1-mean)*inv*g1v + be1);
            out[(size_t)row*32 + l15]      = u0;
            out[(size_t)row*32 + 16 + l15] = u1;
            if (fin) {
                const size_t base = (size_t)kN*kND + (size_t)row*32;
                if (isbf) {
                    ((ush*)fin)[base + l15]      = u0;
                    ((ush*)fin)[base + 16 + l15] = u1;
                } else {
                    ((float*)fin)[base + l15]      = b2f(u0);
                    ((float*)fin)[base + 16 + l15] = b2f(u1);
                }
            }
        }
    }
}

// ---------------- full-graph attention: (b,h,quarter) blocks, 512 grid (online softmax) ----------------
// q: fp32 [4096][256]; kv: bf16 [4096][kKV], full head h: K at h*64, V at h*64+32
__global__ __launch_bounds__(512) void full_attn_k(
    const float* __restrict__ q, const ush* __restrict__ kv,
    const void* __restrict__ rel, const int* __restrict__ feat, ush* __restrict__ o,
    const int* __restrict__ flag)
{
    __shared__ __align__(8) ush ks[128][36];
    __shared__ __align__(8) ush vs[128][36];
    __shared__ __align__(8) ush rs[128][36];
    __shared__ float pb[8][32][34];            // per-wave partials: m, l, acc[32]
    const int isbf = *flag;
    const int bid = blockIdx.x;
    const int b = bid >> 4, h = (bid >> 2) & 3, qtr = bid & 3;
    const int t = threadIdx.x;
    for (int i = t; i < 4096; i += 512) {
        int r = i >> 5, d = i & 31;
        rs[r][d] = ldb(rel, i, isbf);
        const ush* kvrow = kv + (size_t)(b*128 + r)*kKV + h*64 + d;
        ks[r][d] = kvrow[0];
        vs[r][d] = kvrow[32];
    }
    __syncthreads();
    const int wave = t >> 6, lane = t & 63;
    const int dstL = lane >> 1, part = lane & 1;   // 2 lanes per dst
    const int dst = qtr*32 + dstL;
    const int dbase = part*16;                     // this lane's 16 dims
    float qr[16];
    { size_t base = ((size_t)(b*128 + dst))*256 + h*32 + dbase;
      #pragma unroll
      for (int d=0; d<16; ++d) qr[d] = q[base + d]; }
    const int* fp = feat + (size_t)b*16384 + dst;
    const int s0 = wave*16;
    float m = -1e30f, l = 0.f;
    float acc[16];
    #pragma unroll
    for (int d=0; d<16; ++d) acc[d] = 0.f;
    int f = fp[s0*128];
    for (int sI = 0; sI < 16; ++sI) {
        const int s = s0 + sI;
        int fn = (sI+1 < 16) ? fp[(s+1)*128] : 0;
        float er[16];
        float scp = 0.f;
        #pragma unroll
        for (int j2 = 0; j2 < 4; ++j2) {
            ushort4 eu = *(const ushort4*)&rs[f][dbase + j2*4];
            ushort4 ku = *(const ushort4*)&ks[s][dbase + j2*4];
            float e0 = b2f(eu.x), e1 = b2f(eu.y), e2 = b2f(eu.z), e3 = b2f(eu.w);
            er[j2*4+0]=e0; er[j2*4+1]=e1; er[j2*4+2]=e2; er[j2*4+3]=e3;
            scp += (b2f(ku.x)+e0)*qr[j2*4+0] + (b2f(ku.y)+e1)*qr[j2*4+1]
                 + (b2f(ku.z)+e2)*qr[j2*4+2] + (b2f(ku.w)+e3)*qr[j2*4+3];
        }
        const float sc = (scp + __shfl_xor(scp, 1)) * kScaleN;
        float mn = fmaxf(m, sc);
        float c0 = __expf(m - mn);
        float pp = __expf(sc - mn);
        l = l*c0 + pp;
        #pragma unroll
        for (int j2 = 0; j2 < 4; ++j2) {
            ushort4 vu = *(const ushort4*)&vs[s][dbase + j2*4];
            acc[j2*4+0] = acc[j2*4+0]*c0 + pp*(b2f(vu.x)+er[j2*4+0]);
            acc[j2*4+1] = acc[j2*4+1]*c0 + pp*(b2f(vu.y)+er[j2*4+1]);
            acc[j2*4+2] = acc[j2*4+2]*c0 + pp*(b2f(vu.z)+er[j2*4+2]);
            acc[j2*4+3] = acc[j2*4+3]*c0 + pp*(b2f(vu.w)+er[j2*4+3]);
        }
        m = mn; f = fn;
    }
    if (part == 0) { pb[wave][dstL][0] = m; pb[wave][dstL][1] = l; }
    #pragma unroll
    for (int d=0; d<16; ++d) pb[wave][dstL][2 + dbase + d] = acc[d];
    __syncthreads();
    // merge: thread (dstL2, grp) handles dims [grp*2, grp*2+2) of dst=qtr*32+dstL2
    {
        const int dstL2 = t & 31, grp = t >> 5;   // grp in [0,16)
        float mw[8], lw[8];
        #pragma unroll
        for (int w=0; w<8; ++w){ mw[w]=pb[w][dstL2][0]; lw[w]=pb[w][dstL2][1]; }
        float M = mw[0];
        #pragma unroll
        for (int w=1; w<8; ++w) M = fmaxf(M, mw[w]);
        float sw[8];
        float L = 0.f;
        #pragma unroll
        for (int w=0; w<8; ++w){ sw[w] = __expf(mw[w]-M); L += lw[w]*sw[w]; }
        const float inv = 1.f / fmaxf(L, 1e-30f);
        size_t base = ((size_t)(b*128 + qtr*32 + dstL2))*kND + h*32 + grp*2;
        #pragma unroll
        for (int d=0; d<2; ++d) {
            float a = 0.f;
            #pragma unroll
            for (int w=0; w<8; ++w) a += pb[w][dstL2][2+grp*2+d]*sw[w];
            o[base + d] = f2b(a*inv);
        }
    }
}

// ---------------- local-graph GATHER attention (heads 4..7), LDS-staged edge list ----------------
// kv: [4096][kKV] bf16: local head h (0..3): K at 256+h*64, V at 256+h*64+32 (adjacent)
__global__ __launch_bounds__(256) void loc_gather_k(
    const float* __restrict__ q, const ush* __restrict__ kv,
    const ush* __restrict__ lg, const int* __restrict__ gsrc,
    const int* __restrict__ rowp, const int* __restrict__ eidl,
    ush* __restrict__ o)
{
    __shared__ int eids[192], srcs[192];
    const int n = blockIdx.x;
    const int beg = rowp[n], end = rowp[n+1];
    const int deg = end - beg;
    {
        const int tc = threadIdx.x;
        const int dc = (deg < 192) ? deg : 192;
        if (tc < dc) { int e = eidl[beg + tc]; eids[tc] = e; srcs[tc] = gsrc[e]; }
    }
    __syncthreads();
    const int h = threadIdx.x >> 6;
    const int lane = threadIdx.x & 63;
    const int g = lane >> 4;
    const int d0 = (lane & 15) * 2;
    const size_t hoff = (size_t)(4 + h) * 32 + d0;
    const float2 q2 = *(const float2*)&q[(size_t)n*256 + hoff];
    float m = -1e30f, l = 0.f, ax = 0.f, ay = 0.f;
    if (deg > 0) {
        const int nIter = (deg + 3) >> 2;
        int idx = beg + g;
        for (int it = 0; it < nIter; ++it) {
            const bool valid = idx < end;
            const int ii = min(idx, end-1) - beg;
            int e, s;
            if (ii < 192) { e = eids[ii]; s = srcs[ii]; }
            else          { e = eidl[beg + ii]; s = gsrc[e]; }
            idx += 4;
            const ushort2 ku = *(const ushort2*)&kv[(size_t)s*kKV + 256 + h*64 + d0];
            const ushort2 lvu = *(const ushort2*)&lg[(size_t)e*32 + d0];
            const ushort2 vu = *(const ushort2*)&kv[(size_t)s*kKV + 256 + h*64 + 32 + d0];
            const float lvx = b2f(lvu.x), lvy = b2f(lvu.y);
            float part = (b2f(ku.x)+lvx)*q2.x + (b2f(ku.y)+lvy)*q2.y;
            part += __shfl_xor(part, 1);
            part += __shfl_xor(part, 2);
            part += __shfl_xor(part, 4);
            part += __shfl_xor(part, 8);
            const float sc = part * kScaleN;
            const float mn = valid ? fmaxf(m, sc) : m;
            const float c  = __expf(m - mn);
            const float pp = valid ? __expf(sc - mn) : 0.f;
            l  = l*c  + pp;
            ax = ax*c + pp*(b2f(vu.x)+lvx);
            ay = ay*c + pp*(b2f(vu.y)+lvy);
            m  = mn;
        }
        #pragma unroll
        for (int off = 16; off <= 32; off <<= 1) {
            const float mo = __shfl_xor(m, off);
            const float lo = __shfl_xor(l, off);
            const float xo = __shfl_xor(ax, off);
            const float yo = __shfl_xor(ay, off);
            const float M  = fmaxf(m, mo);
            const float c1 = __expf(m - M);
            const float c2 = __expf(mo - M);
            l  = l*c1  + lo*c2;
            ax = ax*c1 + xo*c2;
            ay = ay*c1 + yo*c2;
            m  = M;
        }
    }
    if (g == 0) {
        const float inv = 1.f / fmaxf(l, 1e-30f);
        *(ushort2*)&o[(size_t)n*kND + hoff] = make_ushort2(f2b(ax*inv), f2b(ay*inv));
    }
}

// ---------------- fused line-graph attention + Wo GEMM + LN (bf16 in/out) ----------------
// ekv: [el][64] interleaved; src indices LDS-staged (contiguous eid window per 32 dsts)
__global__ __launch_bounds__(256) void lgs_ewo_k(
    const ush* __restrict__ eq, const ush* __restrict__ ekv,
    const int* __restrict__ lsrc, const int* __restrict__ rowp, const int* __restrict__ eidl,
    const ush* __restrict__ res,
    const ush* __restrict__ WO, size_t wooff, const void* __restrict__ bo, size_t booff,
    const void* __restrict__ g1, const void* __restrict__ be1, size_t g1off,
    ush* __restrict__ out, const int* __restrict__ flag)
{
    __shared__ __align__(16) ush ows[32*40];
    __shared__ __align__(16) ush wos[32*40];
    __shared__ float cs[32][36];
    __shared__ float bos[32], gs[32], bs[32];
    __shared__ int srcs[256];
    const int isbf = *flag;
    const int t = threadIdx.x;
    const int base = blockIdx.x * 32;
    {
        int n = t >> 3, k4 = (t & 7) * 4;
        *(ushort4*)&wos[n*40 + k4] = *(const ushort4*)&WO[wooff + (size_t)n*32 + k4];
    }
    if (t < 32) {
        bos[t] = ldf(bo, booff + t, isbf);
        gs[t]  = ldf(g1, g1off + t, isbf);
        bs[t]  = ldf(be1, g1off + t, isbf);
    }
    // ---- stage src indices for this block's contiguous edge window ----
    const int beg0 = rowp[base];
    {
        int cnt = rowp[base + 32] - beg0;
        if (cnt > 256) cnt = 256;
        for (int j = t; j < cnt; j += 256) srcs[j] = lsrc[eidl[beg0 + j]];
    }
    __syncthreads();
    // ---- phase 1: gather attention, thread = (dst-edge, head) ----
    {
        const int d2 = base + (t >> 3), h = t & 7;
        const ushort4 qu = *(const ushort4*)&eq[(size_t)d2*32 + h*4];
        const float q0 = b2f(qu.x), q1 = b2f(qu.y), q2 = b2f(qu.z), q3 = b2f(qu.w);
        const int beg = rowp[d2], end = rowp[d2+1];
        float m = -1e30f, l = 0.f;
        float4 acc = make_float4(0.f,0.f,0.f,0.f);
        for (int i = beg; i < end; ++i) {
            const int io = i - beg0;
            const int s = (io < 256) ? srcs[io] : lsrc[eidl[i]];
            const uint4 kv8 = *(const uint4*)&ekv[(size_t)s*64 + h*8];   // k4|v4, 16B
            const ush k0 = (ush)(kv8.x & 0xffff), k1 = (ush)(kv8.x >> 16);
            const ush k2 = (ush)(kv8.y & 0xffff), k3 = (ush)(kv8.y >> 16);
            const ush v0u = (ush)(kv8.z & 0xffff), v1u = (ush)(kv8.z >> 16);
            const ush v2u = (ush)(kv8.w & 0xffff), v3u = (ush)(kv8.w >> 16);
            float sc = (b2f(k0)*q0 + b2f(k1)*q1 + b2f(k2)*q2 + b2f(k3)*q3) * 0.5f;
            float mn = fmaxf(m, sc);
            float c = __expf(m - mn);
            float pp = __expf(sc - mn);
            l = l*c + pp;
            acc.x = acc.x*c + pp*b2f(v0u);
            acc.y = acc.y*c + pp*b2f(v1u);
            acc.z = acc.z*c + pp*b2f(v2u);
            acc.w = acc.w*c + pp*b2f(v3u);
            m = mn;
        }
        const float inv = 1.f / fmaxf(l, 1e-30f);
        const int r = t >> 3, c0 = h*4;
        ows[r*40 + c0 + 0] = f2b(acc.x*inv);
        ows[r*40 + c0 + 1] = f2b(acc.y*inv);
        ows[r*40 + c0 + 2] = f2b(acc.z*inv);
        ows[r*40 + c0 + 3] = f2b(acc.w*inv);
    }
    __syncthreads();
    // ---- phase 2: 32x32 GEMM ----
    {
        const int wave = t >> 6, l15 = t & 15, quad = (t >> 4) & 3;
        const int mt = wave & 1, nt = wave >> 1;
        frag_ab af = *(const frag_ab*)&ows[(mt*16 + l15)*40 + quad*8];
        frag_ab bf = *(const frag_ab*)&wos[(nt*16 + l15)*40 + quad*8];
        frag_cd acc = {0.f, 0.f, 0.f, 0.f};
        acc = __builtin_amdgcn_mfma_f32_16x16x32_bf16(af, bf, acc, 0, 0, 0);
        #pragma unroll
        for (int rg = 0; rg < 4; ++rg) {
            const int row = mt*16 + quad*4 + rg;
            const int col = nt*16 + l15;
            cs[row][col] = acc[rg] + bos[col] + b2f(res[(size_t)(base+row)*32 + col]);
        }
    }
    __syncthreads();
    // ---- phase 3: LN per row ----
    {
        const int row = t >> 3, c0 = (t & 7) * 4;
        const float v0 = cs[row][c0], v1 = cs[row][c0+1];
        const float v2 = cs[row][c0+2], v3 = cs[row][c0+3];
        float s = v0+v1+v2+v3;
        s += __shfl_xor(s,1); s += __shfl_xor(s,2); s += __shfl_xor(s,4);
        const float mean = s * (1.f/32.f);
        float qq = (v0-mean)*(v0-mean)+(v1-mean)*(v1-mean)
                 + (v2-mean)*(v2-mean)+(v3-mean)*(v3-mean);
        qq += __shfl_xor(qq,1); qq += __shfl_xor(qq,2); qq += __shfl_xor(qq,4);
        const float inv = rsqrtf(qq * (1.f/32.f) + 1e-5f);
        out[(size_t)(base+row)*32 + c0 + 0] = f2b((v0-mean)*inv*gs[c0+0] + bs[c0+0]);
        out[(size_t)(base+row)*32 + c0 + 1] = f2b((v1-mean)*inv*gs[c0+1] + bs[c0+1]);
        out[(size_t)(base+row)*32 + c0 + 2] = f2b((v2-mean)*inv*gs[c0+2] + bs[c0+2]);
        out[(size_t)(base+row)*32 + c0 + 3] = f2b((v3-mean)*inv*gs[c0+3] + bs[c0+3]);
    }
}

// ---------------- host helper ----------------
static inline void mgemm(const float* A, const ush* WT, const void* bias, size_t boff,
                         float* C, const int* flag, int M, int N, int K, int flags,
                         hipStream_t s, ush* aux, ush* aux2, int splitz = 1){
    dim3 grid((N+63)/64, M/64, splitz);
    mgemm_k<<<grid, 256, 0, s>>>(A, WT, bias, boff, C, flag, M, N, K, flags, aux, aux2);
}

extern "C" void kernel_launch(void* const* d_in, const int* in_sizes, int n_in,
                              void* d_out, int out_size, void* d_ws, size_t ws_size,
                              hipStream_t stream) {
    const void* x_in      = d_in[0];
    const void* rel       = d_in[1];
    const int* g_src      = (const int*)d_in[4];
    const int* g_dst      = (const int*)d_in[5];
    const int* lg_src     = (const int*)d_in[6];
    const int* lg_dst     = (const int*)d_in[7];
    const int* edge_feat  = (const int*)d_in[8];
    const int* full_feat  = (const int*)d_in[9];
    const void* n_Wq   = d_in[10];
    const void* n_bq   = d_in[11];
    const void* n_Wk   = d_in[12];
    const void* n_bk   = d_in[13];
    const void* n_Wv   = d_in[14];
    const void* n_bv   = d_in[15];
    const void* n_Wo   = d_in[16];
    const void* n_bo   = d_in[17];
    const void* n_lng  = d_in[18];
    const void* n_lnb  = d_in[19];
    const void* n_fW1  = d_in[20];
    const void* n_fb1  = d_in[21];
    const void* n_fW2  = d_in[22];
    const void* n_fb2  = d_in[23];
    const void* n_flng = d_in[24];
    const void* n_flnb = d_in[25];
    const void* e_Wsrc = d_in[26];
    const void* e_Wdst = d_in[27];
    const void* e_Wq   = d_in[28];
    const void* e_bq   = d_in[29];
    const void* e_Wk   = d_in[30];
    const void* e_Wv   = d_in[31];
    const void* e_Wo   = d_in[32];
    const void* e_bo   = d_in[33];
    const void* e_lng  = d_in[34];
    const void* e_lnb  = d_in[35];
    const void* e_fW1  = d_in[36];
    const void* e_fb1  = d_in[37];
    const void* e_fW2  = d_in[38];
    const void* e_fb2  = d_in[39];
    const void* e_flng = d_in[40];
    const void* e_flnb = d_in[41];

    // ---- workspace carve-up (units: floats) ----
    float* p = (float*)d_ws;
    size_t off = 0;
    auto AL = [&](size_t n){ float* r = p + off; off += n; return r; };
    int* flagp = (int*)AL(64);
    float* xA   = AL((size_t)kN*kND);
    float* xB   = AL((size_t)kN*kND);
    float* xM   = AL((size_t)kN*kND);
    ush*   xAb  = (ush*)AL((size_t)kN*kND/2);
    ush*   xBb  = (ush*)AL((size_t)kN*kND/2);
    ush*   xMb  = (ush*)AL((size_t)kN*kND/2);
    float* qkvb = AL((size_t)kN*kND);            // fp32 Q only, [4096][256]
    ush*   kvaux= (ush*)AL((size_t)kN*kKV/2);    // bf16 [4096][512]: interleaved K/V
    ush*   xsdb = (ush*)AL((size_t)kN*32);       // bf16 [4096][64]: compact SD
    ush*   ob   = (ush*)AL((size_t)kN*kND/2);
    float* tN   = AL((size_t)kN*kND*2);          // split-K partials (2x)
    ush*   nh   = (ush*)AL((size_t)kN*512);      // kN*1024 bf16
    ush*   lgA  = (ush*)AL((size_t)kEL*kED/2);   // bf16 edge residual chain
    ush*   lgB  = (ush*)AL((size_t)kEL*kED/2);
    ush*   lgM  = (ush*)AL((size_t)kEL*kED/2);
    ush*   eqb  = (ush*)AL((size_t)kEL*16);      // kEL*32 bf16
    ush*   ekvb = (ush*)AL((size_t)kEL*32);      // kEL*64 bf16 interleaved K/V
    // CSR structures
    int* cntL  = (int*)AL(kN);
    int* rowL  = (int*)AL(kN + 64);
    int* curL  = (int*)AL(kN);
    int* eidL  = (int*)AL(kEL);
    int* cntG  = (int*)AL(kEL);
    int* rowG  = (int*)AL(kEL + 64);
    int* curG  = (int*)AL(kEL);
    int* eidG  = (int*)AL(kELG);
    int* bsum  = (int*)AL(256);
    // pre-transposed bf16 weights
    ush* wtQKVSD = (ush*)AL(212992);   // [L][832][256] bf16 (425984 ush)
    float* bQKV  = AL(2*kQW);
    ush* wtO  = (ush*)AL(65536);
    ush* wtF1 = (ush*)AL(262144);
    ush* wtF2 = (ush*)AL(262144);
    ush* wtEQKV = (ush*)AL(3072);
    ush* wtEO   = (ush*)AL(1024);
    ush* wtEF1  = (ush*)AL(4096);
    ush* wtEF2  = (ush*)AL(4096);
    if (ws_size < off * sizeof(float)) return;

    float* tN2 = tN + (size_t)kN*kND;

    detect_k<<<1, 64, 0, stream>>>((const ush*)x_in, flagp);
    {
        long total = (long)kN*kND + (long)kEL*kED + 2*kQW + kN + kEL;
        int blocks = (int)((total + 255) / 256);
        setup_misc_k<<<blocks, 256, 0, stream>>>(x_in, rel, edge_feat, n_bq, n_bk, n_bv,
                                                 xA, xAb, lgA, bQKV, cntL, cntG, flagp);
    }
    trans_tiled_k<<<1592, 256, 0, stream>>>(n_Wq, n_Wk, n_Wv, n_Wo, n_fW1, n_fW2,
                                            e_Wsrc, e_Wdst, e_Wq, e_Wk, e_Wv, e_Wo,
                                            e_fW1, e_fW2, flagp,
                                            wtQKVSD, wtO, wtF1, wtF2,
                                            wtEQKV, wtEO, wtEF1, wtEF2);

    count2_k<<<(kEL+kELG)/256, 256, 0, stream>>>(g_dst, lg_dst, cntL, cntG);
    scan_blk2_k<<<132, 256, 0, stream>>>(cntL, cntG, rowL, rowG, bsum);
    scan_top2_k<<<1, 256, 0, stream>>>(bsum);
    scan_add2_k<<<(kN+kEL)/256, 256, 0, stream>>>(rowL, rowG, bsum, curL, curG);
    fill2_k<<<(kEL+kELG)/256, 256, 0, stream>>>(g_dst, lg_dst, curL, curG, eidL, eidG);

    float* xc = xA;  float* xn = xB;
    ush* xcb = xAb;  ush* xnb = xBb;
    ush* lgc = lgA;  ush* lgn = lgB;

    for (int i = 0; i < kL; ++i) {
        const size_t o256 = (size_t)i*kND;
        const size_t o1024= (size_t)i*1024;
        const size_t o32  = (size_t)i*kED;
        const size_t o128 = (size_t)i*128;
        const bool last = (i == kL - 1);

        // ===== node update (fp32 Q + bf16 K/V + compact SD side-outputs) =====
        mgemm((const float*)xcb, wtQKVSD + (size_t)i*212992, bQKV, (size_t)i*kQW, qkvb,
              flagp, kN, kQW, kND, 4|16|32|64, stream, kvaux, xsdb);
        full_attn_k<<<512, 512, 0, stream>>>(qkvb, kvaux, rel, full_feat, ob, flagp);
        loc_gather_k<<<kN, 256, 0, stream>>>(qkvb, kvaux, lgc, g_src, rowL, eidL, ob);
        mgemm((const float*)ob, wtO + (size_t)i*65536, n_bo, o256, tN, flagp,
              kN, kND, kND, 4|32|128, stream, nullptr, nullptr, 2);
        ln_k<<<kN/4, 256, 0, stream>>>(xc, tN, tN2, n_lng, n_lnb, o256, xM, xMb,
                                       nullptr, flagp, kND);
        mgemm((const float*)xMb, wtF1 + (size_t)i*262144, n_fb1, o1024, (float*)nh, flagp,
              kN, 1024, kND, 4|2|8|32, stream, nullptr, nullptr);
        mgemm((const float*)nh, wtF2 + (size_t)i*262144, n_fb2, o256, tN, flagp,
              kN, kND, 1024, 4|32|128, stream, nullptr, nullptr, 2);
        ln_k<<<kN/4, 256, 0, stream>>>(xM, tN, tN2, n_flng, n_flnb, o256, xn, xnb,
                                       last ? d_out : nullptr, flagp, kND);

        // ===== edge update (uses PRE-update xc, lgc) =====
        eqkv_mfma_k<<<kEL/128, 256, 0, stream>>>(lgc, xsdb, g_src, g_dst,
                                                 wtEQKV, (size_t)i*1024, e_bq, o32,
                                                 eqb, ekvb, flagp);
        lgs_ewo_k<<<kEL/32, 256, 0, stream>>>(eqb, ekvb, lg_src, rowG, eidG,
                                              lgc, wtEO, (size_t)i*1024, e_bo, o32,
                                              e_lng, e_lnb, o32, lgM, flagp);
        effn_mfma_k<<<kEL/128, 256, 0, stream>>>(lgM, wtEF1, (size_t)i*4096, e_fb1, o128,
                                                 wtEF2, (size_t)i*4096, e_fb2, o32,
                                                 e_flng, e_flnb, o32, lgn,
                                                 last ? d_out : nullptr, flagp);

        { float* t = xc; xc = xn; xn = t; }
        { ush* t = xcb; xcb = xnb; xnb = t; }
        { ush* t = lgc; lgc = lgn; lgn = t; }
    }
}

// Round 23
// 497.614 us; speedup vs baseline: 1.1164x; 1.0167x over previous
//
#include <hip/hip_runtime.h>
#include <hip/hip_bf16.h>

typedef __hip_bfloat16 bf16;
typedef unsigned short ush;

static constexpr int kN   = 4096;    // nodes
static constexpr int kND  = 256;     // hidden
static constexpr int kEL  = 131072;  // local edges
static constexpr int kED  = 32;      // edge dim
static constexpr int kELG = 262144;  // line-graph edges
static constexpr int kL   = 2;
static constexpr int kQW  = 832;     // packed qkv+sd GEMM width
static constexpr int kKV  = 512;     // kvaux row stride (bf16), per-head interleaved K/V
static constexpr float kScaleN = 0.17677669529663687f; // 1/sqrt(32)

using frag_ab = __attribute__((ext_vector_type(8))) short;   // 8 bf16 (4 VGPRs)
using frag_cd = __attribute__((ext_vector_type(4))) float;   // 4 fp32

__device__ __forceinline__ float ldf(const void* p, size_t i, int isbf){
    return isbf ? __bfloat162float(((const bf16*)p)[i]) : ((const float*)p)[i];
}
__device__ __forceinline__ ush f2b(float f){ bf16 h = __float2bfloat16(f); return *(ush*)&h; }
__device__ __forceinline__ float b2f(ush u){ return __uint_as_float(((unsigned)u)<<16); }
__device__ __forceinline__ ush ldb(const void* p, size_t i, int isbf){
    return isbf ? ((const ush*)p)[i] : f2b(((const float*)p)[i]);
}

// ---------------- dtype detection (wave-parallel) ----------------
__global__ void detect_k(const ush* __restrict__ xin, int* __restrict__ flag){
    const int t = threadIdx.x;              // 64 threads
    int pl = 0;
    for (int i = t; i < 128; i += 64) {
        ush u = xin[i];
        int e = (u >> 7) & 0xFF;
        if (e == 0 || (e >= 110 && e <= 140)) ++pl;
    }
    #pragma unroll
    for (int off = 32; off > 0; off >>= 1) pl += __shfl_down(pl, off);
    if (t == 0) *flag = (pl >= 102) ? 1 : 0;
}

// ---------------- fused setup (vectorized x4): cast x, init lg, pack bias, zero counters ----------------
__global__ void setup_misc_k(const void* __restrict__ xin, const void* __restrict__ rel,
                             const int* __restrict__ feat,
                             const void* __restrict__ bq, const void* __restrict__ bk,
                             const void* __restrict__ bv,
                             float* __restrict__ xA, ush* __restrict__ xAb,
                             ush* __restrict__ lgA,
                             float* __restrict__ bQKV,
                             int* __restrict__ cntL, int* __restrict__ cntG,
                             const int* __restrict__ flag){
    const int isbf = *flag;
    long g = (long)blockIdx.x*256 + threadIdx.x;
    if (g < (long)kN*kND/4) {                     // x cast, 4 elems/thread
        const size_t i = (size_t)g * 4;
        float4 v;
        if (isbf) {
            ushort4 u = *(const ushort4*)((const ush*)xin + i);
            v = make_float4(b2f(u.x), b2f(u.y), b2f(u.z), b2f(u.w));
        } else {
            v = *(const float4*)((const float*)xin + i);
        }
        *(float4*)&xA[i] = v;
        *(ushort4*)&xAb[i] = make_ushort4(f2b(v.x), f2b(v.y), f2b(v.z), f2b(v.w));
        return;
    }
    g -= (long)kN*kND/4;
    if (g < (long)kEL*kED/4) {                    // lg init, 4 contiguous dims of one edge
        int e = (int)(g >> 3), d4 = (int)(g & 7) * 4;
        const size_t src = (size_t)feat[e]*kED + d4;
        ushort4 u;
        if (isbf) u = *(const ushort4*)((const ush*)rel + src);
        else {
            float4 rf = *(const float4*)((const float*)rel + src);
            u = make_ushort4(f2b(rf.x), f2b(rf.y), f2b(rf.z), f2b(rf.w));
        }
        *(ushort4*)&lgA[(size_t)e*kED + d4] = u;
        return;
    }
    g -= (long)kEL*kED/4;
    if (g < 2*kQW) {
        int layer = (int)(g / kQW), j = (int)(g - (long)layer*kQW);
        float v = 0.f;
        if (j < 768) { int w = j >> 8, jj = j & 255;
            const void* B = (w==0)?bq:((w==1)?bk:bv);
            v = ldf(B, (size_t)layer*256 + jj, isbf); }
        bQKV[g] = v; return;
    }
    g -= 2*kQW;
    if (g < kN) { cntL[g] = 0; return; }
    g -= kN;
    if (g < kEL) { cntG[g] = 0; return; }
}

// ---------------- ALL weight pre-transposes: 32x32 LDS-tiled, coalesced both sides ----------------
__global__ __launch_bounds__(256) void trans_tiled_k(
    const void* __restrict__ nWq, const void* __restrict__ nWk, const void* __restrict__ nWv,
    const void* __restrict__ nWo, const void* __restrict__ nF1, const void* __restrict__ nF2,
    const void* __restrict__ eWs, const void* __restrict__ eWd,
    const void* __restrict__ eWq, const void* __restrict__ eWk, const void* __restrict__ eWv,
    const void* __restrict__ eWo, const void* __restrict__ eF1, const void* __restrict__ eF2,
    const int* __restrict__ flag,
    ush* __restrict__ wtQKVSD, ush* __restrict__ wtO, ush* __restrict__ wtF1,
    ush* __restrict__ wtF2, ush* __restrict__ wtEQKV, ush* __restrict__ wtEO,
    ush* __restrict__ wtEF1, ush* __restrict__ wtEF2)
{
    __shared__ ush lds[32][33];
    const int isbf = *flag;
    int idx = blockIdx.x;
    const void* src; size_t soff; ush* dstp; size_t doff;
    int Ns, Kd, r0, c0;
    if (idx < 384) {                                    // nWq/nWk/nWv [L][256][256] -> QKVSD rows 0-767
        int w = idx >> 7, rem = idx & 127;
        int layer = rem >> 6, tile = rem & 63;
        r0 = (tile >> 3) << 5; c0 = (tile & 7) << 5;
        src = (w==0)?nWq:((w==1)?nWk:nWv); soff = (size_t)layer*65536;
        Ns = 256; Kd = 256;
        dstp = wtQKVSD; doff = (size_t)layer*212992 + (size_t)w*65536;
    } else if ((idx -= 384) < 32) {                     // eWs/eWd [L][256][32] -> rows 768-831
        int w = idx >> 4, rem = idx & 15;
        int layer = rem >> 3, tile = rem & 7;
        r0 = tile << 5; c0 = 0;
        src = w ? eWd : eWs; soff = (size_t)layer*8192;
        Ns = 32; Kd = 256;
        dstp = wtQKVSD; doff = (size_t)layer*212992 + (size_t)(768 + w*32)*256;
    } else if ((idx -= 32) < 128) {                     // nWo [L][256][256]
        int layer = idx >> 6, tile = idx & 63;
        r0 = (tile >> 3) << 5; c0 = (tile & 7) << 5;
        src = nWo; soff = (size_t)layer*65536; Ns = 256; Kd = 256;
        dstp = wtO; doff = (size_t)layer*65536;
    } else if ((idx -= 128) < 512) {                    // nF1 [L][256][1024] -> [L][1024][256]
        int layer = idx >> 8, tile = idx & 255;
        r0 = (tile >> 5) << 5; c0 = (tile & 31) << 5;
        src = nF1; soff = (size_t)layer*262144; Ns = 1024; Kd = 256;
        dstp = wtF1; doff = (size_t)layer*262144;
    } else if ((idx -= 512) < 512) {                    // nF2 [L][1024][256] -> [L][256][1024]
        int layer = idx >> 8, tile = idx & 255;
        r0 = (tile >> 3) << 5; c0 = (tile & 7) << 5;
        src = nF2; soff = (size_t)layer*262144; Ns = 256; Kd = 1024;
        dstp = wtF2; doff = (size_t)layer*262144;
    } else if ((idx -= 512) < 6) {                      // eWq/eWk/eWv [L][32][32]
        int w = idx >> 1, layer = idx & 1;
        r0 = 0; c0 = 0;
        src = (w==0)?eWq:((w==1)?eWk:eWv); soff = (size_t)layer*1024; Ns = 32; Kd = 32;
        dstp = wtEQKV; doff = (size_t)(w*2 + layer)*1024;
    } else if ((idx -= 6) < 2) {                        // eWo [L][32][32]
        r0 = 0; c0 = 0;
        src = eWo; soff = (size_t)idx*1024; Ns = 32; Kd = 32;
        dstp = wtEO; doff = (size_t)idx*1024;
    } else if ((idx -= 2) < 8) {                        // eF1 [L][32][128] -> [L][128][32]
        int layer = idx >> 2, tile = idx & 3;
        r0 = 0; c0 = tile << 5;
        src = eF1; soff = (size_t)layer*4096; Ns = 128; Kd = 32;
        dstp = wtEF1; doff = (size_t)layer*4096;
    } else {                                            // eF2 [L][128][32] -> [L][32][128]
        idx -= 8;
        int layer = idx >> 2, tile = idx & 3;
        r0 = tile << 5; c0 = 0;
        src = eF2; soff = (size_t)layer*4096; Ns = 32; Kd = 128;
        dstp = wtEF2; doff = (size_t)layer*4096;
    }
    const int t = threadIdx.x;
    const int c = t & 31, rb = t >> 5;
    #pragma unroll
    for (int p = 0; p < 4; ++p) {
        int r = rb + p*8;
        lds[r][c] = ldb(src, soff + (size_t)(r0 + r)*Ns + c0 + c, isbf);
    }
    __syncthreads();
    #pragma unroll
    for (int p = 0; p < 4; ++p) {
        int rr = rb + p*8;
        dstp[doff + (size_t)(c0 + rr)*Kd + r0 + c] = lds[c][rr];
    }
}

// ---------------- CSR build (both graphs fused) ----------------
__global__ void count2_k(const int* __restrict__ gd, const int* __restrict__ lgd,
                         int* __restrict__ cntL, int* __restrict__ cntG){
    int g = blockIdx.x*256 + threadIdx.x;
    if (g < kEL) atomicAdd(&cntL[gd[g]], 1);
    else if (g < kEL + kELG) atomicAdd(&cntG[lgd[g - kEL]], 1);
}
__global__ __launch_bounds__(256) void scan_blk2_k(
    const int* __restrict__ cntL, const int* __restrict__ cntG,
    int* __restrict__ rowL, int* __restrict__ rowG, int* __restrict__ bsum)
{
    __shared__ int s[256];
    const int t = threadIdx.x;
    const bool isL = blockIdx.x < 4;
    const int* cnt = isL ? cntL : cntG;
    int* out = isL ? rowL : rowG;
    const int blk = isL ? blockIdx.x : blockIdx.x - 4;
    const int n = isL ? kN : kEL;
    const int b0 = blk*1024;
    int v[4], pre[4], tsum = 0;
    #pragma unroll
    for (int j=0;j<4;++j){
        int idx = b0 + t*4 + j;
        v[j] = (idx < n) ? cnt[idx] : 0;
        pre[j] = tsum; tsum += v[j];
    }
    s[t] = tsum; __syncthreads();
    for (int off=1; off<256; off<<=1){
        int x = (t>=off) ? s[t-off] : 0;
        __syncthreads();
        s[t] += x;
        __syncthreads();
    }
    int texc = s[t] - tsum;
    #pragma unroll
    for (int j=0;j<4;++j){
        int idx = b0 + t*4 + j;
        if (idx < n) out[idx] = texc + pre[j];
    }
    if (t == 255) bsum[(isL ? 0 : 8) + blk] = s[255];
}
__global__ __launch_bounds__(256) void scan_top2_k(int* __restrict__ bsum){
    __shared__ int sL[256], sG[256];
    const int t = threadIdx.x;
    int vL = (t < 4)   ? bsum[t]     : 0;
    int vG = (t < 128) ? bsum[8 + t] : 0;
    sL[t] = vL; sG[t] = vG; __syncthreads();
    for (int off=1; off<256; off<<=1){
        int xL = (t>=off) ? sL[t-off] : 0;
        int xG = (t>=off) ? sG[t-off] : 0;
        __syncthreads();
        sL[t] += xL; sG[t] += xG;
        __syncthreads();
    }
    if (t < 4)   bsum[t]     = sL[t] - vL;
    if (t < 128) bsum[8 + t] = sG[t] - vG;
}
__global__ void scan_add2_k(int* __restrict__ rowL, int* __restrict__ rowG,
                            const int* __restrict__ bsum,
                            int* __restrict__ curL, int* __restrict__ curG){
    int g = blockIdx.x*256 + threadIdx.x;
    if (g < kN){ int v = rowL[g] + bsum[g >> 10]; rowL[g] = v; curL[g] = v; }
    else if (g < kN + kEL){ int gg = g - kN;
        int v = rowG[gg] + bsum[8 + (gg >> 10)]; rowG[gg] = v; curG[gg] = v; }
    if (g == 0){ rowL[kN] = kEL; rowG[kEL] = kELG; }
}
__global__ void fill2_k(const int* __restrict__ gd, const int* __restrict__ lgd,
                        int* __restrict__ curL, int* __restrict__ curG,
                        int* __restrict__ eidL, int* __restrict__ eidG){
    int g = blockIdx.x*256 + threadIdx.x;
    if (g < kEL){ int pos = atomicAdd(&curL[gd[g]], 1); eidL[pos] = g; }
    else if (g < kEL + kELG){ int gg = g - kEL;
        int pos = atomicAdd(&curG[lgd[gg]], 1); eidG[pos] = gg; }
}

// ---------------- MFMA GEMM: C[M,N] = A@WT^T + bias (opt relu); BK=64 ----------------
// WT: bf16 [N][K]. 64x64 tile, 4 waves. Requires K%(64*gridDim.z)==0, N%64==0.
// flags: 2=RELU, 4=has-bias, 8=bf16 out, 16=bias packed fp32, 32=A is bf16,
//        64=QKV split output (col<256 -> fp32 C; 256-767 -> bf16 aux interleaved; 768+ -> aux2),
//        128=split-K over gridDim.z (bias by z==0 only; fp32 partials at C + z*M*N)
__global__ __launch_bounds__(256) void mgemm_k(
    const float* __restrict__ A, const ush* __restrict__ WT,
    const void* __restrict__ bias, size_t boff,
    float* __restrict__ C, const int* __restrict__ flag,
    int M, int N, int K, int flags, ush* __restrict__ aux, ush* __restrict__ aux2)
{
    __shared__ __align__(16) ush As[64*72];
    __shared__ __align__(16) ush Ws[64*72];
    const int isbf = *flag;
    const int t = threadIdx.x;
    const int m0 = blockIdx.y*64, n0 = blockIdx.x*64;
    const int wave = t>>6, lane = t&63;
    const int quad = lane>>4, l15 = lane&15;
    const int r = t>>3, kq = (t&7)*8;      // rows r and r+32, 8 K-elems at kq
    const bool abf = flags & 32;
    const bool spk = flags & 128;
    const int Kc   = spk ? (K / gridDim.z) : K;
    const int koff = spk ? (blockIdx.z * Kc) : 0;

    frag_cd acc[4];
    #pragma unroll
    for (int tl=0; tl<4; ++tl)
        #pragma unroll
        for (int j=0;j<4;++j) acc[tl][j] = 0.f;

    const float* ap0 = A + (size_t)(m0+r)*K + koff + kq;
    const float* ap1 = A + (size_t)(m0+r+32)*K + koff + kq;
    const ush*   ab0 = (const ush*)A + (size_t)(m0+r)*K + koff + kq;
    const ush*   ab1 = (const ush*)A + (size_t)(m0+r+32)*K + koff + kq;
    const ush*   wp0 = WT + (size_t)(n0+r)*K + koff + kq;
    const ush*   wp1 = WT + (size_t)(n0+r+32)*K + koff + kq;

    float4 a00,a01,a10,a11; uint4 av0,av1, wv0,wv1;
    auto loadT = [&](int kk){
        if (abf) { av0 = *(const uint4*)(ab0+kk); av1 = *(const uint4*)(ab1+kk); }
        else { a00 = *(const float4*)(ap0+kk); a01 = *(const float4*)(ap0+kk+4);
               a10 = *(const float4*)(ap1+kk); a11 = *(const float4*)(ap1+kk+4); }
        wv0 = *(const uint4*)(wp0+kk); wv1 = *(const uint4*)(wp1+kk);
    };
    loadT(0);

    for (int kk = 0; kk < Kc; kk += 64) {
        if (abf) {
            *(uint4*)&As[r*72 + kq]        = av0;
            *(uint4*)&As[(r+32)*72 + kq]   = av1;
        } else {
            *(ushort4*)&As[r*72 + kq]       = make_ushort4(f2b(a00.x),f2b(a00.y),f2b(a00.z),f2b(a00.w));
            *(ushort4*)&As[r*72 + kq + 4]   = make_ushort4(f2b(a01.x),f2b(a01.y),f2b(a01.z),f2b(a01.w));
            *(ushort4*)&As[(r+32)*72 + kq]     = make_ushort4(f2b(a10.x),f2b(a10.y),f2b(a10.z),f2b(a10.w));
            *(ushort4*)&As[(r+32)*72 + kq + 4] = make_ushort4(f2b(a11.x),f2b(a11.y),f2b(a11.z),f2b(a11.w));
        }
        *(uint4*)&Ws[r*72 + kq]      = wv0;
        *(uint4*)&Ws[(r+32)*72 + kq] = wv1;
        __syncthreads();
        if (kk + 64 < Kc) loadT(kk + 64);
        frag_ab af0 = *(const frag_ab*)&As[(wave*16 + l15)*72 + quad*8];
        frag_ab af1 = *(const frag_ab*)&As[(wave*16 + l15)*72 + 32 + quad*8];
        #pragma unroll
        for (int tl = 0; tl < 4; ++tl) {
            frag_ab bf0 = *(const frag_ab*)&Ws[(tl*16 + l15)*72 + quad*8];
            acc[tl] = __builtin_amdgcn_mfma_f32_16x16x32_bf16(af0, bf0, acc[tl], 0, 0, 0);
            frag_ab bf1 = *(const frag_ab*)&Ws[(tl*16 + l15)*72 + 32 + quad*8];
            acc[tl] = __builtin_amdgcn_mfma_f32_16x16x32_bf16(af1, bf1, acc[tl], 0, 0, 0);
        }
        __syncthreads();
    }
    const bool do_relu = flags & 2;
    const bool has_b   = (flags & 4) && (!spk || blockIdx.z == 0);
    const bool obf     = flags & 8;
    float* Cz = spk ? (C + (size_t)blockIdx.z * M * N) : C;
    #pragma unroll
    for (int tl = 0; tl < 4; ++tl) {
        int col = n0 + tl*16 + l15;
        float bv = 0.f;
        if (has_b) bv = (flags & 16) ? ((const float*)bias)[boff + col]
                                     : ldf(bias, boff + col, isbf);
        // kvaux/xsd column mapping for QKV split output:
        int adst = -1; bool tox = false;
        if (flags & 64 && col >= 256) {
            int c = col - 256;
            if (c < 512) {
                int isv = c >> 8;            // 0 = K, 1 = V
                int cc = c & 255;
                int h = cc >> 5, d = cc & 31;
                int base = (h < 4) ? h*64 : 256 + (h-4)*64;
                adst = base + isv*32 + d;
            } else { adst = c - 512; tox = true; }   // SD -> compact xsd [row][64]
        }
        #pragma unroll
        for (int rg = 0; rg < 4; ++rg) {
            int row = m0 + wave*16 + quad*4 + rg;
            float v = acc[tl][rg] + bv;
            if (do_relu) v = fmaxf(v, 0.f);
            if (flags & 64) {
                if (col < 256)  C[(size_t)row*256 + col] = v;
                else if (tox)   aux2[(size_t)row*64 + adst] = f2b(v);
                else            aux[(size_t)row*kKV + adst] = f2b(v);
            } else if (obf) ((ush*)C)[(size_t)row*N + col] = f2b(v);
            else            Cz[(size_t)row*N + col] = v;
        }
    }
}

// ---------------- LayerNorm (node rows, D=256): out = LN(a + b [+ b2]), dual f32+bf16 ----------------
// 4 rows/block, wave per row. b2 nullable. fin nullable: also write final output (dtype by flag).
__global__ __launch_bounds__(256) void ln_k(
    const float* __restrict__ a, const float* __restrict__ b, const float* __restrict__ b2,
    const void* __restrict__ g, const void* __restrict__ be, size_t goff,
    float* __restrict__ out, ush* __restrict__ outb,
    void* __restrict__ fin,
    const int* __restrict__ flag, int D)
{
    const int isbf = *flag;
    const int row = blockIdx.x*4 + (threadIdx.x >> 6);
    const int t = threadIdx.x & 63;
    float v[4];
    int cnt = 0;
    float s = 0.f;
    for (int i = t; i < D; i += 64) {
        float x = a[(size_t)row*D + i];
        if (b)  x += b[(size_t)row*D + i];
        if (b2) x += b2[(size_t)row*D + i];
        v[cnt++] = x; s += x;
    }
    #pragma unroll
    for (int off = 32; off > 0; off >>= 1) s += __shfl_down(s, off);
    s = __shfl(s, 0);
    const float mean = s / D;
    float qq = 0.f;
    for (int c2 = 0; c2 < cnt; ++c2) { float d = v[c2]-mean; qq += d*d; }
    #pragma unroll
    for (int off = 32; off > 0; off >>= 1) qq += __shfl_down(qq, off);
    qq = __shfl(qq, 0);
    const float inv = rsqrtf(fmaxf(qq, 0.f) / D + 1e-5f);
    cnt = 0;
    for (int i = t; i < D; i += 64) {
        float r = (v[cnt++] - mean)*inv*ldf(g, goff + i, isbf) + ldf(be, goff + i, isbf);
        out[(size_t)row*D + i] = r;
        outb[(size_t)row*D + i] = f2b(r);
        if (fin) {
            if (isbf) ((ush*)fin)[(size_t)row*D + i] = f2b(r);
            else      ((float*)fin)[(size_t)row*D + i] = r;
        }
    }
}

// ---------------- MFMA eq/ekv (+gathered mixed), 128 rows/block, bf16 in/out ----------------
// xsd: compact [4096][64] bf16 (src at 0-31, dst at 32-63). Vectorized staging.
// Output: eq [el][32]; ekv [el][64] interleaved (k_h at h*8, v_h at h*8+4).
__global__ __launch_bounds__(256) void eqkv_mfma_k(
    const ush* __restrict__ lg, const ush* __restrict__ xsd,
    const int* __restrict__ gsrc, const int* __restrict__ gdst,
    const ush* __restrict__ WQKV, size_t woff,
    const void* __restrict__ bq, size_t boff,
    ush* __restrict__ eq, ush* __restrict__ ekv,
    const int* __restrict__ flag)
{
    __shared__ __align__(16) ush mixs[128*40];
    __shared__ __align__(16) ush wts[3][32*40];
    __shared__ float bqs[32];
    const int isbf = *flag;
    const int t = threadIdx.x;
    const int e0 = blockIdx.x * 128;
    #pragma unroll
    for (int i = t; i < 768; i += 256) {
        int m = i >> 8, r2 = i & 255;
        int n = r2 >> 3, k4 = (r2 & 7) * 4;
        *(ushort4*)&wts[m][n*40 + k4] =
            *(const ushort4*)&WQKV[(size_t)m*2048 + woff + (size_t)n*32 + k4];
    }
    if (t < 32) bqs[t] = ldf(bq, boff + t, isbf);
    {
        int r = t >> 1, c0 = (t & 1) * 16;
        int e = e0 + r;
        int s = gsrc[e], d2 = gdst[e];
        const ush* lp = lg  + (size_t)e*32  + c0;
        const ush* sp = xsd + (size_t)s*64  + c0;
        const ush* dp = xsd + (size_t)d2*64 + 32 + c0;
        uint4 lv0 = *(const uint4*)lp,     lv1 = *(const uint4*)(lp+8);
        uint4 sv0 = *(const uint4*)sp,     sv1 = *(const uint4*)(sp+8);
        uint4 dv0 = *(const uint4*)dp,     dv1 = *(const uint4*)(dp+8);
        auto pk = [](unsigned a, unsigned b, unsigned c)->unsigned {
            ush lo = f2b(b2f((ush)(a & 0xffff)) + b2f((ush)(b & 0xffff)) + b2f((ush)(c & 0xffff)));
            ush hi = f2b(b2f((ush)(a >> 16))    + b2f((ush)(b >> 16))    + b2f((ush)(c >> 16)));
            return (unsigned)lo | ((unsigned)hi << 16);
        };
        uint4 o0, o1;
        o0.x = pk(lv0.x, sv0.x, dv0.x); o0.y = pk(lv0.y, sv0.y, dv0.y);
        o0.z = pk(lv0.z, sv0.z, dv0.z); o0.w = pk(lv0.w, sv0.w, dv0.w);
        o1.x = pk(lv1.x, sv1.x, dv1.x); o1.y = pk(lv1.y, sv1.y, dv1.y);
        o1.z = pk(lv1.z, sv1.z, dv1.z); o1.w = pk(lv1.w, sv1.w, dv1.w);
        *(uint4*)&mixs[r*40 + c0]     = o0;
        *(uint4*)&mixs[r*40 + c0 + 8] = o1;
    }
    __syncthreads();
    const int wave = t >> 6, l15 = t & 15, quad = (t >> 4) & 3;
    #pragma unroll
    for (int mi = 0; mi < 2; ++mi) {
        const int mt = wave*2 + mi;
        frag_ab af = *(const frag_ab*)&mixs[(mt*16 + l15)*40 + quad*8];
        #pragma unroll
        for (int w = 0; w < 3; ++w) {
            #pragma unroll
            for (int nt = 0; nt < 2; ++nt) {
                frag_ab bf = *(const frag_ab*)&wts[w][(nt*16 + l15)*40 + quad*8];
                frag_cd acc = {0.f, 0.f, 0.f, 0.f};
                acc = __builtin_amdgcn_mfma_f32_16x16x32_bf16(af, bf, acc, 0, 0, 0);
                const float bv = (w==0) ? bqs[nt*16 + l15] : 0.f;
                const int col = nt*16 + l15;            // 0..31
                const int h = col >> 2, d = col & 3;
                #pragma unroll
                for (int rg = 0; rg < 4; ++rg) {
                    int row = e0 + mt*16 + quad*4 + rg;
                    float v = acc[rg] + bv;
                    if (w == 0)      eq[(size_t)row*32 + col] = f2b(v);
                    else if (w == 1) ekv[(size_t)row*64 + h*8 + d] = f2b(v);
                    else             ekv[(size_t)row*64 + h*8 + 4 + d] = f2b(v);
                }
            }
        }
    }
}

// ---------------- MFMA edge FFN: LN(A + relu(A@W1+b1)@W2 + b2); bf16 A / bf16 out ----------------
// fin nullable: also write final lg output at offset kN*kND (dtype by flag).
__global__ __launch_bounds__(256) void effn_mfma_k(
    const ush* __restrict__ A,
    const ush* __restrict__ W1T, size_t w1off, const void* __restrict__ b1, size_t b1off,
    const ush* __restrict__ W2T, size_t w2off, const void* __restrict__ b2, size_t b2off,
    const void* __restrict__ g, const void* __restrict__ be, size_t goff,
    ush* __restrict__ out, void* __restrict__ fin, const int* __restrict__ flag)
{
    __shared__ __align__(16) ush w1t[128*40];
    __shared__ __align__(16) ush w2t[32*136];
    __shared__ __align__(16) ush hid[64*136];
    __shared__ float b1s[128], b2s[32];
    const int isbf = *flag;
    const int t = threadIdx.x;
    const int wave = t >> 6, l15 = t & 15, quad = (t >> 4) & 3;

    #pragma unroll
    for (int i = t; i < 1024; i += 256) {
        int n1 = i >> 3, k4 = (i & 7) * 4;
        *(ushort4*)&w1t[n1*40 + k4] = *(const ushort4*)&W1T[w1off + (size_t)n1*32 + k4];
        int n2 = i >> 5, kq2 = (i & 31) * 4;
        *(ushort4*)&w2t[n2*136 + kq2] = *(const ushort4*)&W2T[w2off + (size_t)n2*128 + kq2];
    }
    if (t < 128) b1s[t] = ldf(b1, b1off + t, isbf);
    if (t < 32)  b2s[t] = ldf(b2, b2off + t, isbf);
    __syncthreads();

    const float g0  = ldf(g,  goff + l15, isbf),      g1v = ldf(g,  goff + 16 + l15, isbf);
    const float be0 = ldf(be, goff + l15, isbf),      be1 = ldf(be, goff + 16 + l15, isbf);
    const float bb0 = b2s[l15], bb1 = b2s[16 + l15];

    for (int tt = 0; tt < 2; ++tt) {
        const int e0 = (blockIdx.x*2 + tt) * 64;
        {
            const int m = wave*16 + l15;
            frag_ab af = *(const frag_ab*)&A[(size_t)(e0+m)*32 + quad*8];
            #pragma unroll
            for (int nt = 0; nt < 8; ++nt) {
                frag_ab bf = *(const frag_ab*)&w1t[(nt*16 + l15)*40 + quad*8];
                frag_cd acc = {0.f, 0.f, 0.f, 0.f};
                acc = __builtin_amdgcn_mfma_f32_16x16x32_bf16(af, bf, acc, 0, 0, 0);
                float bv = b1s[nt*16 + l15];
                #pragma unroll
                for (int rg = 0; rg < 4; ++rg) {
                    int row = wave*16 + quad*4 + rg;
                    hid[row*136 + nt*16 + l15] = f2b(fmaxf(acc[rg] + bv, 0.f));
                }
            }
        }
        // hid rows are wave-private -> no barrier needed
        frag_cd acc2[2] = {{0.f,0.f,0.f,0.f},{0.f,0.f,0.f,0.f}};
        #pragma unroll
        for (int ks = 0; ks < 4; ++ks) {
            frag_ab af2 = *(const frag_ab*)&hid[(wave*16 + l15)*136 + ks*32 + quad*8];
            #pragma unroll
            for (int tl = 0; tl < 2; ++tl) {
                frag_ab bf2 = *(const frag_ab*)&w2t[(tl*16 + l15)*136 + ks*32 + quad*8];
                acc2[tl] = __builtin_amdgcn_mfma_f32_16x16x32_bf16(af2, bf2, acc2[tl], 0, 0, 0);
            }
        }
        #pragma unroll
        for (int rg = 0; rg < 4; ++rg) {
            const int row = e0 + wave*16 + quad*4 + rg;
            float v0 = acc2[0][rg] + bb0 + b2f(A[(size_t)row*32 + l15]);
            float v1 = acc2[1][rg] + bb1 + b2f(A[(size_t)row*32 + 16 + l15]);
            float s = v0 + v1;
            s += __shfl_xor(s,1); s += __shfl_xor(s,2); s += __shfl_xor(s,4); s += __shfl_xor(s,8);
            const float mean = s * (1.f/32.f);
            float q = (v0-mean)*(v0-mean) + (v1-mean)*(v1-mean);
            q += __shfl_xor(q,1); q += __shfl_xor(q,2); q += __shfl_xor(q,4); q += __shfl_xor(q,8);
            const float inv = rsqrtf(q * (1.f/32.f) + 1e-5f);
            const ush u0 = f2b((v0-mean)*inv*g0  + be0);
            const ush u1 = f2b((v1-mean)*inv*g1v + be1);
            out[(size_t)row*32 + l15]      = u0;
            out[(size_t)row*32 + 16 + l15] = u1;
            if (fin) {
                const size_t base = (size_t)kN*kND + (size_t)row*32;
                if (isbf) {
                    ((ush*)fin)[base + l15]      = u0;
                    ((ush*)fin)[base + 16 + l15] = u1;
                } else {
                    ((float*)fin)[base + l15]      = b2f(u0);
                    ((float*)fin)[base + 16 + l15] = b2f(u1);
                }
            }
        }
    }
}

// ---------------- full-graph attention: (b,h,quarter) blocks, 512 grid (online softmax) ----------------
// q: fp32 [4096][256]; kv: bf16 [4096][kKV], full head h: K at h*64, V at h*64+32
__global__ __launch_bounds__(512) void full_attn_k(
    const float* __restrict__ q, const ush* __restrict__ kv,
    const void* __restrict__ rel, const int* __restrict__ feat, ush* __restrict__ o,
    const int* __restrict__ flag)
{
    __shared__ __align__(8) ush ks[128][36];
    __shared__ __align__(8) ush vs[128][36];
    __shared__ __align__(8) ush rs[128][36];
    __shared__ float pb[8][32][34];            // per-wave partials: m, l, acc[32]
    const int isbf = *flag;
    const int bid = blockIdx.x;
    const int b = bid >> 4, h = (bid >> 2) & 3, qtr = bid & 3;
    const int t = threadIdx.x;
    // vectorized staging: 4 elems/thread
    for (int i = t; i < 1024; i += 512) {
        int r = i >> 3, d4 = (i & 7) * 4;
        const ush* kvrow = kv + (size_t)(b*128 + r)*kKV + h*64 + d4;
        *(ushort4*)&ks[r][d4] = *(const ushort4*)kvrow;
        *(ushort4*)&vs[r][d4] = *(const ushort4*)(kvrow + 32);
        if (isbf) {
            *(ushort4*)&rs[r][d4] = *(const ushort4*)((const ush*)rel + r*32 + d4);
        } else {
            float4 rf = *(const float4*)((const float*)rel + r*32 + d4);
            *(ushort4*)&rs[r][d4] = make_ushort4(f2b(rf.x), f2b(rf.y), f2b(rf.z), f2b(rf.w));
        }
    }
    __syncthreads();
    const int wave = t >> 6, lane = t & 63;
    const int dstL = lane >> 1, part = lane & 1;   // 2 lanes per dst
    const int dst = qtr*32 + dstL;
    const int dbase = part*16;                     // this lane's 16 dims
    float qr[16];
    { size_t base = ((size_t)(b*128 + dst))*256 + h*32 + dbase;
      #pragma unroll
      for (int d=0; d<16; ++d) qr[d] = q[base + d]; }
    const int* fp = feat + (size_t)b*16384 + dst;
    const int s0 = wave*16;
    float m = -1e30f, l = 0.f;
    float acc[16];
    #pragma unroll
    for (int d=0; d<16; ++d) acc[d] = 0.f;
    int f = fp[s0*128];
    for (int sI = 0; sI < 16; ++sI) {
        const int s = s0 + sI;
        int fn = (sI+1 < 16) ? fp[(s+1)*128] : 0;
        float er[16];
        float scp = 0.f;
        #pragma unroll
        for (int j2 = 0; j2 < 4; ++j2) {
            ushort4 eu = *(const ushort4*)&rs[f][dbase + j2*4];
            ushort4 ku = *(const ushort4*)&ks[s][dbase + j2*4];
            float e0 = b2f(eu.x), e1 = b2f(eu.y), e2 = b2f(eu.z), e3 = b2f(eu.w);
            er[j2*4+0]=e0; er[j2*4+1]=e1; er[j2*4+2]=e2; er[j2*4+3]=e3;
            scp += (b2f(ku.x)+e0)*qr[j2*4+0] + (b2f(ku.y)+e1)*qr[j2*4+1]
                 + (b2f(ku.z)+e2)*qr[j2*4+2] + (b2f(ku.w)+e3)*qr[j2*4+3];
        }
        const float sc = (scp + __shfl_xor(scp, 1)) * kScaleN;
        float mn = fmaxf(m, sc);
        float c0 = __expf(m - mn);
        float pp = __expf(sc - mn);
        l = l*c0 + pp;
        #pragma unroll
        for (int j2 = 0; j2 < 4; ++j2) {
            ushort4 vu = *(const ushort4*)&vs[s][dbase + j2*4];
            acc[j2*4+0] = acc[j2*4+0]*c0 + pp*(b2f(vu.x)+er[j2*4+0]);
            acc[j2*4+1] = acc[j2*4+1]*c0 + pp*(b2f(vu.y)+er[j2*4+1]);
            acc[j2*4+2] = acc[j2*4+2]*c0 + pp*(b2f(vu.z)+er[j2*4+2]);
            acc[j2*4+3] = acc[j2*4+3]*c0 + pp*(b2f(vu.w)+er[j2*4+3]);
        }
        m = mn; f = fn;
    }
    if (part == 0) { pb[wave][dstL][0] = m; pb[wave][dstL][1] = l; }
    #pragma unroll
    for (int d=0; d<16; ++d) pb[wave][dstL][2 + dbase + d] = acc[d];
    __syncthreads();
    // merge: thread (dstL2, grp) handles dims [grp*2, grp*2+2) of dst=qtr*32+dstL2
    {
        const int dstL2 = t & 31, grp = t >> 5;   // grp in [0,16)
        float mw[8], lw[8];
        #pragma unroll
        for (int w=0; w<8; ++w){ mw[w]=pb[w][dstL2][0]; lw[w]=pb[w][dstL2][1]; }
        float M = mw[0];
        #pragma unroll
        for (int w=1; w<8; ++w) M = fmaxf(M, mw[w]);
        float sw[8];
        float L = 0.f;
        #pragma unroll
        for (int w=0; w<8; ++w){ sw[w] = __expf(mw[w]-M); L += lw[w]*sw[w]; }
        const float inv = 1.f / fmaxf(L, 1e-30f);
        size_t base = ((size_t)(b*128 + qtr*32 + dstL2))*kND + h*32 + grp*2;
        #pragma unroll
        for (int d=0; d<2; ++d) {
            float a = 0.f;
            #pragma unroll
            for (int w=0; w<8; ++w) a += pb[w][dstL2][2+grp*2+d]*sw[w];
            o[base + d] = f2b(a*inv);
        }
    }
}

// ---------------- local-graph GATHER attention (heads 4..7), LDS-staged edge list ----------------
// kv: [4096][kKV] bf16: local head h (0..3): K at 256+h*64, V at 256+h*64+32 (adjacent)
__global__ __launch_bounds__(256) void loc_gather_k(
    const float* __restrict__ q, const ush* __restrict__ kv,
    const ush* __restrict__ lg, const int* __restrict__ gsrc,
    const int* __restrict__ rowp, const int* __restrict__ eidl,
    ush* __restrict__ o)
{
    __shared__ int eids[192], srcs[192];
    const int n = blockIdx.x;
    const int beg = rowp[n], end = rowp[n+1];
    const int deg = end - beg;
    {
        const int tc = threadIdx.x;
        const int dc = (deg < 192) ? deg : 192;
        if (tc < dc) { int e = eidl[beg + tc]; eids[tc] = e; srcs[tc] = gsrc[e]; }
    }
    __syncthreads();
    const int h = threadIdx.x >> 6;
    const int lane = threadIdx.x & 63;
    const int g = lane >> 4;
    const int d0 = (lane & 15) * 2;
    const size_t hoff = (size_t)(4 + h) * 32 + d0;
    const float2 q2 = *(const float2*)&q[(size_t)n*256 + hoff];
    float m = -1e30f, l = 0.f, ax = 0.f, ay = 0.f;
    if (deg > 0) {
        const int nIter = (deg + 3) >> 2;
        int idx = beg + g;
        for (int it = 0; it < nIter; ++it) {
            const bool valid = idx < end;
            const int ii = min(idx, end-1) - beg;
            int e, s;
            if (ii < 192) { e = eids[ii]; s = srcs[ii]; }
            else          { e = eidl[beg + ii]; s = gsrc[e]; }
            idx += 4;
            const ushort2 ku = *(const ushort2*)&kv[(size_t)s*kKV + 256 + h*64 + d0];
            const ushort2 lvu = *(const ushort2*)&lg[(size_t)e*32 + d0];
            const ushort2 vu = *(const ushort2*)&kv[(size_t)s*kKV + 256 + h*64 + 32 + d0];
            const float lvx = b2f(lvu.x), lvy = b2f(lvu.y);
            float part = (b2f(ku.x)+lvx)*q2.x + (b2f(ku.y)+lvy)*q2.y;
            part += __shfl_xor(part, 1);
            part += __shfl_xor(part, 2);
            part += __shfl_xor(part, 4);
            part += __shfl_xor(part, 8);
            const float sc = part * kScaleN;
            const float mn = valid ? fmaxf(m, sc) : m;
            const float c  = __expf(m - mn);
            const float pp = valid ? __expf(sc - mn) : 0.f;
            l  = l*c  + pp;
            ax = ax*c + pp*(b2f(vu.x)+lvx);
            ay = ay*c + pp*(b2f(vu.y)+lvy);
            m  = mn;
        }
        #pragma unroll
        for (int off = 16; off <= 32; off <<= 1) {
            const float mo = __shfl_xor(m, off);
            const float lo = __shfl_xor(l, off);
            const float xo = __shfl_xor(ax, off);
            const float yo = __shfl_xor(ay, off);
            const float M  = fmaxf(m, mo);
            const float c1 = __expf(m - M);
            const float c2 = __expf(mo - M);
            l  = l*c1  + lo*c2;
            ax = ax*c1 + xo*c2;
            ay = ay*c1 + yo*c2;
            m  = M;
        }
    }
    if (g == 0) {
        const float inv = 1.f / fmaxf(l, 1e-30f);
        *(ushort2*)&o[(size_t)n*kND + hoff] = make_ushort2(f2b(ax*inv), f2b(ay*inv));
    }
}

// ---------------- fused line-graph attention + Wo GEMM + LN (bf16 in/out) ----------------
// ekv: [el][64] interleaved; src indices LDS-staged (contiguous eid window per 32 dsts)
__global__ __launch_bounds__(256) void lgs_ewo_k(
    const ush* __restrict__ eq, const ush* __restrict__ ekv,
    const int* __restrict__ lsrc, const int* __restrict__ rowp, const int* __restrict__ eidl,
    const ush* __restrict__ res,
    const ush* __restrict__ WO, size_t wooff, const void* __restrict__ bo, size_t booff,
    const void* __restrict__ g1, const void* __restrict__ be1, size_t g1off,
    ush* __restrict__ out, const int* __restrict__ flag)
{
    __shared__ __align__(16) ush ows[32*40];
    __shared__ __align__(16) ush wos[32*40];
    __shared__ float cs[32][36];
    __shared__ float bos[32], gs[32], bs[32];
    __shared__ int srcs[256];
    const int isbf = *flag;
    const int t = threadIdx.x;
    const int base = blockIdx.x * 32;
    {
        int n = t >> 3, k4 = (t & 7) * 4;
        *(ushort4*)&wos[n*40 + k4] = *(const ushort4*)&WO[wooff + (size_t)n*32 + k4];
    }
    if (t < 32) {
        bos[t] = ldf(bo, booff + t, isbf);
        gs[t]  = ldf(g1, g1off + t, isbf);
        bs[t]  = ldf(be1, g1off + t, isbf);
    }
    // ---- stage src indices for this block's contiguous edge window ----
    const int beg0 = rowp[base];
    {
        int cnt = rowp[base + 32] - beg0;
        if (cnt > 256) cnt = 256;
        for (int j = t; j < cnt; j += 256) srcs[j] = lsrc[eidl[beg0 + j]];
    }
    __syncthreads();
    // ---- phase 1: gather attention, thread = (dst-edge, head) ----
    {
        const int d2 = base + (t >> 3), h = t & 7;
        const ushort4 qu = *(const ushort4*)&eq[(size_t)d2*32 + h*4];
        const float q0 = b2f(qu.x), q1 = b2f(qu.y), q2 = b2f(qu.z), q3 = b2f(qu.w);
        const int beg = rowp[d2], end = rowp[d2+1];
        float m = -1e30f, l = 0.f;
        float4 acc = make_float4(0.f,0.f,0.f,0.f);
        for (int i = beg; i < end; ++i) {
            const int io = i - beg0;
            const int s = (io < 256) ? srcs[io] : lsrc[eidl[i]];
            const uint4 kv8 = *(const uint4*)&ekv[(size_t)s*64 + h*8];   // k4|v4, 16B
            const ush k0 = (ush)(kv8.x & 0xffff), k1 = (ush)(kv8.x >> 16);
            const ush k2 = (ush)(kv8.y & 0xffff), k3 = (ush)(kv8.y >> 16);
            const ush v0u = (ush)(kv8.z & 0xffff), v1u = (ush)(kv8.z >> 16);
            const ush v2u = (ush)(kv8.w & 0xffff), v3u = (ush)(kv8.w >> 16);
            float sc = (b2f(k0)*q0 + b2f(k1)*q1 + b2f(k2)*q2 + b2f(k3)*q3) * 0.5f;
            float mn = fmaxf(m, sc);
            float c = __expf(m - mn);
            float pp = __expf(sc - mn);
            l = l*c + pp;
            acc.x = acc.x*c + pp*b2f(v0u);
            acc.y = acc.y*c + pp*b2f(v1u);
            acc.z = acc.z*c + pp*b2f(v2u);
            acc.w = acc.w*c + pp*b2f(v3u);
            m = mn;
        }
        const float inv = 1.f / fmaxf(l, 1e-30f);
        const int r = t >> 3, c0 = h*4;
        ows[r*40 + c0 + 0] = f2b(acc.x*inv);
        ows[r*40 + c0 + 1] = f2b(acc.y*inv);
        ows[r*40 + c0 + 2] = f2b(acc.z*inv);
        ows[r*40 + c0 + 3] = f2b(acc.w*inv);
    }
    __syncthreads();
    // ---- phase 2: 32x32 GEMM ----
    {
        const int wave = t >> 6, l15 = t & 15, quad = (t >> 4) & 3;
        const int mt = wave & 1, nt = wave >> 1;
        frag_ab af = *(const frag_ab*)&ows[(mt*16 + l15)*40 + quad*8];
        frag_ab bf = *(const frag_ab*)&wos[(nt*16 + l15)*40 + quad*8];
        frag_cd acc = {0.f, 0.f, 0.f, 0.f};
        acc = __builtin_amdgcn_mfma_f32_16x16x32_bf16(af, bf, acc, 0, 0, 0);
        #pragma unroll
        for (int rg = 0; rg < 4; ++rg) {
            const int row = mt*16 + quad*4 + rg;
            const int col = nt*16 + l15;
            cs[row][col] = acc[rg] + bos[col] + b2f(res[(size_t)(base+row)*32 + col]);
        }
    }
    __syncthreads();
    // ---- phase 3: LN per row ----
    {
        const int row = t >> 3, c0 = (t & 7) * 4;
        const float v0 = cs[row][c0], v1 = cs[row][c0+1];
        const float v2 = cs[row][c0+2], v3 = cs[row][c0+3];
        float s = v0+v1+v2+v3;
        s += __shfl_xor(s,1); s += __shfl_xor(s,2); s += __shfl_xor(s,4);
        const float mean = s * (1.f/32.f);
        float qq = (v0-mean)*(v0-mean)+(v1-mean)*(v1-mean)
                 + (v2-mean)*(v2-mean)+(v3-mean)*(v3-mean);
        qq += __shfl_xor(qq,1); qq += __shfl_xor(qq,2); qq += __shfl_xor(qq,4);
        const float inv = rsqrtf(qq * (1.f/32.f) + 1e-5f);
        out[(size_t)(base+row)*32 + c0 + 0] = f2b((v0-mean)*inv*gs[c0+0] + bs[c0+0]);
        out[(size_t)(base+row)*32 + c0 + 1] = f2b((v1-mean)*inv*gs[c0+1] + bs[c0+1]);
        out[(size_t)(base+row)*32 + c0 + 2] = f2b((v2-mean)*inv*gs[c0+2] + bs[c0+2]);
        out[(size_t)(base+row)*32 + c0 + 3] = f2b((v3-mean)*inv*gs[c0+3] + bs[c0+3]);
    }
}

// ---------------- host helper ----------------
static inline void mgemm(const float* A, const ush* WT, const void* bias, size_t boff,
                         float* C, const int* flag, int M, int N, int K, int flags,
                         hipStream_t s, ush* aux, ush* aux2, int splitz = 1){
    dim3 grid((N+63)/64, M/64, splitz);
    mgemm_k<<<grid, 256, 0, s>>>(A, WT, bias, boff, C, flag, M, N, K, flags, aux, aux2);
}

extern "C" void kernel_launch(void* const* d_in, const int* in_sizes, int n_in,
                              void* d_out, int out_size, void* d_ws, size_t ws_size,
                              hipStream_t stream) {
    const void* x_in      = d_in[0];
    const void* rel       = d_in[1];
    const int* g_src      = (const int*)d_in[4];
    const int* g_dst      = (const int*)d_in[5];
    const int* lg_src     = (const int*)d_in[6];
    const int* lg_dst     = (const int*)d_in[7];
    const int* edge_feat  = (const int*)d_in[8];
    const int* full_feat  = (const int*)d_in[9];
    const void* n_Wq   = d_in[10];
    const void* n_bq   = d_in[11];
    const void* n_Wk   = d_in[12];
    const void* n_bk   = d_in[13];
    const void* n_Wv   = d_in[14];
    const void* n_bv   = d_in[15];
    const void* n_Wo   = d_in[16];
    const void* n_bo   = d_in[17];
    const void* n_lng  = d_in[18];
    const void* n_lnb  = d_in[19];
    const void* n_fW1  = d_in[20];
    const void* n_fb1  = d_in[21];
    const void* n_fW2  = d_in[22];
    const void* n_fb2  = d_in[23];
    const void* n_flng = d_in[24];
    const void* n_flnb = d_in[25];
    const void* e_Wsrc = d_in[26];
    const void* e_Wdst = d_in[27];
    const void* e_Wq   = d_in[28];
    const void* e_bq   = d_in[29];
    const void* e_Wk   = d_in[30];
    const void* e_Wv   = d_in[31];
    const void* e_Wo   = d_in[32];
    const void* e_bo   = d_in[33];
    const void* e_lng  = d_in[34];
    const void* e_lnb  = d_in[35];
    const void* e_fW1  = d_in[36];
    const void* e_fb1  = d_in[37];
    const void* e_fW2  = d_in[38];
    const void* e_fb2  = d_in[39];
    const void* e_flng = d_in[40];
    const void* e_flnb = d_in[41];

    // ---- workspace carve-up (units: floats) ----
    float* p = (float*)d_ws;
    size_t off = 0;
    auto AL = [&](size_t n){ float* r = p + off; off += n; return r; };
    int* flagp = (int*)AL(64);
    float* xA   = AL((size_t)kN*kND);
    float* xB   = AL((size_t)kN*kND);
    float* xM   = AL((size_t)kN*kND);
    ush*   xAb  = (ush*)AL((size_t)kN*kND/2);
    ush*   xBb  = (ush*)AL((size_t)kN*kND/2);
    ush*   xMb  = (ush*)AL((size_t)kN*kND/2);
    float* qkvb = AL((size_t)kN*kND);            // fp32 Q only, [4096][256]
    ush*   kvaux= (ush*)AL((size_t)kN*kKV/2);    // bf16 [4096][512]: interleaved K/V
    ush*   xsdb = (ush*)AL((size_t)kN*32);       // bf16 [4096][64]: compact SD
    ush*   ob   = (ush*)AL((size_t)kN*kND/2);
    float* tN   = AL((size_t)kN*kND*2);          // split-K partials (2x)
    ush*   nh   = (ush*)AL((size_t)kN*512);      // kN*1024 bf16
    ush*   lgA  = (ush*)AL((size_t)kEL*kED/2);   // bf16 edge residual chain
    ush*   lgB  = (ush*)AL((size_t)kEL*kED/2);
    ush*   lgM  = (ush*)AL((size_t)kEL*kED/2);
    ush*   eqb  = (ush*)AL((size_t)kEL*16);      // kEL*32 bf16
    ush*   ekvb = (ush*)AL((size_t)kEL*32);      // kEL*64 bf16 interleaved K/V
    // CSR structures
    int* cntL  = (int*)AL(kN);
    int* rowL  = (int*)AL(kN + 64);
    int* curL  = (int*)AL(kN);
    int* eidL  = (int*)AL(kEL);
    int* cntG  = (int*)AL(kEL);
    int* rowG  = (int*)AL(kEL + 64);
    int* curG  = (int*)AL(kEL);
    int* eidG  = (int*)AL(kELG);
    int* bsum  = (int*)AL(256);
    // pre-transposed bf16 weights
    ush* wtQKVSD = (ush*)AL(212992);   // [L][832][256] bf16 (425984 ush)
    float* bQKV  = AL(2*kQW);
    ush* wtO  = (ush*)AL(65536);
    ush* wtF1 = (ush*)AL(262144);
    ush* wtF2 = (ush*)AL(262144);
    ush* wtEQKV = (ush*)AL(3072);
    ush* wtEO   = (ush*)AL(1024);
    ush* wtEF1  = (ush*)AL(4096);
    ush* wtEF2  = (ush*)AL(4096);
    if (ws_size < off * sizeof(float)) return;

    float* tN2 = tN + (size_t)kN*kND;

    detect_k<<<1, 64, 0, stream>>>((const ush*)x_in, flagp);
    {
        long total = (long)kN*kND/4 + (long)kEL*kED/4 + 2*kQW + kN + kEL;
        int blocks = (int)((total + 255) / 256);
        setup_misc_k<<<blocks, 256, 0, stream>>>(x_in, rel, edge_feat, n_bq, n_bk, n_bv,
                                                 xA, xAb, lgA, bQKV, cntL, cntG, flagp);
    }
    trans_tiled_k<<<1592, 256, 0, stream>>>(n_Wq, n_Wk, n_Wv, n_Wo, n_fW1, n_fW2,
                                            e_Wsrc, e_Wdst, e_Wq, e_Wk, e_Wv, e_Wo,
                                            e_fW1, e_fW2, flagp,
                                            wtQKVSD, wtO, wtF1, wtF2,
                                            wtEQKV, wtEO, wtEF1, wtEF2);

    count2_k<<<(kEL+kELG)/256, 256, 0, stream>>>(g_dst, lg_dst, cntL, cntG);
    scan_blk2_k<<<132, 256, 0, stream>>>(cntL, cntG, rowL, rowG, bsum);
    scan_top2_k<<<1, 256, 0, stream>>>(bsum);
    scan_add2_k<<<(kN+kEL)/256, 256, 0, stream>>>(rowL, rowG, bsum, curL, curG);
    fill2_k<<<(kEL+kELG)/256, 256, 0, stream>>>(g_dst, lg_dst, curL, curG, eidL, eidG);

    float* xc = xA;  float* xn = xB;
    ush* xcb = xAb;  ush* xnb = xBb;
    ush* lgc = lgA;  ush* lgn = lgB;

    for (int i = 0; i < kL; ++i) {
        const size_t o256 = (size_t)i*kND;
        const size_t o1024= (size_t)i*1024;
        const size_t o32  = (size_t)i*kED;
        const size_t o128 = (size_t)i*128;
        const bool last = (i == kL - 1);

        // ===== node update (fp32 Q + bf16 K/V + compact SD side-outputs) =====
        mgemm((const float*)xcb, wtQKVSD + (size_t)i*212992, bQKV, (size_t)i*kQW, qkvb,
              flagp, kN, kQW, kND, 4|16|32|64, stream, kvaux, xsdb);
        full_attn_k<<<512, 512, 0, stream>>>(qkvb, kvaux, rel, full_feat, ob, flagp);
        loc_gather_k<<<kN, 256, 0, stream>>>(qkvb, kvaux, lgc, g_src, rowL, eidL, ob);
        mgemm((const float*)ob, wtO + (size_t)i*65536, n_bo, o256, tN, flagp,
              kN, kND, kND, 4|32|128, stream, nullptr, nullptr, 2);
        ln_k<<<kN/4, 256, 0, stream>>>(xc, tN, tN2, n_lng, n_lnb, o256, xM, xMb,
                                       nullptr, flagp, kND);
        mgemm((const float*)xMb, wtF1 + (size_t)i*262144, n_fb1, o1024, (float*)nh, flagp,
              kN, 1024, kND, 4|2|8|32, stream, nullptr, nullptr);
        mgemm((const float*)nh, wtF2 + (size_t)i*262144, n_fb2, o256, tN, flagp,
              kN, kND, 1024, 4|32|128, stream, nullptr, nullptr, 2);
        ln_k<<<kN/4, 256, 0, stream>>>(xM, tN, tN2, n_flng, n_flnb, o256, xn, xnb,
                                       last ? d_out : nullptr, flagp, kND);

        // ===== edge update (uses PRE-update xc, lgc) =====
        eqkv_mfma_k<<<kEL/128, 256, 0, stream>>>(lgc, xsdb, g_src, g_dst,
                                                 wtEQKV, (size_t)i*1024, e_bq, o32,
                                                 eqb, ekvb, flagp);
        lgs_ewo_k<<<kEL/32, 256, 0, stream>>>(eqb, ekvb, lg_src, rowG, eidG,
                                              lgc, wtEO, (size_t)i*1024, e_bo, o32,
                                              e_lng, e_lnb, o32, lgM, flagp);
        effn_mfma_k<<<kEL/128, 256, 0, stream>>>(lgM, wtEF1, (size_t)i*4096, e_fb1, o128,
                                                 wtEF2, (size_t)i*4096, e_fb2, o32,
                                                 e_flng, e_flnb, o32, lgn,
                                                 last ? d_out : nullptr, flagp);

        { float* t = xc; xc = xn; xn = t; }
        { ush* t = xcb; xcb = xnb; xnb = t; }
        { ush* t = lgc; lgc = lgn; lgn = t; }
    }
}

// Round 24
// 476.486 us; speedup vs baseline: 1.1659x; 1.0443x over previous
//
#include <hip/hip_runtime.h>
#include <hip/hip_bf16.h>

typedef __hip_bfloat16 bf16;
typedef unsigned short ush;

static constexpr int kN   = 4096;    // nodes
static constexpr int kND  = 256;     // hidden
static constexpr int kEL  = 131072;  // local edges
static constexpr int kED  = 32;      // edge dim
static constexpr int kELG = 262144;  // line-graph edges
static constexpr int kL   = 2;
static constexpr int kQW  = 832;     // packed qkv+sd GEMM width
static constexpr int kKV  = 512;     // kvaux row stride (bf16), per-head interleaved K/V
static constexpr float kScaleN = 0.17677669529663687f; // 1/sqrt(32)

using frag_ab = __attribute__((ext_vector_type(8))) short;   // 8 bf16 (4 VGPRs)
using frag_cd = __attribute__((ext_vector_type(4))) float;   // 4 fp32

__device__ __forceinline__ float ldf(const void* p, size_t i, int isbf){
    return isbf ? __bfloat162float(((const bf16*)p)[i]) : ((const float*)p)[i];
}
__device__ __forceinline__ ush f2b(float f){ bf16 h = __float2bfloat16(f); return *(ush*)&h; }
__device__ __forceinline__ float b2f(ush u){ return __uint_as_float(((unsigned)u)<<16); }
__device__ __forceinline__ ush ldb(const void* p, size_t i, int isbf){
    return isbf ? ((const ush*)p)[i] : f2b(((const float*)p)[i]);
}

// ---------------- dtype detection (wave-parallel) ----------------
__global__ void detect_k(const ush* __restrict__ xin, int* __restrict__ flag){
    const int t = threadIdx.x;              // 64 threads
    int pl = 0;
    for (int i = t; i < 128; i += 64) {
        ush u = xin[i];
        int e = (u >> 7) & 0xFF;
        if (e == 0 || (e >= 110 && e <= 140)) ++pl;
    }
    #pragma unroll
    for (int off = 32; off > 0; off >>= 1) pl += __shfl_down(pl, off);
    if (t == 0) *flag = (pl >= 102) ? 1 : 0;
}

// ---------------- fused setup (vectorized x4): cast x, init lg, pack bias, zero counters ----------------
__global__ void setup_misc_k(const void* __restrict__ xin, const void* __restrict__ rel,
                             const int* __restrict__ feat,
                             const void* __restrict__ bq, const void* __restrict__ bk,
                             const void* __restrict__ bv,
                             float* __restrict__ xA, ush* __restrict__ xAb,
                             ush* __restrict__ lgA,
                             float* __restrict__ bQKV,
                             int* __restrict__ cntL, int* __restrict__ cntG,
                             const int* __restrict__ flag){
    const int isbf = *flag;
    long g = (long)blockIdx.x*256 + threadIdx.x;
    if (g < (long)kN*kND/4) {                     // x cast, 4 elems/thread
        const size_t i = (size_t)g * 4;
        float4 v;
        if (isbf) {
            ushort4 u = *(const ushort4*)((const ush*)xin + i);
            v = make_float4(b2f(u.x), b2f(u.y), b2f(u.z), b2f(u.w));
        } else {
            v = *(const float4*)((const float*)xin + i);
        }
        *(float4*)&xA[i] = v;
        *(ushort4*)&xAb[i] = make_ushort4(f2b(v.x), f2b(v.y), f2b(v.z), f2b(v.w));
        return;
    }
    g -= (long)kN*kND/4;
    if (g < (long)kEL*kED/4) {                    // lg init, 4 contiguous dims of one edge
        int e = (int)(g >> 3), d4 = (int)(g & 7) * 4;
        const size_t src = (size_t)feat[e]*kED + d4;
        ushort4 u;
        if (isbf) u = *(const ushort4*)((const ush*)rel + src);
        else {
            float4 rf = *(const float4*)((const float*)rel + src);
            u = make_ushort4(f2b(rf.x), f2b(rf.y), f2b(rf.z), f2b(rf.w));
        }
        *(ushort4*)&lgA[(size_t)e*kED + d4] = u;
        return;
    }
    g -= (long)kEL*kED/4;
    if (g < 2*kQW) {
        int layer = (int)(g / kQW), j = (int)(g - (long)layer*kQW);
        float v = 0.f;
        if (j < 768) { int w = j >> 8, jj = j & 255;
            const void* B = (w==0)?bq:((w==1)?bk:bv);
            v = ldf(B, (size_t)layer*256 + jj, isbf); }
        bQKV[g] = v; return;
    }
    g -= 2*kQW;
    if (g < kN) { cntL[g] = 0; return; }
    g -= kN;
    if (g < kEL) { cntG[g] = 0; return; }
}

// ---------------- ALL weight pre-transposes: 32x32 LDS-tiled, coalesced both sides ----------------
__global__ __launch_bounds__(256) void trans_tiled_k(
    const void* __restrict__ nWq, const void* __restrict__ nWk, const void* __restrict__ nWv,
    const void* __restrict__ nWo, const void* __restrict__ nF1, const void* __restrict__ nF2,
    const void* __restrict__ eWs, const void* __restrict__ eWd,
    const void* __restrict__ eWq, const void* __restrict__ eWk, const void* __restrict__ eWv,
    const void* __restrict__ eWo, const void* __restrict__ eF1, const void* __restrict__ eF2,
    const int* __restrict__ flag,
    ush* __restrict__ wtQKVSD, ush* __restrict__ wtO, ush* __restrict__ wtF1,
    ush* __restrict__ wtF2, ush* __restrict__ wtEQKV, ush* __restrict__ wtEO,
    ush* __restrict__ wtEF1, ush* __restrict__ wtEF2)
{
    __shared__ ush lds[32][33];
    const int isbf = *flag;
    int idx = blockIdx.x;
    const void* src; size_t soff; ush* dstp; size_t doff;
    int Ns, Kd, r0, c0;
    if (idx < 384) {                                    // nWq/nWk/nWv [L][256][256] -> QKVSD rows 0-767
        int w = idx >> 7, rem = idx & 127;
        int layer = rem >> 6, tile = rem & 63;
        r0 = (tile >> 3) << 5; c0 = (tile & 7) << 5;
        src = (w==0)?nWq:((w==1)?nWk:nWv); soff = (size_t)layer*65536;
        Ns = 256; Kd = 256;
        dstp = wtQKVSD; doff = (size_t)layer*212992 + (size_t)w*65536;
    } else if ((idx -= 384) < 32) {                     // eWs/eWd [L][256][32] -> rows 768-831
        int w = idx >> 4, rem = idx & 15;
        int layer = rem >> 3, tile = rem & 7;
        r0 = tile << 5; c0 = 0;
        src = w ? eWd : eWs; soff = (size_t)layer*8192;
        Ns = 32; Kd = 256;
        dstp = wtQKVSD; doff = (size_t)layer*212992 + (size_t)(768 + w*32)*256;
    } else if ((idx -= 32) < 128) {                     // nWo [L][256][256]
        int layer = idx >> 6, tile = idx & 63;
        r0 = (tile >> 3) << 5; c0 = (tile & 7) << 5;
        src = nWo; soff = (size_t)layer*65536; Ns = 256; Kd = 256;
        dstp = wtO; doff = (size_t)layer*65536;
    } else if ((idx -= 128) < 512) {                    // nF1 [L][256][1024] -> [L][1024][256]
        int layer = idx >> 8, tile = idx & 255;
        r0 = (tile >> 5) << 5; c0 = (tile & 31) << 5;
        src = nF1; soff = (size_t)layer*262144; Ns = 1024; Kd = 256;
        dstp = wtF1; doff = (size_t)layer*262144;
    } else if ((idx -= 512) < 512) {                    // nF2 [L][1024][256] -> [L][256][1024]
        int layer = idx >> 8, tile = idx & 255;
        r0 = (tile >> 3) << 5; c0 = (tile & 7) << 5;
        src = nF2; soff = (size_t)layer*262144; Ns = 256; Kd = 1024;
        dstp = wtF2; doff = (size_t)layer*262144;
    } else if ((idx -= 512) < 6) {                      // eWq/eWk/eWv [L][32][32]
        int w = idx >> 1, layer = idx & 1;
        r0 = 0; c0 = 0;
        src = (w==0)?eWq:((w==1)?eWk:eWv); soff = (size_t)layer*1024; Ns = 32; Kd = 32;
        dstp = wtEQKV; doff = (size_t)(w*2 + layer)*1024;
    } else if ((idx -= 6) < 2) {                        // eWo [L][32][32]
        r0 = 0; c0 = 0;
        src = eWo; soff = (size_t)idx*1024; Ns = 32; Kd = 32;
        dstp = wtEO; doff = (size_t)idx*1024;
    } else if ((idx -= 2) < 8) {                        // eF1 [L][32][128] -> [L][128][32]
        int layer = idx >> 2, tile = idx & 3;
        r0 = 0; c0 = tile << 5;
        src = eF1; soff = (size_t)layer*4096; Ns = 128; Kd = 32;
        dstp = wtEF1; doff = (size_t)layer*4096;
    } else {                                            // eF2 [L][128][32] -> [L][32][128]
        idx -= 8;
        int layer = idx >> 2, tile = idx & 3;
        r0 = tile << 5; c0 = 0;
        src = eF2; soff = (size_t)layer*4096; Ns = 32; Kd = 128;
        dstp = wtEF2; doff = (size_t)layer*4096;
    }
    const int t = threadIdx.x;
    const int c = t & 31, rb = t >> 5;
    #pragma unroll
    for (int p = 0; p < 4; ++p) {
        int r = rb + p*8;
        lds[r][c] = ldb(src, soff + (size_t)(r0 + r)*Ns + c0 + c, isbf);
    }
    __syncthreads();
    #pragma unroll
    for (int p = 0; p < 4; ++p) {
        int rr = rb + p*8;
        dstp[doff + (size_t)(c0 + rr)*Kd + r0 + c] = lds[c][rr];
    }
}

// ---------------- CSR build (both graphs fused) ----------------
__global__ void count2_k(const int* __restrict__ gd, const int* __restrict__ lgd,
                         int* __restrict__ cntL, int* __restrict__ cntG){
    int g = blockIdx.x*256 + threadIdx.x;
    if (g < kEL) atomicAdd(&cntL[gd[g]], 1);
    else if (g < kEL + kELG) atomicAdd(&cntG[lgd[g - kEL]], 1);
}
__global__ __launch_bounds__(256) void scan_blk2_k(
    const int* __restrict__ cntL, const int* __restrict__ cntG,
    int* __restrict__ rowL, int* __restrict__ rowG, int* __restrict__ bsum)
{
    __shared__ int s[256];
    const int t = threadIdx.x;
    const bool isL = blockIdx.x < 4;
    const int* cnt = isL ? cntL : cntG;
    int* out = isL ? rowL : rowG;
    const int blk = isL ? blockIdx.x : blockIdx.x - 4;
    const int n = isL ? kN : kEL;
    const int b0 = blk*1024;
    int v[4], pre[4], tsum = 0;
    #pragma unroll
    for (int j=0;j<4;++j){
        int idx = b0 + t*4 + j;
        v[j] = (idx < n) ? cnt[idx] : 0;
        pre[j] = tsum; tsum += v[j];
    }
    s[t] = tsum; __syncthreads();
    for (int off=1; off<256; off<<=1){
        int x = (t>=off) ? s[t-off] : 0;
        __syncthreads();
        s[t] += x;
        __syncthreads();
    }
    int texc = s[t] - tsum;
    #pragma unroll
    for (int j=0;j<4;++j){
        int idx = b0 + t*4 + j;
        if (idx < n) out[idx] = texc + pre[j];
    }
    if (t == 255) bsum[(isL ? 0 : 8) + blk] = s[255];
}
__global__ __launch_bounds__(256) void scan_top2_k(int* __restrict__ bsum){
    __shared__ int sL[256], sG[256];
    const int t = threadIdx.x;
    int vL = (t < 4)   ? bsum[t]     : 0;
    int vG = (t < 128) ? bsum[8 + t] : 0;
    sL[t] = vL; sG[t] = vG; __syncthreads();
    for (int off=1; off<256; off<<=1){
        int xL = (t>=off) ? sL[t-off] : 0;
        int xG = (t>=off) ? sG[t-off] : 0;
        __syncthreads();
        sL[t] += xL; sG[t] += xG;
        __syncthreads();
    }
    if (t < 4)   bsum[t]     = sL[t] - vL;
    if (t < 128) bsum[8 + t] = sG[t] - vG;
}
__global__ void scan_add2_k(int* __restrict__ rowL, int* __restrict__ rowG,
                            const int* __restrict__ bsum,
                            int* __restrict__ curL, int* __restrict__ curG){
    int g = blockIdx.x*256 + threadIdx.x;
    if (g < kN){ int v = rowL[g] + bsum[g >> 10]; rowL[g] = v; curL[g] = v; }
    else if (g < kN + kEL){ int gg = g - kN;
        int v = rowG[gg] + bsum[8 + (gg >> 10)]; rowG[gg] = v; curG[gg] = v; }
    if (g == 0){ rowL[kN] = kEL; rowG[kEL] = kELG; }
}
__global__ void fill2_k(const int* __restrict__ gd, const int* __restrict__ lgd,
                        int* __restrict__ curL, int* __restrict__ curG,
                        int* __restrict__ eidL, int* __restrict__ eidG){
    int g = blockIdx.x*256 + threadIdx.x;
    if (g < kEL){ int pos = atomicAdd(&curL[gd[g]], 1); eidL[pos] = g; }
    else if (g < kEL + kELG){ int gg = g - kEL;
        int pos = atomicAdd(&curG[lgd[gg]], 1); eidG[pos] = gg; }
}

// ---------------- MFMA GEMM: C[M,N] = A@WT^T + bias (opt relu); BK=64 ----------------
// WT: bf16 [N][K]. 64x64 tile, 4 waves. Requires K%(64*gridDim.z)==0, N%64==0.
// flags: 2=RELU, 4=has-bias, 8=bf16 out, 16=bias packed fp32, 32=A is bf16,
//        64=QKV split output (col<256 -> fp32 C; 256-767 -> bf16 aux interleaved; 768+ -> aux2),
//        128=split-K over gridDim.z (bias by z==0 only; fp32 partials at C + z*M*N)
__global__ __launch_bounds__(256) void mgemm_k(
    const float* __restrict__ A, const ush* __restrict__ WT,
    const void* __restrict__ bias, size_t boff,
    float* __restrict__ C, const int* __restrict__ flag,
    int M, int N, int K, int flags, ush* __restrict__ aux, ush* __restrict__ aux2)
{
    __shared__ __align__(16) ush As[64*72];
    __shared__ __align__(16) ush Ws[64*72];
    const int isbf = *flag;
    const int t = threadIdx.x;
    const int m0 = blockIdx.y*64, n0 = blockIdx.x*64;
    const int wave = t>>6, lane = t&63;
    const int quad = lane>>4, l15 = lane&15;
    const int r = t>>3, kq = (t&7)*8;      // rows r and r+32, 8 K-elems at kq
    const bool abf = flags & 32;
    const bool spk = flags & 128;
    const int Kc   = spk ? (K / gridDim.z) : K;
    const int koff = spk ? (blockIdx.z * Kc) : 0;

    frag_cd acc[4];
    #pragma unroll
    for (int tl=0; tl<4; ++tl)
        #pragma unroll
        for (int j=0;j<4;++j) acc[tl][j] = 0.f;

    const float* ap0 = A + (size_t)(m0+r)*K + koff + kq;
    const float* ap1 = A + (size_t)(m0+r+32)*K + koff + kq;
    const ush*   ab0 = (const ush*)A + (size_t)(m0+r)*K + koff + kq;
    const ush*   ab1 = (const ush*)A + (size_t)(m0+r+32)*K + koff + kq;
    const ush*   wp0 = WT + (size_t)(n0+r)*K + koff + kq;
    const ush*   wp1 = WT + (size_t)(n0+r+32)*K + koff + kq;

    float4 a00,a01,a10,a11; uint4 av0,av1, wv0,wv1;
    auto loadT = [&](int kk){
        if (abf) { av0 = *(const uint4*)(ab0+kk); av1 = *(const uint4*)(ab1+kk); }
        else { a00 = *(const float4*)(ap0+kk); a01 = *(const float4*)(ap0+kk+4);
               a10 = *(const float4*)(ap1+kk); a11 = *(const float4*)(ap1+kk+4); }
        wv0 = *(const uint4*)(wp0+kk); wv1 = *(const uint4*)(wp1+kk);
    };
    loadT(0);

    for (int kk = 0; kk < Kc; kk += 64) {
        if (abf) {
            *(uint4*)&As[r*72 + kq]        = av0;
            *(uint4*)&As[(r+32)*72 + kq]   = av1;
        } else {
            *(ushort4*)&As[r*72 + kq]       = make_ushort4(f2b(a00.x),f2b(a00.y),f2b(a00.z),f2b(a00.w));
            *(ushort4*)&As[r*72 + kq + 4]   = make_ushort4(f2b(a01.x),f2b(a01.y),f2b(a01.z),f2b(a01.w));
            *(ushort4*)&As[(r+32)*72 + kq]     = make_ushort4(f2b(a10.x),f2b(a10.y),f2b(a10.z),f2b(a10.w));
            *(ushort4*)&As[(r+32)*72 + kq + 4] = make_ushort4(f2b(a11.x),f2b(a11.y),f2b(a11.z),f2b(a11.w));
        }
        *(uint4*)&Ws[r*72 + kq]      = wv0;
        *(uint4*)&Ws[(r+32)*72 + kq] = wv1;
        __syncthreads();
        if (kk + 64 < Kc) loadT(kk + 64);
        frag_ab af0 = *(const frag_ab*)&As[(wave*16 + l15)*72 + quad*8];
        frag_ab af1 = *(const frag_ab*)&As[(wave*16 + l15)*72 + 32 + quad*8];
        #pragma unroll
        for (int tl = 0; tl < 4; ++tl) {
            frag_ab bf0 = *(const frag_ab*)&Ws[(tl*16 + l15)*72 + quad*8];
            acc[tl] = __builtin_amdgcn_mfma_f32_16x16x32_bf16(af0, bf0, acc[tl], 0, 0, 0);
            frag_ab bf1 = *(const frag_ab*)&Ws[(tl*16 + l15)*72 + 32 + quad*8];
            acc[tl] = __builtin_amdgcn_mfma_f32_16x16x32_bf16(af1, bf1, acc[tl], 0, 0, 0);
        }
        __syncthreads();
    }
    const bool do_relu = flags & 2;
    const bool has_b   = (flags & 4) && (!spk || blockIdx.z == 0);
    const bool obf     = flags & 8;
    float* Cz = spk ? (C + (size_t)blockIdx.z * M * N) : C;
    #pragma unroll
    for (int tl = 0; tl < 4; ++tl) {
        int col = n0 + tl*16 + l15;
        float bv = 0.f;
        if (has_b) bv = (flags & 16) ? ((const float*)bias)[boff + col]
                                     : ldf(bias, boff + col, isbf);
        // kvaux/xsd column mapping for QKV split output:
        int adst = -1; bool tox = false;
        if (flags & 64 && col >= 256) {
            int c = col - 256;
            if (c < 512) {
                int isv = c >> 8;            // 0 = K, 1 = V
                int cc = c & 255;
                int h = cc >> 5, d = cc & 31;
                int base = (h < 4) ? h*64 : 256 + (h-4)*64;
                adst = base + isv*32 + d;
            } else { adst = c - 512; tox = true; }   // SD -> compact xsd [row][64]
        }
        #pragma unroll
        for (int rg = 0; rg < 4; ++rg) {
            int row = m0 + wave*16 + quad*4 + rg;
            float v = acc[tl][rg] + bv;
            if (do_relu) v = fmaxf(v, 0.f);
            if (flags & 64) {
                if (col < 256)  C[(size_t)row*256 + col] = v;
                else if (tox)   aux2[(size_t)row*64 + adst] = f2b(v);
                else            aux[(size_t)row*kKV + adst] = f2b(v);
            } else if (obf) ((ush*)C)[(size_t)row*N + col] = f2b(v);
            else            Cz[(size_t)row*N + col] = v;
        }
    }
}

// ---------------- LayerNorm (node rows, D=256 fixed): vectorized float4, dual f32+bf16 ----------------
// 4 rows/block, wave per row; lane t handles 4 contiguous cols. b2/fin nullable.
__global__ __launch_bounds__(256) void ln_k(
    const float* __restrict__ a, const float* __restrict__ b, const float* __restrict__ b2,
    const void* __restrict__ g, const void* __restrict__ be, size_t goff,
    float* __restrict__ out, ush* __restrict__ outb,
    void* __restrict__ fin,
    const int* __restrict__ flag, int D)
{
    const int isbf = *flag;
    const int row = blockIdx.x*4 + (threadIdx.x >> 6);
    const int t = threadIdx.x & 63;
    const int c0 = t * 4;                 // D == 256
    const size_t base = (size_t)row*256 + c0;
    float4 x = *(const float4*)&a[base];
    if (b)  { float4 y = *(const float4*)&b[base];  x.x+=y.x; x.y+=y.y; x.z+=y.z; x.w+=y.w; }
    if (b2) { float4 y = *(const float4*)&b2[base]; x.x+=y.x; x.y+=y.y; x.z+=y.z; x.w+=y.w; }
    float s = x.x + x.y + x.z + x.w;
    #pragma unroll
    for (int off = 32; off > 0; off >>= 1) s += __shfl_down(s, off);
    s = __shfl(s, 0);
    const float mean = s * (1.f/256.f);
    float qq = (x.x-mean)*(x.x-mean) + (x.y-mean)*(x.y-mean)
             + (x.z-mean)*(x.z-mean) + (x.w-mean)*(x.w-mean);
    #pragma unroll
    for (int off = 32; off > 0; off >>= 1) qq += __shfl_down(qq, off);
    qq = __shfl(qq, 0);
    const float inv = rsqrtf(fmaxf(qq, 0.f) * (1.f/256.f) + 1e-5f);
    float4 r;
    r.x = (x.x-mean)*inv*ldf(g, goff + c0 + 0, isbf) + ldf(be, goff + c0 + 0, isbf);
    r.y = (x.y-mean)*inv*ldf(g, goff + c0 + 1, isbf) + ldf(be, goff + c0 + 1, isbf);
    r.z = (x.z-mean)*inv*ldf(g, goff + c0 + 2, isbf) + ldf(be, goff + c0 + 2, isbf);
    r.w = (x.w-mean)*inv*ldf(g, goff + c0 + 3, isbf) + ldf(be, goff + c0 + 3, isbf);
    *(float4*)&out[base] = r;
    const ushort4 rb = make_ushort4(f2b(r.x), f2b(r.y), f2b(r.z), f2b(r.w));
    *(ushort4*)&outb[base] = rb;
    if (fin) {
        if (isbf) *(ushort4*)((ush*)fin + base) = rb;
        else      *(float4*)((float*)fin + base) = r;
    }
}

// ---------------- MFMA eq/ekv (+gathered mixed), 128 rows/block, bf16 in/out ----------------
// xsd: compact [4096][64] bf16 (src at 0-31, dst at 32-63). Vectorized staging.
// Output: eq [el][32]; ekv [el][64] interleaved (k_h at h*8, v_h at h*8+4).
__global__ __launch_bounds__(256) void eqkv_mfma_k(
    const ush* __restrict__ lg, const ush* __restrict__ xsd,
    const int* __restrict__ gsrc, const int* __restrict__ gdst,
    const ush* __restrict__ WQKV, size_t woff,
    const void* __restrict__ bq, size_t boff,
    ush* __restrict__ eq, ush* __restrict__ ekv,
    const int* __restrict__ flag)
{
    __shared__ __align__(16) ush mixs[128*40];
    __shared__ __align__(16) ush wts[3][32*40];
    __shared__ float bqs[32];
    const int isbf = *flag;
    const int t = threadIdx.x;
    const int e0 = blockIdx.x * 128;
    #pragma unroll
    for (int i = t; i < 768; i += 256) {
        int m = i >> 8, r2 = i & 255;
        int n = r2 >> 3, k4 = (r2 & 7) * 4;
        *(ushort4*)&wts[m][n*40 + k4] =
            *(const ushort4*)&WQKV[(size_t)m*2048 + woff + (size_t)n*32 + k4];
    }
    if (t < 32) bqs[t] = ldf(bq, boff + t, isbf);
    {
        int r = t >> 1, c0 = (t & 1) * 16;
        int e = e0 + r;
        int s = gsrc[e], d2 = gdst[e];
        const ush* lp = lg  + (size_t)e*32  + c0;
        const ush* sp = xsd + (size_t)s*64  + c0;
        const ush* dp = xsd + (size_t)d2*64 + 32 + c0;
        uint4 lv0 = *(const uint4*)lp,     lv1 = *(const uint4*)(lp+8);
        uint4 sv0 = *(const uint4*)sp,     sv1 = *(const uint4*)(sp+8);
        uint4 dv0 = *(const uint4*)dp,     dv1 = *(const uint4*)(dp+8);
        auto pk = [](unsigned a, unsigned b, unsigned c)->unsigned {
            ush lo = f2b(b2f((ush)(a & 0xffff)) + b2f((ush)(b & 0xffff)) + b2f((ush)(c & 0xffff)));
            ush hi = f2b(b2f((ush)(a >> 16))    + b2f((ush)(b >> 16))    + b2f((ush)(c >> 16)));
            return (unsigned)lo | ((unsigned)hi << 16);
        };
        uint4 o0, o1;
        o0.x = pk(lv0.x, sv0.x, dv0.x); o0.y = pk(lv0.y, sv0.y, dv0.y);
        o0.z = pk(lv0.z, sv0.z, dv0.z); o0.w = pk(lv0.w, sv0.w, dv0.w);
        o1.x = pk(lv1.x, sv1.x, dv1.x); o1.y = pk(lv1.y, sv1.y, dv1.y);
        o1.z = pk(lv1.z, sv1.z, dv1.z); o1.w = pk(lv1.w, sv1.w, dv1.w);
        *(uint4*)&mixs[r*40 + c0]     = o0;
        *(uint4*)&mixs[r*40 + c0 + 8] = o1;
    }
    __syncthreads();
    const int wave = t >> 6, l15 = t & 15, quad = (t >> 4) & 3;
    #pragma unroll
    for (int mi = 0; mi < 2; ++mi) {
        const int mt = wave*2 + mi;
        frag_ab af = *(const frag_ab*)&mixs[(mt*16 + l15)*40 + quad*8];
        #pragma unroll
        for (int w = 0; w < 3; ++w) {
            #pragma unroll
            for (int nt = 0; nt < 2; ++nt) {
                frag_ab bf = *(const frag_ab*)&wts[w][(nt*16 + l15)*40 + quad*8];
                frag_cd acc = {0.f, 0.f, 0.f, 0.f};
                acc = __builtin_amdgcn_mfma_f32_16x16x32_bf16(af, bf, acc, 0, 0, 0);
                const float bv = (w==0) ? bqs[nt*16 + l15] : 0.f;
                const int col = nt*16 + l15;            // 0..31
                const int h = col >> 2, d = col & 3;
                #pragma unroll
                for (int rg = 0; rg < 4; ++rg) {
                    int row = e0 + mt*16 + quad*4 + rg;
                    float v = acc[rg] + bv;
                    if (w == 0)      eq[(size_t)row*32 + col] = f2b(v);
                    else if (w == 1) ekv[(size_t)row*64 + h*8 + d] = f2b(v);
                    else             ekv[(size_t)row*64 + h*8 + 4 + d] = f2b(v);
                }
            }
        }
    }
}

// ---------------- MFMA edge FFN: LN(A + relu(A@W1+b1)@W2 + b2); bf16 A / bf16 out ----------------
// fin nullable: also write final lg output at offset kN*kND (dtype by flag).
__global__ __launch_bounds__(256) void effn_mfma_k(
    const ush* __restrict__ A,
    const ush* __restrict__ W1T, size_t w1off, const void* __restrict__ b1, size_t b1off,
    const ush* __restrict__ W2T, size_t w2off, const void* __restrict__ b2, size_t b2off,
    const void* __restrict__ g, const void* __restrict__ be, size_t goff,
    ush* __restrict__ out, void* __restrict__ fin, const int* __restrict__ flag)
{
    __shared__ __align__(16) ush w1t[128*40];
    __shared__ __align__(16) ush w2t[32*136];
    __shared__ __align__(16) ush hid[64*136];
    __shared__ float b1s[128], b2s[32];
    const int isbf = *flag;
    const int t = threadIdx.x;
    const int wave = t >> 6, l15 = t & 15, quad = (t >> 4) & 3;

    #pragma unroll
    for (int i = t; i < 1024; i += 256) {
        int n1 = i >> 3, k4 = (i & 7) * 4;
        *(ushort4*)&w1t[n1*40 + k4] = *(const ushort4*)&W1T[w1off + (size_t)n1*32 + k4];
        int n2 = i >> 5, kq2 = (i & 31) * 4;
        *(ushort4*)&w2t[n2*136 + kq2] = *(const ushort4*)&W2T[w2off + (size_t)n2*128 + kq2];
    }
    if (t < 128) b1s[t] = ldf(b1, b1off + t, isbf);
    if (t < 32)  b2s[t] = ldf(b2, b2off + t, isbf);
    __syncthreads();

    const float g0  = ldf(g,  goff + l15, isbf),      g1v = ldf(g,  goff + 16 + l15, isbf);
    const float be0 = ldf(be, goff + l15, isbf),      be1 = ldf(be, goff + 16 + l15, isbf);
    const float bb0 = b2s[l15], bb1 = b2s[16 + l15];

    for (int tt = 0; tt < 2; ++tt) {
        const int e0 = (blockIdx.x*2 + tt) * 64;
        {
            const int m = wave*16 + l15;
            frag_ab af = *(const frag_ab*)&A[(size_t)(e0+m)*32 + quad*8];
            #pragma unroll
            for (int nt = 0; nt < 8; ++nt) {
                frag_ab bf = *(const frag_ab*)&w1t[(nt*16 + l15)*40 + quad*8];
                frag_cd acc = {0.f, 0.f, 0.f, 0.f};
                acc = __builtin_amdgcn_mfma_f32_16x16x32_bf16(af, bf, acc, 0, 0, 0);
                float bv = b1s[nt*16 + l15];
                #pragma unroll
                for (int rg = 0; rg < 4; ++rg) {
                    int row = wave*16 + quad*4 + rg;
                    hid[row*136 + nt*16 + l15] = f2b(fmaxf(acc[rg] + bv, 0.f));
                }
            }
        }
        // hid rows are wave-private -> no barrier needed
        frag_cd acc2[2] = {{0.f,0.f,0.f,0.f},{0.f,0.f,0.f,0.f}};
        #pragma unroll
        for (int ks = 0; ks < 4; ++ks) {
            frag_ab af2 = *(const frag_ab*)&hid[(wave*16 + l15)*136 + ks*32 + quad*8];
            #pragma unroll
            for (int tl = 0; tl < 2; ++tl) {
                frag_ab bf2 = *(const frag_ab*)&w2t[(tl*16 + l15)*136 + ks*32 + quad*8];
                acc2[tl] = __builtin_amdgcn_mfma_f32_16x16x32_bf16(af2, bf2, acc2[tl], 0, 0, 0);
            }
        }
        #pragma unroll
        for (int rg = 0; rg < 4; ++rg) {
            const int row = e0 + wave*16 + quad*4 + rg;
            float v0 = acc2[0][rg] + bb0 + b2f(A[(size_t)row*32 + l15]);
            float v1 = acc2[1][rg] + bb1 + b2f(A[(size_t)row*32 + 16 + l15]);
            float s = v0 + v1;
            s += __shfl_xor(s,1); s += __shfl_xor(s,2); s += __shfl_xor(s,4); s += __shfl_xor(s,8);
            const float mean = s * (1.f/32.f);
            float q = (v0-mean)*(v0-mean) + (v1-mean)*(v1-mean);
            q += __shfl_xor(q,1); q += __shfl_xor(q,2); q += __shfl_xor(q,4); q += __shfl_xor(q,8);
            const float inv = rsqrtf(q * (1.f/32.f) + 1e-5f);
            const ush u0 = f2b((v0-mean)*inv*g0  + be0);
            const ush u1 = f2b((v1-mean)*inv*g1v + be1);
            out[(size_t)row*32 + l15]      = u0;
            out[(size_t)row*32 + 16 + l15] = u1;
            if (fin) {
                const size_t base = (size_t)kN*kND + (size_t)row*32;
                if (isbf) {
                    ((ush*)fin)[base + l15]      = u0;
                    ((ush*)fin)[base + 16 + l15] = u1;
                } else {
                    ((float*)fin)[base + l15]      = b2f(u0);
                    ((float*)fin)[base + 16 + l15] = b2f(u1);
                }
            }
        }
    }
}

// ---------------- full-graph attention: (b,h,quarter) blocks, 512 grid (online softmax) ----------------
// q: fp32 [4096][256]; kv: bf16 [4096][kKV], full head h: K at h*64, V at h*64+32
__global__ __launch_bounds__(512) void full_attn_k(
    const float* __restrict__ q, const ush* __restrict__ kv,
    const void* __restrict__ rel, const int* __restrict__ feat, ush* __restrict__ o,
    const int* __restrict__ flag)
{
    __shared__ __align__(8) ush ks[128][36];
    __shared__ __align__(8) ush vs[128][36];
    __shared__ __align__(8) ush rs[128][36];
    __shared__ float pb[8][32][34];            // per-wave partials: m, l, acc[32]
    const int isbf = *flag;
    const int bid = blockIdx.x;
    const int b = bid >> 4, h = (bid >> 2) & 3, qtr = bid & 3;
    const int t = threadIdx.x;
    // vectorized staging: 4 elems/thread
    for (int i = t; i < 1024; i += 512) {
        int r = i >> 3, d4 = (i & 7) * 4;
        const ush* kvrow = kv + (size_t)(b*128 + r)*kKV + h*64 + d4;
        *(ushort4*)&ks[r][d4] = *(const ushort4*)kvrow;
        *(ushort4*)&vs[r][d4] = *(const ushort4*)(kvrow + 32);
        if (isbf) {
            *(ushort4*)&rs[r][d4] = *(const ushort4*)((const ush*)rel + r*32 + d4);
        } else {
            float4 rf = *(const float4*)((const float*)rel + r*32 + d4);
            *(ushort4*)&rs[r][d4] = make_ushort4(f2b(rf.x), f2b(rf.y), f2b(rf.z), f2b(rf.w));
        }
    }
    __syncthreads();
    const int wave = t >> 6, lane = t & 63;
    const int dstL = lane >> 1, part = lane & 1;   // 2 lanes per dst
    const int dst = qtr*32 + dstL;
    const int dbase = part*16;                     // this lane's 16 dims
    float qr[16];
    { size_t base = ((size_t)(b*128 + dst))*256 + h*32 + dbase;
      #pragma unroll
      for (int d=0; d<16; ++d) qr[d] = q[base + d]; }
    const int* fp = feat + (size_t)b*16384 + dst;
    const int s0 = wave*16;
    float m = -1e30f, l = 0.f;
    float acc[16];
    #pragma unroll
    for (int d=0; d<16; ++d) acc[d] = 0.f;
    int f = fp[s0*128];
    for (int sI = 0; sI < 16; ++sI) {
        const int s = s0 + sI;
        int fn = (sI+1 < 16) ? fp[(s+1)*128] : 0;
        float er[16];
        float scp = 0.f;
        #pragma unroll
        for (int j2 = 0; j2 < 4; ++j2) {
            ushort4 eu = *(const ushort4*)&rs[f][dbase + j2*4];
            ushort4 ku = *(const ushort4*)&ks[s][dbase + j2*4];
            float e0 = b2f(eu.x), e1 = b2f(eu.y), e2 = b2f(eu.z), e3 = b2f(eu.w);
            er[j2*4+0]=e0; er[j2*4+1]=e1; er[j2*4+2]=e2; er[j2*4+3]=e3;
            scp += (b2f(ku.x)+e0)*qr[j2*4+0] + (b2f(ku.y)+e1)*qr[j2*4+1]
                 + (b2f(ku.z)+e2)*qr[j2*4+2] + (b2f(ku.w)+e3)*qr[j2*4+3];
        }
        const float sc = (scp + __shfl_xor(scp, 1)) * kScaleN;
        float mn = fmaxf(m, sc);
        float c0 = __expf(m - mn);
        float pp = __expf(sc - mn);
        l = l*c0 + pp;
        #pragma unroll
        for (int j2 = 0; j2 < 4; ++j2) {
            ushort4 vu = *(const ushort4*)&vs[s][dbase + j2*4];
            acc[j2*4+0] = acc[j2*4+0]*c0 + pp*(b2f(vu.x)+er[j2*4+0]);
            acc[j2*4+1] = acc[j2*4+1]*c0 + pp*(b2f(vu.y)+er[j2*4+1]);
            acc[j2*4+2] = acc[j2*4+2]*c0 + pp*(b2f(vu.z)+er[j2*4+2]);
            acc[j2*4+3] = acc[j2*4+3]*c0 + pp*(b2f(vu.w)+er[j2*4+3]);
        }
        m = mn; f = fn;
    }
    if (part == 0) { pb[wave][dstL][0] = m; pb[wave][dstL][1] = l; }
    #pragma unroll
    for (int d=0; d<16; ++d) pb[wave][dstL][2 + dbase + d] = acc[d];
    __syncthreads();
    // merge: thread (dstL2, grp) handles dims [grp*2, grp*2+2) of dst=qtr*32+dstL2
    {
        const int dstL2 = t & 31, grp = t >> 5;   // grp in [0,16)
        float mw[8], lw[8];
        #pragma unroll
        for (int w=0; w<8; ++w){ mw[w]=pb[w][dstL2][0]; lw[w]=pb[w][dstL2][1]; }
        float M = mw[0];
        #pragma unroll
        for (int w=1; w<8; ++w) M = fmaxf(M, mw[w]);
        float sw[8];
        float L = 0.f;
        #pragma unroll
        for (int w=0; w<8; ++w){ sw[w] = __expf(mw[w]-M); L += lw[w]*sw[w]; }
        const float inv = 1.f / fmaxf(L, 1e-30f);
        size_t base = ((size_t)(b*128 + qtr*32 + dstL2))*kND + h*32 + grp*2;
        #pragma unroll
        for (int d=0; d<2; ++d) {
            float a = 0.f;
            #pragma unroll
            for (int w=0; w<8; ++w) a += pb[w][dstL2][2+grp*2+d]*sw[w];
            o[base + d] = f2b(a*inv);
        }
    }
}

// ---------------- local-graph GATHER attention (heads 4..7), 8-way edge-parallel, ushort4 ----------------
// kv: [4096][kKV] bf16: local head h (0..3): K at 256+h*64, V at 256+h*64+32 (adjacent)
__global__ __launch_bounds__(256) void loc_gather_k(
    const float* __restrict__ q, const ush* __restrict__ kv,
    const ush* __restrict__ lg, const int* __restrict__ gsrc,
    const int* __restrict__ rowp, const int* __restrict__ eidl,
    ush* __restrict__ o)
{
    __shared__ int eids[192], srcs[192];
    const int n = blockIdx.x;
    const int beg = rowp[n], end = rowp[n+1];
    const int deg = end - beg;
    {
        const int tc = threadIdx.x;
        const int dc = (deg < 192) ? deg : 192;
        if (tc < dc) { int e = eidl[beg + tc]; eids[tc] = e; srcs[tc] = gsrc[e]; }
    }
    __syncthreads();
    const int h = threadIdx.x >> 6;
    const int lane = threadIdx.x & 63;
    const int g = lane >> 3;              // 8 edge-groups
    const int d0 = (lane & 7) * 4;        // 4 dims each
    const size_t hoff = (size_t)(4 + h) * 32 + d0;
    const float4 q4 = *(const float4*)&q[(size_t)n*256 + hoff];
    float m = -1e30f, l = 0.f;
    float4 a4 = make_float4(0.f, 0.f, 0.f, 0.f);
    if (deg > 0) {
        const int nIter = (deg + 7) >> 3;
        int idx = beg + g;
        for (int it = 0; it < nIter; ++it) {
            const bool valid = idx < end;
            const int ii = min(idx, end-1) - beg;
            int e, s;
            if (ii < 192) { e = eids[ii]; s = srcs[ii]; }
            else          { e = eidl[beg + ii]; s = gsrc[e]; }
            idx += 8;
            const ushort4 ku  = *(const ushort4*)&kv[(size_t)s*kKV + 256 + h*64 + d0];
            const ushort4 lvu = *(const ushort4*)&lg[(size_t)e*32 + d0];
            const ushort4 vu  = *(const ushort4*)&kv[(size_t)s*kKV + 256 + h*64 + 32 + d0];
            const float l0 = b2f(lvu.x), l1 = b2f(lvu.y), l2 = b2f(lvu.z), l3 = b2f(lvu.w);
            float part = (b2f(ku.x)+l0)*q4.x + (b2f(ku.y)+l1)*q4.y
                       + (b2f(ku.z)+l2)*q4.z + (b2f(ku.w)+l3)*q4.w;
            part += __shfl_xor(part, 1);
            part += __shfl_xor(part, 2);
            part += __shfl_xor(part, 4);
            const float sc = part * kScaleN;
            const float mn = valid ? fmaxf(m, sc) : m;
            const float c  = __expf(m - mn);
            const float pp = valid ? __expf(sc - mn) : 0.f;
            l  = l*c  + pp;
            a4.x = a4.x*c + pp*(b2f(vu.x)+l0);
            a4.y = a4.y*c + pp*(b2f(vu.y)+l1);
            a4.z = a4.z*c + pp*(b2f(vu.z)+l2);
            a4.w = a4.w*c + pp*(b2f(vu.w)+l3);
            m  = mn;
        }
        #pragma unroll
        for (int off = 8; off <= 32; off <<= 1) {
            const float mo = __shfl_xor(m, off);
            const float lo = __shfl_xor(l, off);
            const float xo = __shfl_xor(a4.x, off);
            const float yo = __shfl_xor(a4.y, off);
            const float zo = __shfl_xor(a4.z, off);
            const float wo = __shfl_xor(a4.w, off);
            const float M  = fmaxf(m, mo);
            const float c1 = __expf(m - M);
            const float c2 = __expf(mo - M);
            l  = l*c1  + lo*c2;
            a4.x = a4.x*c1 + xo*c2;
            a4.y = a4.y*c1 + yo*c2;
            a4.z = a4.z*c1 + zo*c2;
            a4.w = a4.w*c1 + wo*c2;
            m  = M;
        }
    }
    if (g == 0) {
        const float inv = 1.f / fmaxf(l, 1e-30f);
        *(ushort4*)&o[(size_t)n*kND + hoff] =
            make_ushort4(f2b(a4.x*inv), f2b(a4.y*inv), f2b(a4.z*inv), f2b(a4.w*inv));
    }
}

// ---------------- fused line-graph attention + Wo GEMM + LN (bf16 in/out) ----------------
// ekv: [el][64] interleaved; src indices LDS-staged (contiguous eid window per 32 dsts)
__global__ __launch_bounds__(256) void lgs_ewo_k(
    const ush* __restrict__ eq, const ush* __restrict__ ekv,
    const int* __restrict__ lsrc, const int* __restrict__ rowp, const int* __restrict__ eidl,
    const ush* __restrict__ res,
    const ush* __restrict__ WO, size_t wooff, const void* __restrict__ bo, size_t booff,
    const void* __restrict__ g1, const void* __restrict__ be1, size_t g1off,
    ush* __restrict__ out, const int* __restrict__ flag)
{
    __shared__ __align__(16) ush ows[32*40];
    __shared__ __align__(16) ush wos[32*40];
    __shared__ float cs[32][36];
    __shared__ float bos[32], gs[32], bs[32];
    __shared__ int srcs[256];
    const int isbf = *flag;
    const int t = threadIdx.x;
    const int base = blockIdx.x * 32;
    {
        int n = t >> 3, k4 = (t & 7) * 4;
        *(ushort4*)&wos[n*40 + k4] = *(const ushort4*)&WO[wooff + (size_t)n*32 + k4];
    }
    if (t < 32) {
        bos[t] = ldf(bo, booff + t, isbf);
        gs[t]  = ldf(g1, g1off + t, isbf);
        bs[t]  = ldf(be1, g1off + t, isbf);
    }
    // ---- stage src indices for this block's contiguous edge window ----
    const int beg0 = rowp[base];
    {
        int cnt = rowp[base + 32] - beg0;
        if (cnt > 256) cnt = 256;
        for (int j = t; j < cnt; j += 256) srcs[j] = lsrc[eidl[beg0 + j]];
    }
    __syncthreads();
    // ---- phase 1: gather attention, thread = (dst-edge, head) ----
    {
        const int d2 = base + (t >> 3), h = t & 7;
        const ushort4 qu = *(const ushort4*)&eq[(size_t)d2*32 + h*4];
        const float q0 = b2f(qu.x), q1 = b2f(qu.y), q2 = b2f(qu.z), q3 = b2f(qu.w);
        const int beg = rowp[d2], end = rowp[d2+1];
        float m = -1e30f, l = 0.f;
        float4 acc = make_float4(0.f,0.f,0.f,0.f);
        for (int i = beg; i < end; ++i) {
            const int io = i - beg0;
            const int s = (io < 256) ? srcs[io] : lsrc[eidl[i]];
            const uint4 kv8 = *(const uint4*)&ekv[(size_t)s*64 + h*8];   // k4|v4, 16B
            const ush k0 = (ush)(kv8.x & 0xffff), k1 = (ush)(kv8.x >> 16);
            const ush k2 = (ush)(kv8.y & 0xffff), k3 = (ush)(kv8.y >> 16);
            const ush v0u = (ush)(kv8.z & 0xffff), v1u = (ush)(kv8.z >> 16);
            const ush v2u = (ush)(kv8.w & 0xffff), v3u = (ush)(kv8.w >> 16);
            float sc = (b2f(k0)*q0 + b2f(k1)*q1 + b2f(k2)*q2 + b2f(k3)*q3) * 0.5f;
            float mn = fmaxf(m, sc);
            float c = __expf(m - mn);
            float pp = __expf(sc - mn);
            l = l*c + pp;
            acc.x = acc.x*c + pp*b2f(v0u);
            acc.y = acc.y*c + pp*b2f(v1u);
            acc.z = acc.z*c + pp*b2f(v2u);
            acc.w = acc.w*c + pp*b2f(v3u);
            m = mn;
        }
        const float inv = 1.f / fmaxf(l, 1e-30f);
        const int r = t >> 3, c0 = h*4;
        ows[r*40 + c0 + 0] = f2b(acc.x*inv);
        ows[r*40 + c0 + 1] = f2b(acc.y*inv);
        ows[r*40 + c0 + 2] = f2b(acc.z*inv);
        ows[r*40 + c0 + 3] = f2b(acc.w*inv);
    }
    __syncthreads();
    // ---- phase 2: 32x32 GEMM ----
    {
        const int wave = t >> 6, l15 = t & 15, quad = (t >> 4) & 3;
        const int mt = wave & 1, nt = wave >> 1;
        frag_ab af = *(const frag_ab*)&ows[(mt*16 + l15)*40 + quad*8];
        frag_ab bf = *(const frag_ab*)&wos[(nt*16 + l15)*40 + quad*8];
        frag_cd acc = {0.f, 0.f, 0.f, 0.f};
        acc = __builtin_amdgcn_mfma_f32_16x16x32_bf16(af, bf, acc, 0, 0, 0);
        #pragma unroll
        for (int rg = 0; rg < 4; ++rg) {
            const int row = mt*16 + quad*4 + rg;
            const int col = nt*16 + l15;
            cs[row][col] = acc[rg] + bos[col] + b2f(res[(size_t)(base+row)*32 + col]);
        }
    }
    __syncthreads();
    // ---- phase 3: LN per row ----
    {
        const int row = t >> 3, c0 = (t & 7) * 4;
        const float v0 = cs[row][c0], v1 = cs[row][c0+1];
        const float v2 = cs[row][c0+2], v3 = cs[row][c0+3];
        float s = v0+v1+v2+v3;
        s += __shfl_xor(s,1); s += __shfl_xor(s,2); s += __shfl_xor(s,4);
        const float mean = s * (1.f/32.f);
        float qq = (v0-mean)*(v0-mean)+(v1-mean)*(v1-mean)
                 + (v2-mean)*(v2-mean)+(v3-mean)*(v3-mean);
        qq += __shfl_xor(qq,1); qq += __shfl_xor(qq,2); qq += __shfl_xor(qq,4);
        const float inv = rsqrtf(qq * (1.f/32.f) + 1e-5f);
        out[(size_t)(base+row)*32 + c0 + 0] = f2b((v0-mean)*inv*gs[c0+0] + bs[c0+0]);
        out[(size_t)(base+row)*32 + c0 + 1] = f2b((v1-mean)*inv*gs[c0+1] + bs[c0+1]);
        out[(size_t)(base+row)*32 + c0 + 2] = f2b((v2-mean)*inv*gs[c0+2] + bs[c0+2]);
        out[(size_t)(base+row)*32 + c0 + 3] = f2b((v3-mean)*inv*gs[c0+3] + bs[c0+3]);
    }
}

// ---------------- host helper ----------------
static inline void mgemm(const float* A, const ush* WT, const void* bias, size_t boff,
                         float* C, const int* flag, int M, int N, int K, int flags,
                         hipStream_t s, ush* aux, ush* aux2, int splitz = 1){
    dim3 grid((N+63)/64, M/64, splitz);
    mgemm_k<<<grid, 256, 0, s>>>(A, WT, bias, boff, C, flag, M, N, K, flags, aux, aux2);
}

extern "C" void kernel_launch(void* const* d_in, const int* in_sizes, int n_in,
                              void* d_out, int out_size, void* d_ws, size_t ws_size,
                              hipStream_t stream) {
    const void* x_in      = d_in[0];
    const void* rel       = d_in[1];
    const int* g_src      = (const int*)d_in[4];
    const int* g_dst      = (const int*)d_in[5];
    const int* lg_src     = (const int*)d_in[6];
    const int* lg_dst     = (const int*)d_in[7];
    const int* edge_feat  = (const int*)d_in[8];
    const int* full_feat  = (const int*)d_in[9];
    const void* n_Wq   = d_in[10];
    const void* n_bq   = d_in[11];
    const void* n_Wk   = d_in[12];
    const void* n_bk   = d_in[13];
    const void* n_Wv   = d_in[14];
    const void* n_bv   = d_in[15];
    const void* n_Wo   = d_in[16];
    const void* n_bo   = d_in[17];
    const void* n_lng  = d_in[18];
    const void* n_lnb  = d_in[19];
    const void* n_fW1  = d_in[20];
    const void* n_fb1  = d_in[21];
    const void* n_fW2  = d_in[22];
    const void* n_fb2  = d_in[23];
    const void* n_flng = d_in[24];
    const void* n_flnb = d_in[25];
    const void* e_Wsrc = d_in[26];
    const void* e_Wdst = d_in[27];
    const void* e_Wq   = d_in[28];
    const void* e_bq   = d_in[29];
    const void* e_Wk   = d_in[30];
    const void* e_Wv   = d_in[31];
    const void* e_Wo   = d_in[32];
    const void* e_bo   = d_in[33];
    const void* e_lng  = d_in[34];
    const void* e_lnb  = d_in[35];
    const void* e_fW1  = d_in[36];
    const void* e_fb1  = d_in[37];
    const void* e_fW2  = d_in[38];
    const void* e_fb2  = d_in[39];
    const void* e_flng = d_in[40];
    const void* e_flnb = d_in[41];

    // ---- workspace carve-up (units: floats) ----
    float* p = (float*)d_ws;
    size_t off = 0;
    auto AL = [&](size_t n){ float* r = p + off; off += n; return r; };
    int* flagp = (int*)AL(64);
    float* xA   = AL((size_t)kN*kND);
    float* xB   = AL((size_t)kN*kND);
    float* xM   = AL((size_t)kN*kND);
    ush*   xAb  = (ush*)AL((size_t)kN*kND/2);
    ush*   xBb  = (ush*)AL((size_t)kN*kND/2);
    ush*   xMb  = (ush*)AL((size_t)kN*kND/2);
    float* qkvb = AL((size_t)kN*kND);            // fp32 Q only, [4096][256]
    ush*   kvaux= (ush*)AL((size_t)kN*kKV/2);    // bf16 [4096][512]: interleaved K/V
    ush*   xsdb = (ush*)AL((size_t)kN*32);       // bf16 [4096][64]: compact SD
    ush*   ob   = (ush*)AL((size_t)kN*kND/2);
    float* tN   = AL((size_t)kN*kND*2);          // split-K partials (2x)
    ush*   nh   = (ush*)AL((size_t)kN*512);      // kN*1024 bf16
    ush*   lgA  = (ush*)AL((size_t)kEL*kED/2);   // bf16 edge residual chain
    ush*   lgB  = (ush*)AL((size_t)kEL*kED/2);
    ush*   lgM  = (ush*)AL((size_t)kEL*kED/2);
    ush*   eqb  = (ush*)AL((size_t)kEL*16);      // kEL*32 bf16
    ush*   ekvb = (ush*)AL((size_t)kEL*32);      // kEL*64 bf16 interleaved K/V
    // CSR structures
    int* cntL  = (int*)AL(kN);
    int* rowL  = (int*)AL(kN + 64);
    int* curL  = (int*)AL(kN);
    int* eidL  = (int*)AL(kEL);
    int* cntG  = (int*)AL(kEL);
    int* rowG  = (int*)AL(kEL + 64);
    int* curG  = (int*)AL(kEL);
    int* eidG  = (int*)AL(kELG);
    int* bsum  = (int*)AL(256);
    // pre-transposed bf16 weights
    ush* wtQKVSD = (ush*)AL(212992);   // [L][832][256] bf16 (425984 ush)
    float* bQKV  = AL(2*kQW);
    ush* wtO  = (ush*)AL(65536);
    ush* wtF1 = (ush*)AL(262144);
    ush* wtF2 = (ush*)AL(262144);
    ush* wtEQKV = (ush*)AL(3072);
    ush* wtEO   = (ush*)AL(1024);
    ush* wtEF1  = (ush*)AL(4096);
    ush* wtEF2  = (ush*)AL(4096);
    if (ws_size < off * sizeof(float)) return;

    float* tN2 = tN + (size_t)kN*kND;

    detect_k<<<1, 64, 0, stream>>>((const ush*)x_in, flagp);
    {
        long total = (long)kN*kND/4 + (long)kEL*kED/4 + 2*kQW + kN + kEL;
        int blocks = (int)((total + 255) / 256);
        setup_misc_k<<<blocks, 256, 0, stream>>>(x_in, rel, edge_feat, n_bq, n_bk, n_bv,
                                                 xA, xAb, lgA, bQKV, cntL, cntG, flagp);
    }
    trans_tiled_k<<<1592, 256, 0, stream>>>(n_Wq, n_Wk, n_Wv, n_Wo, n_fW1, n_fW2,
                                            e_Wsrc, e_Wdst, e_Wq, e_Wk, e_Wv, e_Wo,
                                            e_fW1, e_fW2, flagp,
                                            wtQKVSD, wtO, wtF1, wtF2,
                                            wtEQKV, wtEO, wtEF1, wtEF2);

    count2_k<<<(kEL+kELG)/256, 256, 0, stream>>>(g_dst, lg_dst, cntL, cntG);
    scan_blk2_k<<<132, 256, 0, stream>>>(cntL, cntG, rowL, rowG, bsum);
    scan_top2_k<<<1, 256, 0, stream>>>(bsum);
    scan_add2_k<<<(kN+kEL)/256, 256, 0, stream>>>(rowL, rowG, bsum, curL, curG);
    fill2_k<<<(kEL+kELG)/256, 256, 0, stream>>>(g_dst, lg_dst, curL, curG, eidL, eidG);

    float* xc = xA;  float* xn = xB;
    ush* xcb = xAb;  ush* xnb = xBb;
    ush* lgc = lgA;  ush* lgn = lgB;

    for (int i = 0; i < kL; ++i) {
        const size_t o256 = (size_t)i*kND;
        const size_t o1024= (size_t)i*1024;
        const size_t o32  = (size_t)i*kED;
        const size_t o128 = (size_t)i*128;
        const bool last = (i == kL - 1);

        // ===== node update (fp32 Q + bf16 K/V + compact SD side-outputs) =====
        mgemm((const float*)xcb, wtQKVSD + (size_t)i*212992, bQKV, (size_t)i*kQW, qkvb,
              flagp, kN, kQW, kND, 4|16|32|64, stream, kvaux, xsdb);
        full_attn_k<<<512, 512, 0, stream>>>(qkvb, kvaux, rel, full_feat, ob, flagp);
        loc_gather_k<<<kN, 256, 0, stream>>>(qkvb, kvaux, lgc, g_src, rowL, eidL, ob);
        mgemm((const float*)ob, wtO + (size_t)i*65536, n_bo, o256, tN, flagp,
              kN, kND, kND, 4|32|128, stream, nullptr, nullptr, 2);
        ln_k<<<kN/4, 256, 0, stream>>>(xc, tN, tN2, n_lng, n_lnb, o256, xM, xMb,
                                       nullptr, flagp, kND);
        mgemm((const float*)xMb, wtF1 + (size_t)i*262144, n_fb1, o1024, (float*)nh, flagp,
              kN, 1024, kND, 4|2|8|32, stream, nullptr, nullptr);
        mgemm((const float*)nh, wtF2 + (size_t)i*262144, n_fb2, o256, tN, flagp,
              kN, kND, 1024, 4|32|128, stream, nullptr, nullptr, 2);
        ln_k<<<kN/4, 256, 0, stream>>>(xM, tN, tN2, n_flng, n_flnb, o256, xn, xnb,
                                       last ? d_out : nullptr, flagp, kND);

        // ===== edge update (uses PRE-update xc, lgc) =====
        eqkv_mfma_k<<<kEL/128, 256, 0, stream>>>(lgc, xsdb, g_src, g_dst,
                                                 wtEQKV, (size_t)i*1024, e_bq, o32,
                                                 eqb, ekvb, flagp);
        lgs_ewo_k<<<kEL/32, 256, 0, stream>>>(eqb, ekvb, lg_src, rowG, eidG,
                                              lgc, wtEO, (size_t)i*1024, e_bo, o32,
                                              e_lng, e_lnb, o32, lgM, flagp);
        effn_mfma_k<<<kEL/128, 256, 0, stream>>>(lgM, wtEF1, (size_t)i*4096, e_fb1, o128,
                                                 wtEF2, (size_t)i*4096, e_fb2, o32,
                                                 e_flng, e_flnb, o32, lgn,
                                                 last ? d_out : nullptr, flagp);

        { float* t = xc; xc = xn; xn = t; }
        { ush* t = xcb; xcb = xnb; xnb = t; }
        { ush* t = lgc; lgc = lgn; lgn = t; }
    }
}